// Round 2
// baseline (15906.181 us; speedup 1.0000x reference)
//
#include <hip/hip_runtime.h>
#include <math.h>

#define NB   32
#define KG   2048
#define NSEQ 2049
#define DIM  256
#define NH   4
#define DH   64
#define MF   266
#define FFD  1024
#define BN   (NB*NSEQ)          // 65568
#define FFROWS 16392            // BN/4
#define NORMC 0.35355339059327376f   // 64^-0.25
#define RATIOC (1.0f/16.309506430300091f) // 266^-0.5

__device__ __forceinline__ float gelu_f(float x){
  return 0.5f*x*(1.0f+erff(x*0.70710678118654752f));
}
__device__ __forceinline__ float waveSum(float v){
  #pragma unroll
  for(int o=32;o>0;o>>=1) v += __shfl_down(v,o);
  return v;
}
__device__ __forceinline__ float waveMax(float v){
  #pragma unroll
  for(int o=32;o>0;o>>=1) v = fmaxf(v,__shfl_down(v,o));
  return v;
}
// blockDim.x == 256 assumed (4 waves)
__device__ __forceinline__ float blockSum256(float v, float* red){
  int lane = threadIdx.x & 63, wid = threadIdx.x >> 6;
  v = waveSum(v);
  __syncthreads();
  if(lane==0) red[wid]=v;
  __syncthreads();
  return red[0]+red[1]+red[2]+red[3];
}
__device__ __forceinline__ float blockMax256(float v, float* red){
  int lane = threadIdx.x & 63, wid = threadIdx.x >> 6;
  v = waveMax(v);
  __syncthreads();
  if(lane==0) red[wid]=v;
  __syncthreads();
  return fmaxf(fmaxf(red[0],red[1]),fmaxf(red[2],red[3]));
}
// order-preserving float<->uint for atomicMax (all real floats encode > 0)
__device__ __forceinline__ unsigned fenc(float f){
  unsigned u = __float_as_uint(f);
  return (u & 0x80000000u) ? ~u : (u | 0x80000000u);
}
__device__ __forceinline__ float fdec(unsigned u){
  return (u & 0x80000000u) ? __uint_as_float(u & 0x7FFFFFFFu) : __uint_as_float(~u);
}

// ---------------- embed
__global__ __launch_bounds__(256) void embed_kernel(
    const float* __restrict__ expr, const float* __restrict__ coords,
    const float* __restrict__ gene_emb, const float* __restrict__ pos_emb,
    const float* __restrict__ val_w, const float* __restrict__ val_b,
    const float* __restrict__ val_g, const float* __restrict__ val_bb,
    const float* __restrict__ sp_w, const float* __restrict__ sp_b,
    const float* __restrict__ sp_g, const float* __restrict__ sp_bb,
    float* __restrict__ x){
  __shared__ float red[4];
  int row = blockIdx.x; int b = row / NSEQ, n = row % NSEQ;
  int d = threadIdx.x;
  float v;
  if(n==0) v = coords[b*2]*sp_w[d] + coords[b*2+1]*sp_w[DIM+d] + sp_b[d];
  else     v = expr[(size_t)b*KG + (n-1)]*val_w[d] + val_b[d];
  float mu = blockSum256(v, red)*(1.0f/DIM);
  float c  = v - mu;
  float var = blockSum256(c*c, red)*(1.0f/DIM);
  float r = rsqrtf(var + 1e-5f);
  float g  = (n==0)? sp_g[d]  : val_g[d];
  float be = (n==0)? sp_bb[d] : val_bb[d];
  float h = gelu_f(c*r*g + be);
  float o = (n==0)? h : (gene_emb[(size_t)(n-1)*DIM+d]+pos_emb[(size_t)(n-1)*DIM+d]+h);
  x[(size_t)row*DIM + d] = o;
}

// ---------------- per-row LN stats: mu, rstd
__global__ __launch_bounds__(256) void ln_stats_kernel(const float* __restrict__ xin,
    float* __restrict__ mu, float* __restrict__ rstd){
  __shared__ float red[4];
  int row = blockIdx.x; int d = threadIdx.x;
  float v = xin[(size_t)row*DIM+d];
  float m = blockSum256(v,red)*(1.0f/DIM);
  float c = v-m;
  float var = blockSum256(c*c,red)*(1.0f/DIM);
  if(d==0){ mu[row]=m; rstd[row]=rsqrtf(var+1e-5f); }
}

// ---------------- generic fp32 GEMM: C = epi(LNF(A)@B + bias [+C])
// EPI 0=none 1=residual-add 2=gelu ; LNF=1 applies (a-mu[m])*rstd[m]*g[k]+bb[k] to A
template<int EPI, int LNF>
__global__ __launch_bounds__(256) void gemm_kernel(
    const float* __restrict__ A, const float* __restrict__ Bm,
    const float* __restrict__ bias, float* __restrict__ C,
    const float* __restrict__ mu, const float* __restrict__ rstd,
    const float* __restrict__ lng, const float* __restrict__ lnb,
    int M, int N, int Kd){
  __shared__ float As[16][65];
  __shared__ float Bs[16][65];
  int t = threadIdx.x;
  int tx = t & 15, ty = t >> 4;
  int m0 = blockIdx.y*64, n0 = blockIdx.x*64;
  float acc[4][4]={};
  for(int k0=0;k0<Kd;k0+=16){
    #pragma unroll
    for(int i=0;i<4;i++){
      int e=t+i*256; int mm=e>>4, kk=e&15;
      int gm=m0+mm;
      float xv = 0.0f;
      if(gm<M){
        xv = A[(size_t)gm*Kd + k0+kk];
        if(LNF) xv = (xv - mu[gm])*rstd[gm]*lng[k0+kk] + lnb[k0+kk];
      }
      As[kk][mm] = xv;
    }
    #pragma unroll
    for(int i=0;i<4;i++){
      int e=t+i*256; int kk=e>>6, nn=e&63;
      Bs[kk][nn] = Bm[(size_t)(k0+kk)*N + n0+nn];
    }
    __syncthreads();
    #pragma unroll
    for(int kk=0;kk<16;kk++){
      float a[4],bv[4];
      #pragma unroll
      for(int i=0;i<4;i++) a[i]=As[kk][ty+16*i];
      #pragma unroll
      for(int j=0;j<4;j++) bv[j]=Bs[kk][tx+16*j];
      #pragma unroll
      for(int i=0;i<4;i++)
        #pragma unroll
        for(int j=0;j<4;j++) acc[i][j] += a[i]*bv[j];
    }
    __syncthreads();
  }
  #pragma unroll
  for(int i=0;i<4;i++){
    int mm=m0+ty+16*i; if(mm>=M) continue;
    #pragma unroll
    for(int j=0;j<4;j++){
      int nn=n0+tx+16*j;
      float vv=acc[i][j]+bias[nn];
      size_t idx=(size_t)mm*N+nn;
      if(EPI==1) vv += C[idx];
      if(EPI==2) vv = gelu_f(vv);
      C[idx]=vv;
    }
  }
}

// ---------------- diag_k[b,h,n] = 0.0625*||k[b,h,n,:]||^2
__global__ __launch_bounds__(256) void diagk_kernel(const float* __restrict__ kbuf, float* __restrict__ diagk){
  int row = blockIdx.x; int b=row/NSEQ, n=row%NSEQ;
  int t=threadIdx.x; int h=t>>6;
  float v = kbuf[(size_t)row*DIM + t];
  float s = waveSum(v*v);
  if((t&63)==0) diagk[((size_t)(b*NH+h))*NSEQ + n] = 0.0625f*s;
}

__global__ void kmax_init_kernel(unsigned* km){ *km = 0u; }

// ---------------- k-side: PASS0 = global max of xd_k; PASS1 = context[b,h,m,d] & ksum[b,h,m]
template<int PASS>
__global__ __launch_bounds__(256) void kside_kernel(
    const float* __restrict__ kbuf, const float* __restrict__ vbuf,
    const float* __restrict__ proj, const float* __restrict__ diagk,
    unsigned* __restrict__ kmax,
    float* __restrict__ ctx, float* __restrict__ ksum){
  __shared__ float projS[32][65];
  __shared__ float kS[32][65];
  __shared__ float vS[32][65];
  __shared__ float kfS[32][33];
  __shared__ float diagS[32];
  __shared__ float red[4];
  int t = threadIdx.x;
  int mt = blockIdx.x, bh = blockIdx.y;
  int b = bh >> 2, h = bh & 3;
  int m0 = mt*32;
  #pragma unroll
  for(int i=0;i<8;i++){
    int e=t+i*256; int mi=e>>6, dd=e&63;
    projS[mi][dd] = (m0+mi<MF)? proj[(size_t)(m0+mi)*DH+dd] : 0.0f;
  }
  float stab=0.0f;
  if(PASS==1) stab = fdec(*kmax);
  float acc[8]={0,0,0,0,0,0,0,0};
  float aks[8]={0,0,0,0,0,0,0,0};
  float lmax=-3.4e38f;
  int mgrp=t>>6, d=t&63;
  int nirow = t&31, mi0 = t>>5;
  for(int n0=0;n0<NSEQ;n0+=32){
    int nrows = min(32, NSEQ-n0);
    __syncthreads();
    #pragma unroll
    for(int i=0;i<8;i++){
      int e=t+i*256; int ni=e>>6, dd=e&63;
      float kv=0.0f, vv=0.0f;
      if(ni<nrows){
        size_t base = ((size_t)(b*NSEQ+n0+ni))*DIM + h*DH + dd;
        kv = kbuf[base];
        if(PASS==1) vv = vbuf[base];
      }
      kS[ni][dd]=kv;
      if(PASS==1) vS[ni][dd]=vv;
    }
    if(PASS==1 && t<32) diagS[t] = (t<nrows)? diagk[(size_t)bh*NSEQ + n0+t] : 0.0f;
    __syncthreads();
    float s0=0,s1=0,s2=0,s3=0;
    #pragma unroll 16
    for(int dd=0;dd<64;dd++){
      float kv = kS[nirow][dd];
      s0 += kv*projS[mi0][dd];
      s1 += kv*projS[mi0+8][dd];
      s2 += kv*projS[mi0+16][dd];
      s3 += kv*projS[mi0+24][dd];
    }
    s0*=NORMC; s1*=NORMC; s2*=NORMC; s3*=NORMC;
    if(PASS==0){
      if(nirow<nrows){
        if(m0+mi0<MF)    lmax=fmaxf(lmax,s0);
        if(m0+mi0+8<MF)  lmax=fmaxf(lmax,s1);
        if(m0+mi0+16<MF) lmax=fmaxf(lmax,s2);
        if(m0+mi0+24<MF) lmax=fmaxf(lmax,s3);
      }
    } else {
      float dg = diagS[nirow];
      bool rowok = nirow<nrows;
      kfS[nirow][mi0]    = (rowok && m0+mi0<MF)?    RATIOC*(expf(s0-dg-stab)+1e-4f) : 0.0f;
      kfS[nirow][mi0+8]  = (rowok && m0+mi0+8<MF)?  RATIOC*(expf(s1-dg-stab)+1e-4f) : 0.0f;
      kfS[nirow][mi0+16] = (rowok && m0+mi0+16<MF)? RATIOC*(expf(s2-dg-stab)+1e-4f) : 0.0f;
      kfS[nirow][mi0+24] = (rowok && m0+mi0+24<MF)? RATIOC*(expf(s3-dg-stab)+1e-4f) : 0.0f;
      __syncthreads();
      for(int ni=0;ni<32;ni++){
        float vv = vS[ni][d];
        #pragma unroll
        for(int m8=0;m8<8;m8++) acc[m8] += kfS[ni][mgrp*8+m8]*vv;
        if(d==0){
          #pragma unroll
          for(int m8=0;m8<8;m8++) aks[m8] += kfS[ni][mgrp*8+m8];
        }
      }
    }
  }
  if(PASS==0){
    float bm = blockMax256(lmax, red);
    if(t==0) atomicMax(kmax, fenc(bm));
  } else {
    #pragma unroll
    for(int m8=0;m8<8;m8++){
      int m = m0 + mgrp*8 + m8;
      if(m<MF){
        ctx[((size_t)bh*MF + m)*DH + d] = acc[m8];
        if(d==0) ksum[(size_t)bh*MF + m] = aks[m8];
      }
    }
  }
}

// ---------------- fused q-side (in-place safe: reads own 64 floats first, writes them last)
__global__ __launch_bounds__(256) void qside_kernel(
    const float* __restrict__ qbuf, const float* __restrict__ proj,
    const float* __restrict__ ctx, const float* __restrict__ ksum,
    float* __restrict__ outb){
  __shared__ float qs[64];
  __shared__ float qf[MF];
  __shared__ float red[4];
  __shared__ float outp[4][64];
  __shared__ float dred[4];
  int n = blockIdx.x, bh = blockIdx.y;
  int b = bh>>2, h = bh&3;
  int t = threadIdx.x;
  size_t qbase = ((size_t)(b*NSEQ+n))*DIM + h*DH;
  if(t<64) qs[t]=qbuf[qbase+t];
  __syncthreads();
  float dv = (t<64)? qs[t]*qs[t] : 0.0f;
  float diag = 0.0625f*blockSum256(dv,red);
  float xv0, xv1=0.0f;
  float lmax;
  {
    const float* pr = proj + (size_t)t*DH;
    float s=0;
    #pragma unroll 16
    for(int dd=0;dd<64;dd++) s += qs[dd]*pr[dd];
    xv0 = s*NORMC; lmax=xv0;
  }
  if(t<MF-256){
    const float* pr = proj + (size_t)(t+256)*DH;
    float s=0;
    #pragma unroll 16
    for(int dd=0;dd<64;dd++) s += qs[dd]*pr[dd];
    xv1 = s*NORMC; lmax=fmaxf(lmax,xv1);
  }
  float stab = blockMax256(lmax,red);
  qf[t] = RATIOC*(expf(xv0-diag-stab)+1e-4f);
  if(t<MF-256) qf[t+256] = RATIOC*(expf(xv1-diag-stab)+1e-4f);
  __syncthreads();
  int d=t&63, qd=t>>6;
  int ms=qd*67, me=min(MF, ms+67);
  float po=0.0f, pd=0.0f;
  const float* cb = ctx + ((size_t)bh*MF)*DH + d;
  const float* kb = ksum + (size_t)bh*MF;
  for(int m=ms;m<me;m++){
    float f=qf[m];
    po += f*cb[(size_t)m*DH];
    if(d==0) pd += f*kb[m];
  }
  outp[qd][d]=po;
  if(d==0) dred[qd]=pd;
  __syncthreads();
  if(t<64){
    float o   = outp[0][t]+outp[1][t]+outp[2][t]+outp[3][t];
    float den = dred[0]+dred[1]+dred[2]+dred[3];
    outb[qbase+t] = o/den;
  }
}

// ---------------- small (32 x 256)@(256 x 256) row projection
__global__ __launch_bounds__(256) void rowproj_kernel(const float* __restrict__ src,
    const float* __restrict__ W, const float* __restrict__ bias,
    float* __restrict__ dst, int rowstride){
  __shared__ float rs[DIM];
  int b=blockIdx.x, t=threadIdx.x;
  rs[t]=src[(size_t)b*rowstride+t];
  __syncthreads();
  float s=bias[t];
  for(int j=0;j<DIM;j++) s += rs[j]*W[(size_t)j*DIM+t];
  dst[(size_t)b*DIM+t]=s;
}

// ---------------- final pooling attention over K gene tokens
__global__ __launch_bounds__(256) void attnpool_kernel(const float* __restrict__ qfin,
    const float* __restrict__ kk, const float* __restrict__ vv, float* __restrict__ pooled){
  __shared__ float qsh[DIM];
  __shared__ float sc[KG];
  __shared__ float red[4];
  int b=blockIdx.x, t=threadIdx.x;
  qsh[t]=qfin[b*DIM+t];
  __syncthreads();
  float ls[8]; float lmax=-3.4e38f;
  #pragma unroll
  for(int i=0;i<8;i++){
    int kidx=t+i*256;
    const float* kr = kk + ((size_t)(b*NSEQ+1+kidx))*DIM;
    float s=0;
    for(int j=0;j<DIM;j++) s += qsh[j]*kr[j];
    s *= 0.0625f;
    ls[i]=s; lmax=fmaxf(lmax,s);
  }
  float gmax=blockMax256(lmax,red);
  float lsum=0;
  #pragma unroll
  for(int i=0;i<8;i++){ float e=expf(ls[i]-gmax); sc[t+i*256]=e; lsum+=e; }
  float gsum=blockSum256(lsum,red);
  __syncthreads();
  float inv=1.0f/gsum;
  float p=0;
  for(int kidx=0;kidx<KG;kidx++) p += sc[kidx]*vv[((size_t)(b*NSEQ+1+kidx))*DIM + t];
  pooled[b*DIM+t]=p*inv;
}

extern "C" void kernel_launch(void* const* d_in, const int* in_sizes, int n_in,
                              void* d_out, int out_size, void* d_ws, size_t ws_size,
                              hipStream_t stream){
  const float* expr   =(const float*)d_in[0];
  const float* coords =(const float*)d_in[1];
  const float* gene_emb=(const float*)d_in[2];
  const float* pos_emb=(const float*)d_in[3];
  const float* val_w  =(const float*)d_in[4];
  const float* val_b  =(const float*)d_in[5];
  const float* val_g  =(const float*)d_in[6];
  const float* val_bb =(const float*)d_in[7];
  const float* sp_w   =(const float*)d_in[8];
  const float* sp_b   =(const float*)d_in[9];
  const float* sp_g   =(const float*)d_in[10];
  const float* sp_bb  =(const float*)d_in[11];
  const float* p_ln1_g=(const float*)d_in[12];
  const float* p_ln1_b=(const float*)d_in[13];
  const float* p_wq   =(const float*)d_in[14];
  const float* p_bq   =(const float*)d_in[15];
  const float* p_wk   =(const float*)d_in[16];
  const float* p_bk   =(const float*)d_in[17];
  const float* p_wv   =(const float*)d_in[18];
  const float* p_bv   =(const float*)d_in[19];
  const float* p_wo   =(const float*)d_in[20];
  const float* p_bo   =(const float*)d_in[21];
  const float* p_ln2_g=(const float*)d_in[22];
  const float* p_ln2_b=(const float*)d_in[23];
  const float* p_ff1_w=(const float*)d_in[24];
  const float* p_ff1_b=(const float*)d_in[25];
  const float* p_ff2_w=(const float*)d_in[26];
  const float* p_ff2_b=(const float*)d_in[27];
  const float* proj   =(const float*)d_in[28];
  const float* q_w    =(const float*)d_in[29];
  const float* q_b    =(const float*)d_in[30];
  const float* k_w    =(const float*)d_in[31];
  const float* k_b    =(const float*)d_in[32];
  const float* v_w    =(const float*)d_in[33];
  const float* v_b    =(const float*)d_in[34];
  const float* o_w    =(const float*)d_in[35];
  const float* o_b    =(const float*)d_in[36];
  float* out = (float*)d_out;

  const size_t BND = (size_t)BN*DIM;                 // 16,785,408 floats
  // ws layout (floats): x | b | c | mu | rstd | diagk | ctx | ksum | kmax | qfin | pooled
  size_t need = 3*BND + 2*(size_t)BN + (size_t)NB*NH*NSEQ
              + (size_t)NB*NH*MF*DH + (size_t)NB*NH*MF + 4 + 2*(size_t)NB*DIM;
  if(ws_size < need*sizeof(float)){
    // diagnostic fallback: zero output (clean absmax-fail instead of OOB fault)
    hipMemsetAsync(d_out, 0, (size_t)out_size*sizeof(float), stream);
    return;
  }
  float* ws = (float*)d_ws;
  float* x  = ws;
  float* b_ = x  + BND;
  float* c_ = b_ + BND;
  float* mu   = c_ + BND;
  float* rstd = mu + BN;
  float* diagk = rstd + BN;
  float* ctx  = diagk + (size_t)NB*NH*NSEQ;
  float* ksum = ctx + (size_t)NB*NH*MF*DH;
  unsigned* kmax = (unsigned*)(ksum + (size_t)NB*NH*MF);
  float* qfin   = (float*)(kmax+4);
  float* pooled = qfin + NB*DIM;

  embed_kernel<<<BN,256,0,stream>>>(expr,coords,gene_emb,pos_emb,val_w,val_b,val_g,val_bb,
                                    sp_w,sp_b,sp_g,sp_bb,x);

  dim3 g256(DIM/64, (BN+63)/64);
  dim3 gff1(FFD/64, (FFROWS+63)/64);
  dim3 gff2(DIM/64, (FFROWS+63)/64);
  dim3 gks((MF+31)/32, NB*NH);
  dim3 gq(NSEQ, NB*NH);

  for(int l=0;l<2;l++){
    const float* prj = proj + (size_t)l*MF*DH;
    const float* g1 = p_ln1_g+l*DIM, *bb1 = p_ln1_b+l*DIM;
    const float* g2 = p_ln2_g+l*DIM, *bb2 = p_ln2_b+l*DIM;
    ln_stats_kernel<<<BN,256,0,stream>>>(x, mu, rstd);
    // k -> c_, v -> b_ (LN1 folded into A-load)
    gemm_kernel<0,1><<<g256,256,0,stream>>>(x, p_wk+(size_t)l*DIM*DIM, p_bk+l*DIM, c_, mu,rstd,g1,bb1, BN, DIM, DIM);
    gemm_kernel<0,1><<<g256,256,0,stream>>>(x, p_wv+(size_t)l*DIM*DIM, p_bv+l*DIM, b_, mu,rstd,g1,bb1, BN, DIM, DIM);
    diagk_kernel<<<BN,256,0,stream>>>(c_, diagk);
    kmax_init_kernel<<<1,1,0,stream>>>(kmax);
    kside_kernel<0><<<gks,256,0,stream>>>(c_,(const float*)nullptr,prj,(const float*)nullptr,kmax,(float*)nullptr,(float*)nullptr);
    kside_kernel<1><<<gks,256,0,stream>>>(c_,b_,prj,diagk,kmax,ctx,ksum);
    // q -> b_ (v is dead now), attention in-place in b_
    gemm_kernel<0,1><<<g256,256,0,stream>>>(x, p_wq+(size_t)l*DIM*DIM, p_bq+l*DIM, b_, mu,rstd,g1,bb1, BN, DIM, DIM);
    qside_kernel<<<gq,256,0,stream>>>(b_,prj,ctx,ksum,b_);
    // x += attn_out @ Wo + bo
    gemm_kernel<1,0><<<g256,256,0,stream>>>(b_, p_wo+(size_t)l*DIM*DIM, p_bo+l*DIM, x, nullptr,nullptr,nullptr,nullptr, BN, DIM, DIM);
    // FF (LN2 folded into ff1 A-load), intermediate chunks in c_
    ln_stats_kernel<<<BN,256,0,stream>>>(x, mu, rstd);
    for(int c4=0;c4<4;c4++){
      size_t roff=(size_t)c4*FFROWS;
      gemm_kernel<2,1><<<gff1,256,0,stream>>>(x+roff*DIM, p_ff1_w+(size_t)l*DIM*FFD, p_ff1_b+l*FFD, c_,
                                              mu+roff, rstd+roff, g2, bb2, FFROWS, FFD, DIM);
      gemm_kernel<1,0><<<gff2,256,0,stream>>>(c_, p_ff2_w+(size_t)l*FFD*DIM, p_ff2_b+l*DIM, x+roff*DIM,
                                              nullptr,nullptr,nullptr,nullptr, FFROWS, DIM, FFD);
    }
  }

  // final pooling attention
  gemm_kernel<0,0><<<g256,256,0,stream>>>(x, k_w, k_b, b_, nullptr,nullptr,nullptr,nullptr, BN, DIM, DIM);
  gemm_kernel<0,0><<<g256,256,0,stream>>>(x, v_w, v_b, c_, nullptr,nullptr,nullptr,nullptr, BN, DIM, DIM);
  rowproj_kernel<<<NB,256,0,stream>>>(x, q_w, q_b, qfin, NSEQ*DIM);
  attnpool_kernel<<<NB,256,0,stream>>>(qfin, b_, c_, pooled);
  rowproj_kernel<<<NB,256,0,stream>>>(pooled, o_w, o_b, out, DIM);
}

// Round 3
// 3559.237 us; speedup vs baseline: 4.4690x; 4.4690x over previous
//
#include <hip/hip_runtime.h>
#include <hip/hip_bf16.h>
#include <math.h>

#define NB   32
#define KG   2048
#define NSEQ 2049
#define DIM  256
#define NH   4
#define DH   64
#define MF   266
#define FFD  1024
#define BN   (NB*NSEQ)          // 65568
#define FFROWS 16392            // BN/4
#define NORMC 0.35355339059327376f   // 64^-0.25
#define RATIOC (1.0f/16.309506430300091f) // 266^-0.5

typedef __attribute__((ext_vector_type(8))) short short8;
typedef __attribute__((ext_vector_type(4))) float f32x4;
#define MFMA16(a,b,c) __builtin_amdgcn_mfma_f32_16x16x32_bf16(a,b,c,0,0,0)

__device__ __forceinline__ short f2b(float f){
  union{ __hip_bfloat16 h; short s;} u; u.h = __float2bfloat16(f); return u.s;
}
__device__ __forceinline__ float b2f(short s){
  union{ short s; __hip_bfloat16 h;} u; u.s = s; return __bfloat162float(u.h);
}
__device__ __forceinline__ float gelu_f(float x){
  return 0.5f*x*(1.0f+erff(x*0.70710678118654752f));
}
__device__ __forceinline__ float waveSum(float v){
  #pragma unroll
  for(int o=32;o>0;o>>=1) v += __shfl_down(v,o);
  return v;
}
__device__ __forceinline__ float waveMax(float v){
  #pragma unroll
  for(int o=32;o>0;o>>=1) v = fmaxf(v,__shfl_down(v,o));
  return v;
}
__device__ __forceinline__ float blockSum256(float v, float* red){
  int lane = threadIdx.x & 63, wid = threadIdx.x >> 6;
  v = waveSum(v);
  __syncthreads();
  if(lane==0) red[wid]=v;
  __syncthreads();
  return red[0]+red[1]+red[2]+red[3];
}
__device__ __forceinline__ float blockMax256(float v, float* red){
  int lane = threadIdx.x & 63, wid = threadIdx.x >> 6;
  v = waveMax(v);
  __syncthreads();
  if(lane==0) red[wid]=v;
  __syncthreads();
  return fmaxf(fmaxf(red[0],red[1]),fmaxf(red[2],red[3]));
}
__device__ __forceinline__ unsigned fenc(float f){
  unsigned u = __float_as_uint(f);
  return (u & 0x80000000u) ? ~u : (u | 0x80000000u);
}
__device__ __forceinline__ float fdec(unsigned u){
  return (u & 0x80000000u) ? __uint_as_float(u & 0x7FFFFFFFu) : __uint_as_float(~u);
}

// ---------------- embed
__global__ __launch_bounds__(256) void embed_kernel(
    const float* __restrict__ expr, const float* __restrict__ coords,
    const float* __restrict__ gene_emb, const float* __restrict__ pos_emb,
    const float* __restrict__ val_w, const float* __restrict__ val_b,
    const float* __restrict__ val_g, const float* __restrict__ val_bb,
    const float* __restrict__ sp_w, const float* __restrict__ sp_b,
    const float* __restrict__ sp_g, const float* __restrict__ sp_bb,
    float* __restrict__ x){
  __shared__ float red[4];
  int row = blockIdx.x; int b = row / NSEQ, n = row % NSEQ;
  int d = threadIdx.x;
  float v;
  if(n==0) v = coords[b*2]*sp_w[d] + coords[b*2+1]*sp_w[DIM+d] + sp_b[d];
  else     v = expr[(size_t)b*KG + (n-1)]*val_w[d] + val_b[d];
  float mu = blockSum256(v, red)*(1.0f/DIM);
  float c  = v - mu;
  float var = blockSum256(c*c, red)*(1.0f/DIM);
  float r = rsqrtf(var + 1e-5f);
  float g  = (n==0)? sp_g[d]  : val_g[d];
  float be = (n==0)? sp_bb[d] : val_bb[d];
  float h = gelu_f(c*r*g + be);
  float o = (n==0)? h : (gene_emb[(size_t)(n-1)*DIM+d]+pos_emb[(size_t)(n-1)*DIM+d]+h);
  x[(size_t)row*DIM + d] = o;
}

// ---------------- per-row LN stats
__global__ __launch_bounds__(256) void ln_stats_kernel(const float* __restrict__ xin,
    float* __restrict__ mu, float* __restrict__ rstd){
  __shared__ float red[4];
  int row = blockIdx.x; int d = threadIdx.x;
  float v = xin[(size_t)row*DIM+d];
  float m = blockSum256(v,red)*(1.0f/DIM);
  float c = v-m;
  float var = blockSum256(c*c,red)*(1.0f/DIM);
  if(d==0){ mu[row]=m; rstd[row]=rsqrtf(var+1e-5f); }
}

// ---------------- MFMA GEMM: C = epi(LNF(A)@B + bias [+C]), bf16 inputs fp32 accum
// tile 128m x 64n x 32k, 4 waves (2m x 2n), each wave 64x32 -> 4x2 frags
template<int EPI, int LNF>
__global__ __launch_bounds__(256) void mgemm(
    const float* __restrict__ A, const float* __restrict__ Bm,
    const float* __restrict__ bias, float* __restrict__ C,
    const float* __restrict__ mu, const float* __restrict__ rstd,
    const float* __restrict__ lng, const float* __restrict__ lnb,
    int M, int N, int Kd){
  __shared__ short As[128*40];
  __shared__ short Bs[64*40];
  int t = threadIdx.x;
  int l = t & 63, w = t >> 6;
  int wm = w >> 1, wn = w & 1;
  int lr = l & 15, lk = l >> 4;
  int m0 = blockIdx.y*128, n0 = blockIdx.x*64;
  f32x4 acc[4][2];
  #pragma unroll
  for(int i=0;i<4;i++)
    #pragma unroll
    for(int j=0;j<2;j++) acc[i][j] = f32x4{0.f,0.f,0.f,0.f};
  for(int k0=0;k0<Kd;k0+=32){
    // stage A (128x32 fp32 -> bf16, LN fold optional)
    #pragma unroll
    for(int p=0;p<4;p++){
      int r = (t>>3) + p*32;
      int gm = m0 + r;
      int kc = (t&7)*4;
      float vx=0.f,vy=0.f,vz=0.f,vw=0.f;
      if(gm<M){
        const float* ap = A + (size_t)gm*Kd + k0 + kc;
        float4 v = *reinterpret_cast<const float4*>(ap);
        vx=v.x; vy=v.y; vz=v.z; vw=v.w;
        if(LNF){
          float mm=mu[gm], rr=rstd[gm];
          vx=(vx-mm)*rr*lng[k0+kc+0]+lnb[k0+kc+0];
          vy=(vy-mm)*rr*lng[k0+kc+1]+lnb[k0+kc+1];
          vz=(vz-mm)*rr*lng[k0+kc+2]+lnb[k0+kc+2];
          vw=(vw-mm)*rr*lng[k0+kc+3]+lnb[k0+kc+3];
        }
      }
      *reinterpret_cast<short4*>(&As[r*40+kc]) = make_short4(f2b(vx),f2b(vy),f2b(vz),f2b(vw));
    }
    // stage B transposed: Bs[n][k]
    #pragma unroll
    for(int p=0;p<4;p++){
      int k1 = 2*((t>>6) + p*4);
      int nn = t & 63;
      float b0 = Bm[(size_t)(k0+k1  )*N + n0+nn];
      float b1 = Bm[(size_t)(k0+k1+1)*N + n0+nn];
      *reinterpret_cast<short2*>(&Bs[nn*40+k1]) = make_short2(f2b(b0),f2b(b1));
    }
    __syncthreads();
    short8 af[4], bfr[2];
    #pragma unroll
    for(int i=0;i<4;i++) af[i] = *reinterpret_cast<const short8*>(&As[(wm*64+i*16+lr)*40 + lk*8]);
    #pragma unroll
    for(int j=0;j<2;j++) bfr[j] = *reinterpret_cast<const short8*>(&Bs[(wn*32+j*16+lr)*40 + lk*8]);
    #pragma unroll
    for(int i=0;i<4;i++)
      #pragma unroll
      for(int j=0;j<2;j++) acc[i][j] = MFMA16(af[i], bfr[j], acc[i][j]);
    __syncthreads();
  }
  #pragma unroll
  for(int i=0;i<4;i++){
    int gr0 = m0 + wm*64 + i*16 + lk*4;
    #pragma unroll
    for(int j=0;j<2;j++){
      int gc = n0 + wn*32 + j*16 + lr;
      float bs = bias[gc];
      #pragma unroll
      for(int r=0;r<4;r++){
        int gm = gr0 + r;
        if(gm<M){
          float vv = acc[i][j][r] + bs;
          size_t idx = (size_t)gm*N + gc;
          if(EPI==1) vv += C[idx];
          if(EPI==2) vv = gelu_f(vv);
          C[idx] = vv;
        }
      }
    }
  }
}

// ---------------- projbf: bf16(proj * NORMC), 272 rows (pad zero)
__global__ __launch_bounds__(256) void projprep_kernel(const float* __restrict__ proj, short* __restrict__ projbf){
  int i = blockIdx.x*256 + threadIdx.x;
  if(i < 272*64){
    int m = i>>6, d = i&63;
    float v = (m<MF)? proj[(size_t)m*DH + d]*NORMC : 0.f;
    projbf[i] = f2b(v);
  }
}

// ---------------- diag_k
__global__ __launch_bounds__(256) void diagk_kernel(const float* __restrict__ kbuf, float* __restrict__ diagk){
  int row = blockIdx.x; int b=row/NSEQ, n=row%NSEQ;
  int t=threadIdx.x; int h=t>>6;
  float v = kbuf[(size_t)row*DIM + t];
  float s = waveSum(v*v);
  if((t&63)==0) diagk[((size_t)(b*NH+h))*NSEQ + n] = 0.0625f*s;
}

__global__ void kmax_init_kernel(unsigned* km){ *km = 0u; }

// ---------------- kside pass0: global max of xd_k via MFMA (xd^T = projn @ k^T)
__global__ __launch_bounds__(256) void kside_max(
    const float* __restrict__ kbuf, const short* __restrict__ projbf,
    unsigned* __restrict__ kmax){
  __shared__ short kS[32*72];
  __shared__ float red[4];
  int t=threadIdx.x, l=t&63, w=t>>6, lr=l&15, lk=l>>4;
  int split = blockIdx.x, bh = blockIdx.y;
  int b=bh>>2, h=bh&3;
  int c0 = split*17, c1 = min(c0+17, 65);
  int nf = (w==3)?5:4;
  short8 apf[5][2];
  for(int fi=0;fi<nf;fi++){
    int fr = (fi<4)? (fi*4+w) : 16;
    #pragma unroll
    for(int ks=0;ks<2;ks++)
      apf[fi][ks] = *reinterpret_cast<const short8*>(projbf + (fr*16+lr)*64 + ks*32 + lk*8);
  }
  float lmax = -3.0e38f;
  for(int ch=c0; ch<c1; ++ch){
    int n0 = ch*32;
    __syncthreads();
    #pragma unroll
    for(int p=0;p<2;p++){
      int r = t>>3, cq = ((t&7)+p*8)*4;
      int gn = n0 + r;
      float4 v={0.f,0.f,0.f,0.f};
      if(gn<NSEQ) v = *reinterpret_cast<const float4*>(kbuf + ((size_t)(b*NSEQ+gn))*DIM + h*DH + cq);
      *reinterpret_cast<short4*>(&kS[r*72+cq]) = make_short4(f2b(v.x),f2b(v.y),f2b(v.z),f2b(v.w));
    }
    __syncthreads();
    for(int fi=0;fi<nf;fi++){
      int fr = (fi<4)? (fi*4+w) : 16;
      #pragma unroll
      for(int fn=0;fn<2;fn++){
        f32x4 xa = f32x4{0.f,0.f,0.f,0.f};
        #pragma unroll
        for(int ks=0;ks<2;ks++){
          short8 bk = *reinterpret_cast<const short8*>(&kS[(fn*16+lr)*72 + ks*32 + lk*8]);
          xa = MFMA16(apf[fi][ks], bk, xa);
        }
        #pragma unroll
        for(int r=0;r<4;r++){
          int m = fr*16 + lk*4 + r;
          int n = n0 + fn*16 + lr;
          if(m<MF && n<NSEQ) lmax = fmaxf(lmax, xa[r]);
        }
      }
    }
  }
  float bm = blockMax256(lmax, red);
  if(t==0) atomicMax(kmax, fenc(bm));
}

// ---------------- kside pass1: one block per bh. kf -> ctx (MFMA) + ksum (VALU),
// writes ctxT bf16 [80][288]: rows0-63=ctx^T(d,m), row64=ksum, rest zero.
__global__ __launch_bounds__(256) void kside_ctx(
    const float* __restrict__ kbuf, const float* __restrict__ vbuf,
    const short* __restrict__ projbf, const float* __restrict__ diagk,
    const unsigned* __restrict__ kmax, short* __restrict__ ctxT){
  __shared__ short kS[32*72];
  __shared__ short vT[64*40];
  __shared__ short kfS[272*40];
  __shared__ float diagS[32];
  int t=threadIdx.x, l=t&63, w=t>>6, lr=l&15, lk=l>>4;
  int bh=blockIdx.x; int b=bh>>2, h=bh&3;
  float stab = fdec(*kmax);
  f32x4 ctx[17];
  #pragma unroll
  for(int f=0;f<17;f++) ctx[f]=f32x4{0.f,0.f,0.f,0.f};
  float ks0=0.f, ks1=0.f;
  int nf = (w==3)?5:4;
  short8 apf[5][2];
  for(int fi=0;fi<nf;fi++){
    int fr = (fi<4)? (fi*4+w) : 16;
    #pragma unroll
    for(int ks=0;ks<2;ks++)
      apf[fi][ks] = *reinterpret_cast<const short8*>(projbf + (fr*16+lr)*64 + ks*32 + lk*8);
  }
  for(int ch=0; ch<65; ++ch){
    int n0 = ch*32;
    __syncthreads();
    // stage k (32x64) bf16
    #pragma unroll
    for(int p=0;p<2;p++){
      int r = t>>3, cq = ((t&7)+p*8)*4;
      int gn = n0 + r;
      float4 v={0.f,0.f,0.f,0.f};
      if(gn<NSEQ) v = *reinterpret_cast<const float4*>(kbuf + ((size_t)(b*NSEQ+gn))*DIM + h*DH + cq);
      *reinterpret_cast<short4*>(&kS[r*72+cq]) = make_short4(f2b(v.x),f2b(v.y),f2b(v.z),f2b(v.w));
    }
    // stage v transposed: vT[d][n]
    #pragma unroll
    for(int p=0;p<4;p++){
      int n2 = 2*(t>>6) + 8*p;
      int dd = t&63;
      int gn0=n0+n2, gn1=n0+n2+1;
      float v0 = (gn0<NSEQ)? vbuf[((size_t)(b*NSEQ+gn0))*DIM + h*DH + dd] : 0.f;
      float v1 = (gn1<NSEQ)? vbuf[((size_t)(b*NSEQ+gn1))*DIM + h*DH + dd] : 0.f;
      *reinterpret_cast<short2*>(&vT[dd*40 + n2]) = make_short2(f2b(v0),f2b(v1));
    }
    if(t<32) diagS[t] = (n0+t<NSEQ)? diagk[(size_t)bh*NSEQ + n0+t] : 0.f;
    __syncthreads();
    // xd^T -> kf -> kfS[m][n]
    for(int fi=0;fi<nf;fi++){
      int fr = (fi<4)? (fi*4+w) : 16;
      #pragma unroll
      for(int fn=0;fn<2;fn++){
        f32x4 xa = f32x4{0.f,0.f,0.f,0.f};
        #pragma unroll
        for(int ks=0;ks<2;ks++){
          short8 bk = *reinterpret_cast<const short8*>(&kS[(fn*16+lr)*72 + ks*32 + lk*8]);
          xa = MFMA16(apf[fi][ks], bk, xa);
        }
        float dgn = diagS[fn*16+lr];
        #pragma unroll
        for(int r=0;r<4;r++){
          int m = fr*16 + lk*4 + r;
          int n = n0 + fn*16 + lr;
          float kf = 0.f;
          if(m<MF && n<NSEQ) kf = RATIOC*(expf(xa[r]-dgn-stab)+1e-4f);
          kfS[m*40 + fn*16 + lr] = f2b(kf);
        }
      }
    }
    __syncthreads();
    // ksum accumulation (VALU, persistent regs)
    #pragma unroll 8
    for(int n=0;n<32;n++) ks0 += b2f(kfS[t*40+n]);
    if(t<16){
      for(int n=0;n<32;n++) ks1 += b2f(kfS[(256+t)*40+n]);
    }
    // ctx accum: D[m][d] += kf[m][n] * v[n][d]; wave w owns d-col w*16+lr
    short8 bv = *reinterpret_cast<const short8*>(&vT[(w*16+lr)*40 + lk*8]);
    #pragma unroll
    for(int f=0;f<17;f++){
      short8 a_ = *reinterpret_cast<const short8*>(&kfS[(f*16+lr)*40 + lk*8]);
      ctx[f] = MFMA16(a_, bv, ctx[f]);
    }
  }
  // epilogue -> ctxT
  short* cT = ctxT + (size_t)bh*80*288;
  #pragma unroll
  for(int f=0;f<17;f++)
    #pragma unroll
    for(int r=0;r<4;r++){
      int m = f*16 + lk*4 + r;
      cT[(w*16+lr)*288 + m] = f2b(ctx[f][r]);
    }
  cT[64*288 + t] = f2b(ks0);
  if(t<16){ cT[64*288+256+t] = f2b(ks1); cT[64*288+272+t] = 0; }
  for(int i=t;i<64*16;i+=256){ int dd=i>>4, c=272+(i&15); cT[dd*288+c]=0; }
  for(int i=t;i<15*288;i+=256) cT[65*288+i]=0;
}

// ---------------- qside fused: xd -> rowmax/diag/exp -> PV + denom, all MFMA
__global__ __launch_bounds__(256) void qside_mfma(
    const float* __restrict__ qbuf, const short* __restrict__ projbf,
    const short* __restrict__ ctxT, float* __restrict__ outb){
  __shared__ short qS[64*72];
  __shared__ short qfS[64*296];
  __shared__ float diagS[64];
  int t=threadIdx.x, l=t&63, w=t>>6, lr=l&15, lk=l>>4;
  int n0 = blockIdx.x*64, bh = blockIdx.y;
  int b = bh>>2, h = bh&3;
  // stage q (64x64) + diag + zero qfS pad cols
  {
    int r = t>>2, cq = (t&3)*16;
    int gn = n0 + r;
    float ssq = 0.f;
    #pragma unroll
    for(int i=0;i<4;i++){
      float4 v={0.f,0.f,0.f,0.f};
      if(gn<NSEQ) v = *reinterpret_cast<const float4*>(qbuf + ((size_t)(b*NSEQ+gn))*DIM + h*DH + cq + i*4);
      ssq += v.x*v.x+v.y*v.y+v.z*v.z+v.w*v.w;
      *reinterpret_cast<short4*>(&qS[r*72+cq+i*4]) = make_short4(f2b(v.x),f2b(v.y),f2b(v.z),f2b(v.w));
    }
    ssq += __shfl_xor(ssq,1); ssq += __shfl_xor(ssq,2);
    if((t&3)==0) diagS[r] = 0.0625f*ssq;
    #pragma unroll
    for(int i=0;i<4;i++) qfS[r*296 + 272 + (t&3)*4 + i] = 0;
  }
  __syncthreads();
  // xd = q @ projn^T : wave w owns q-rows [w*16, w*16+16)
  short8 aq[2];
  #pragma unroll
  for(int ks=0;ks<2;ks++) aq[ks] = *reinterpret_cast<const short8*>(&qS[(w*16+lr)*72 + ks*32 + lk*8]);
  f32x4 acc[17];
  #pragma unroll
  for(int f=0;f<17;f++) acc[f]=f32x4{0.f,0.f,0.f,0.f};
  #pragma unroll
  for(int f=0;f<17;f++){
    #pragma unroll
    for(int ks=0;ks<2;ks++){
      short8 bp = *reinterpret_cast<const short8*>(projbf + (f*16+lr)*64 + ks*32 + lk*8);
      acc[f] = MFMA16(aq[ks], bp, acc[f]);
    }
  }
  // rowmax (mask pad cols), diag, exp -> qfS
  float rmax[4];
  #pragma unroll
  for(int r=0;r<4;r++){
    float m = -3.0e38f;
    #pragma unroll
    for(int f=0;f<17;f++){
      float v = (f==16 && lr>=10)? -3.0e38f : acc[f][r];
      m = fmaxf(m,v);
    }
    m = fmaxf(m,__shfl_xor(m,1)); m = fmaxf(m,__shfl_xor(m,2));
    m = fmaxf(m,__shfl_xor(m,4)); m = fmaxf(m,__shfl_xor(m,8));
    rmax[r]=m;
  }
  float dg[4];
  #pragma unroll
  for(int r=0;r<4;r++) dg[r] = diagS[w*16 + lk*4 + r];
  #pragma unroll
  for(int f=0;f<17;f++)
    #pragma unroll
    for(int r=0;r<4;r++){
      float qv = RATIOC*(expf(acc[f][r] - dg[r] - rmax[r]) + 1e-4f);
      qfS[(w*16+lk*4+r)*296 + f*16 + lr] = f2b(qv);
    }
  __syncthreads();
  // PV: out[64 x 80] = qf[64 x 288] @ ctxT^T ; col 64 = denominator
  f32x4 pv[5];
  #pragma unroll
  for(int f=0;f<5;f++) pv[f]=f32x4{0.f,0.f,0.f,0.f};
  const short* cT = ctxT + (size_t)bh*80*288;
  for(int ks=0;ks<9;ks++){
    short8 a_ = *reinterpret_cast<const short8*>(&qfS[(w*16+lr)*296 + ks*32 + lk*8]);
    #pragma unroll
    for(int f=0;f<5;f++){
      short8 bb = *reinterpret_cast<const short8*>(cT + (f*16+lr)*288 + ks*32 + lk*8);
      pv[f] = MFMA16(a_, bb, pv[f]);
    }
  }
  #pragma unroll
  for(int r=0;r<4;r++){
    int gn = n0 + w*16 + lk*4 + r;
    if(gn>=NSEQ) continue;
    float den = __shfl(pv[4][r], (l & 48), 64);   // lane lr==0 holds col 64
    float inv = 1.0f/den;
    size_t obase = ((size_t)(b*NSEQ+gn))*DIM + h*DH;
    #pragma unroll
    for(int f=0;f<4;f++) outb[obase + f*16 + lr] = pv[f][r]*inv;
  }
}

// ---------------- small row projection
__global__ __launch_bounds__(256) void rowproj_kernel(const float* __restrict__ src,
    const float* __restrict__ W, const float* __restrict__ bias,
    float* __restrict__ dst, int rowstride){
  __shared__ float rs[DIM];
  int b=blockIdx.x, t=threadIdx.x;
  rs[t]=src[(size_t)b*rowstride+t];
  __syncthreads();
  float s=bias[t];
  for(int j=0;j<DIM;j++) s += rs[j]*W[(size_t)j*DIM+t];
  dst[(size_t)b*DIM+t]=s;
}

// ---------------- final pooling attention
__global__ __launch_bounds__(256) void attnpool_kernel(const float* __restrict__ qfin,
    const float* __restrict__ kk, const float* __restrict__ vv, float* __restrict__ pooled){
  __shared__ float qsh[DIM];
  __shared__ float sc[KG];
  __shared__ float red[4];
  int b=blockIdx.x, t=threadIdx.x;
  qsh[t]=qfin[b*DIM+t];
  __syncthreads();
  float ls[8]; float lmax=-3.4e38f;
  #pragma unroll
  for(int i=0;i<8;i++){
    int kidx=t+i*256;
    const float* kr = kk + ((size_t)(b*NSEQ+1+kidx))*DIM;
    float s=0;
    for(int j=0;j<DIM;j++) s += qsh[j]*kr[j];
    s *= 0.0625f;
    ls[i]=s; lmax=fmaxf(lmax,s);
  }
  float gmax=blockMax256(lmax,red);
  float lsum=0;
  #pragma unroll
  for(int i=0;i<8;i++){ float e=expf(ls[i]-gmax); sc[t+i*256]=e; lsum+=e; }
  float gsum=blockSum256(lsum,red);
  __syncthreads();
  float inv=1.0f/gsum;
  float p=0;
  for(int kidx=0;kidx<KG;kidx++) p += sc[kidx]*vv[((size_t)(b*NSEQ+1+kidx))*DIM + t];
  pooled[b*DIM+t]=p*inv;
}

extern "C" void kernel_launch(void* const* d_in, const int* in_sizes, int n_in,
                              void* d_out, int out_size, void* d_ws, size_t ws_size,
                              hipStream_t stream){
  const float* expr   =(const float*)d_in[0];
  const float* coords =(const float*)d_in[1];
  const float* gene_emb=(const float*)d_in[2];
  const float* pos_emb=(const float*)d_in[3];
  const float* val_w  =(const float*)d_in[4];
  const float* val_b  =(const float*)d_in[5];
  const float* val_g  =(const float*)d_in[6];
  const float* val_bb =(const float*)d_in[7];
  const float* sp_w   =(const float*)d_in[8];
  const float* sp_b   =(const float*)d_in[9];
  const float* sp_g   =(const float*)d_in[10];
  const float* sp_bb  =(const float*)d_in[11];
  const float* p_ln1_g=(const float*)d_in[12];
  const float* p_ln1_b=(const float*)d_in[13];
  const float* p_wq   =(const float*)d_in[14];
  const float* p_bq   =(const float*)d_in[15];
  const float* p_wk   =(const float*)d_in[16];
  const float* p_bk   =(const float*)d_in[17];
  const float* p_wv   =(const float*)d_in[18];
  const float* p_bv   =(const float*)d_in[19];
  const float* p_wo   =(const float*)d_in[20];
  const float* p_bo   =(const float*)d_in[21];
  const float* p_ln2_g=(const float*)d_in[22];
  const float* p_ln2_b=(const float*)d_in[23];
  const float* p_ff1_w=(const float*)d_in[24];
  const float* p_ff1_b=(const float*)d_in[25];
  const float* p_ff2_w=(const float*)d_in[26];
  const float* p_ff2_b=(const float*)d_in[27];
  const float* proj   =(const float*)d_in[28];
  const float* q_w    =(const float*)d_in[29];
  const float* q_b    =(const float*)d_in[30];
  const float* k_w    =(const float*)d_in[31];
  const float* k_b    =(const float*)d_in[32];
  const float* v_w    =(const float*)d_in[33];
  const float* v_b    =(const float*)d_in[34];
  const float* o_w    =(const float*)d_in[35];
  const float* o_b    =(const float*)d_in[36];
  float* out = (float*)d_out;

  const size_t BND = (size_t)BN*DIM;
  // floats: x | b | c | mu | rstd | diagk | kmax(4) | qfin | pooled | projbf(8704) | ctxT(1474560)
  size_t need = 3*BND + 2*(size_t)BN + (size_t)NB*NH*NSEQ + 4
              + 2*(size_t)NB*DIM + 8704 + 1474560;
  if(ws_size < need*sizeof(float)){
    hipMemsetAsync(d_out, 0, (size_t)out_size*sizeof(float), stream);
    return;
  }
  float* ws = (float*)d_ws;
  float* x  = ws;
  float* b_ = x  + BND;
  float* c_ = b_ + BND;
  float* mu   = c_ + BND;
  float* rstd = mu + BN;
  float* diagk = rstd + BN;
  unsigned* kmax = (unsigned*)(diagk + (size_t)NB*NH*NSEQ);
  float* qfin   = (float*)(kmax+4);
  float* pooled = qfin + NB*DIM;
  short* projbf = (short*)(pooled + NB*DIM);
  short* ctxT   = projbf + 17408;   // 272*64

  embed_kernel<<<BN,256,0,stream>>>(expr,coords,gene_emb,pos_emb,val_w,val_b,val_g,val_bb,
                                    sp_w,sp_b,sp_g,sp_bb,x);

  dim3 g256(DIM/64, (BN+127)/128);
  dim3 gff1(FFD/64, (FFROWS+127)/128);
  dim3 gff2(DIM/64, (FFROWS+127)/128);
  dim3 gkm(4, NB*NH);
  dim3 gq((NSEQ+63)/64, NB*NH);

  for(int l=0;l<2;l++){
    const float* prj = proj + (size_t)l*MF*DH;
    const float* g1 = p_ln1_g+l*DIM, *bb1 = p_ln1_b+l*DIM;
    const float* g2 = p_ln2_g+l*DIM, *bb2 = p_ln2_b+l*DIM;
    ln_stats_kernel<<<BN,256,0,stream>>>(x, mu, rstd);
    mgemm<0,1><<<g256,256,0,stream>>>(x, p_wk+(size_t)l*DIM*DIM, p_bk+l*DIM, c_, mu,rstd,g1,bb1, BN, DIM, DIM);
    mgemm<0,1><<<g256,256,0,stream>>>(x, p_wv+(size_t)l*DIM*DIM, p_bv+l*DIM, b_, mu,rstd,g1,bb1, BN, DIM, DIM);
    diagk_kernel<<<BN,256,0,stream>>>(c_, diagk);
    kmax_init_kernel<<<1,1,0,stream>>>(kmax);
    projprep_kernel<<<68,256,0,stream>>>(prj, projbf);
    kside_max<<<gkm,256,0,stream>>>(c_, projbf, kmax);
    kside_ctx<<<NB*NH,256,0,stream>>>(c_, b_, projbf, diagk, kmax, ctxT);
    mgemm<0,1><<<g256,256,0,stream>>>(x, p_wq+(size_t)l*DIM*DIM, p_bq+l*DIM, b_, mu,rstd,g1,bb1, BN, DIM, DIM);
    qside_mfma<<<gq,256,0,stream>>>(b_, projbf, ctxT, b_);
    mgemm<1,0><<<g256,256,0,stream>>>(b_, p_wo+(size_t)l*DIM*DIM, p_bo+l*DIM, x, nullptr,nullptr,nullptr,nullptr, BN, DIM, DIM);
    ln_stats_kernel<<<BN,256,0,stream>>>(x, mu, rstd);
    for(int c4=0;c4<4;c4++){
      size_t roff=(size_t)c4*FFROWS;
      mgemm<2,1><<<gff1,256,0,stream>>>(x+roff*DIM, p_ff1_w+(size_t)l*DIM*FFD, p_ff1_b+l*FFD, c_,
                                        mu+roff, rstd+roff, g2, bb2, FFROWS, FFD, DIM);
      mgemm<1,0><<<gff2,256,0,stream>>>(c_, p_ff2_w+(size_t)l*FFD*DIM, p_ff2_b+l*DIM, x+roff*DIM,
                                        nullptr,nullptr,nullptr,nullptr, FFROWS, DIM, FFD);
    }
  }

  mgemm<0,0><<<g256,256,0,stream>>>(x, k_w, k_b, b_, nullptr,nullptr,nullptr,nullptr, BN, DIM, DIM);
  mgemm<0,0><<<g256,256,0,stream>>>(x, v_w, v_b, c_, nullptr,nullptr,nullptr,nullptr, BN, DIM, DIM);
  rowproj_kernel<<<NB,256,0,stream>>>(x, q_w, q_b, qfin, NSEQ*DIM);
  attnpool_kernel<<<NB,256,0,stream>>>(qfin, b_, c_, pooled);
  rowproj_kernel<<<NB,256,0,stream>>>(pooled, o_w, o_b, out, DIM);
}

// Round 5
// 2372.576 us; speedup vs baseline: 6.7042x; 1.5002x over previous
//
#include <hip/hip_runtime.h>
#include <hip/hip_bf16.h>
#include <math.h>

#define NB   32
#define KG   2048
#define NSEQ 2049
#define DIM  256
#define NH   4
#define DH   64
#define MF   266
#define FFD  1024
#define BN   (NB*NSEQ)          // 65568
#define FFROWS 16392            // BN/4
#define NORMC 0.35355339059327376f   // 64^-0.25
#define RATIOC (1.0f/16.309506430300091f) // 266^-0.5

typedef __attribute__((ext_vector_type(8))) short short8;
typedef __attribute__((ext_vector_type(4))) float f32x4;
#define MFMA16(a,b,c) __builtin_amdgcn_mfma_f32_16x16x32_bf16(a,b,c,0,0,0)

__device__ __forceinline__ short f2b(float f){
  union{ __hip_bfloat16 h; short s;} u; u.h = __float2bfloat16(f); return u.s;
}
__device__ __forceinline__ float b2f(short s){
  union{ short s; __hip_bfloat16 h;} u; u.s = s; return __bfloat162float(u.h);
}
__device__ __forceinline__ float gelu_f(float x){
  return 0.5f*x*(1.0f+erff(x*0.70710678118654752f));
}
__device__ __forceinline__ float waveSum(float v){
  #pragma unroll
  for(int o=32;o>0;o>>=1) v += __shfl_down(v,o);
  return v;
}
__device__ __forceinline__ float waveMax(float v){
  #pragma unroll
  for(int o=32;o>0;o>>=1) v = fmaxf(v,__shfl_down(v,o));
  return v;
}
__device__ __forceinline__ float blockSum256(float v, float* red){
  int lane = threadIdx.x & 63, wid = threadIdx.x >> 6;
  v = waveSum(v);
  __syncthreads();
  if(lane==0) red[wid]=v;
  __syncthreads();
  return red[0]+red[1]+red[2]+red[3];
}
__device__ __forceinline__ float blockMax256(float v, float* red){
  int lane = threadIdx.x & 63, wid = threadIdx.x >> 6;
  v = waveMax(v);
  __syncthreads();
  if(lane==0) red[wid]=v;
  __syncthreads();
  return fmaxf(fmaxf(red[0],red[1]),fmaxf(red[2],red[3]));
}
__device__ __forceinline__ unsigned fenc(float f){
  unsigned u = __float_as_uint(f);
  return (u & 0x80000000u) ? ~u : (u | 0x80000000u);
}
__device__ __forceinline__ float fdec(unsigned u){
  return (u & 0x80000000u) ? __uint_as_float(u & 0x7FFFFFFFu) : __uint_as_float(~u);
}

// ---------------- embed
__global__ __launch_bounds__(256) void embed_kernel(
    const float* __restrict__ expr, const float* __restrict__ coords,
    const float* __restrict__ gene_emb, const float* __restrict__ pos_emb,
    const float* __restrict__ val_w, const float* __restrict__ val_b,
    const float* __restrict__ val_g, const float* __restrict__ val_bb,
    const float* __restrict__ sp_w, const float* __restrict__ sp_b,
    const float* __restrict__ sp_g, const float* __restrict__ sp_bb,
    float* __restrict__ x){
  __shared__ float red[4];
  int row = blockIdx.x; int b = row / NSEQ, n = row % NSEQ;
  int d = threadIdx.x;
  float v;
  if(n==0) v = coords[b*2]*sp_w[d] + coords[b*2+1]*sp_w[DIM+d] + sp_b[d];
  else     v = expr[(size_t)b*KG + (n-1)]*val_w[d] + val_b[d];
  float mu = blockSum256(v, red)*(1.0f/DIM);
  float c  = v - mu;
  float var = blockSum256(c*c, red)*(1.0f/DIM);
  float r = rsqrtf(var + 1e-5f);
  float g  = (n==0)? sp_g[d]  : val_g[d];
  float be = (n==0)? sp_bb[d] : val_bb[d];
  float h = gelu_f(c*r*g + be);
  float o = (n==0)? h : (gene_emb[(size_t)(n-1)*DIM+d]+pos_emb[(size_t)(n-1)*DIM+d]+h);
  x[(size_t)row*DIM + d] = o;
}

// ---------------- fused LN -> bf16
__global__ __launch_bounds__(256) void ln_bf(const float* __restrict__ xin,
    const float* __restrict__ g, const float* __restrict__ bb, short* __restrict__ ybf){
  __shared__ float red[4];
  int row = blockIdx.x; int d = threadIdx.x;
  float v = xin[(size_t)row*DIM+d];
  float m = blockSum256(v,red)*(1.0f/DIM);
  float c = v-m;
  float var = blockSum256(c*c,red)*(1.0f/DIM);
  float r = rsqrtf(var+1e-5f);
  ybf[(size_t)row*DIM+d] = f2b(c*r*g[d]+bb[d]);
}

// ---------------- fp32 -> bf16 cast (n divisible by 1024)
__global__ __launch_bounds__(256) void castbf(const float* __restrict__ in, short* __restrict__ out){
  size_t i = ((size_t)blockIdx.x*256 + threadIdx.x)*4;
  float4 v = *reinterpret_cast<const float4*>(in+i);
  *reinterpret_cast<short4*>(out+i) = make_short4(f2b(v.x),f2b(v.y),f2b(v.z),f2b(v.w));
}

// ---------------- weight prep: W[k][n] fp32 -> WT[n][k] bf16
__global__ __launch_bounds__(256) void wprep(const float* __restrict__ W, short* __restrict__ out,
                                             int K, int N){
  int i = blockIdx.x*256 + threadIdx.x;
  if(i < K*N){ int k = i/N, n = i - k*N; out[(size_t)n*K + k] = f2b(W[i]); }
}

// ---------------- MFMA GEMM v2: bf16 A [M][Kd], bf16 Bt [N][Kd], fp32 bias
// tile 128x128x32, 4 waves (2m x 2n), wave = 64x64 (4x4 frags)
// EPI: 0=none 1=fp32 residual add 2=gelu ; OBF: 1 -> bf16 out, 0 -> fp32 out
template<int EPI, int OBF>
__global__ __launch_bounds__(256) void mgemm2(
    const short* __restrict__ A, const short* __restrict__ Bt,
    const float* __restrict__ bias, void* __restrict__ Cv,
    int M, int N, int Kd){
  __shared__ short As[128*40];
  __shared__ short Bs[128*40];
  int t=threadIdx.x, l=t&63, w=t>>6, lr=l&15, lk=l>>4;
  int wm=w>>1, wn=w&1;
  int m0=blockIdx.y*128, n0=blockIdx.x*128;
  f32x4 acc[4][4];
  #pragma unroll
  for(int i=0;i<4;i++)
    #pragma unroll
    for(int j=0;j<4;j++) acc[i][j]=f32x4{0.f,0.f,0.f,0.f};
  const short8 z8 = {0,0,0,0,0,0,0,0};
  for(int k0=0;k0<Kd;k0+=32){
    #pragma unroll
    for(int p=0;p<2;p++){
      int idx=t+p*256; int r=idx>>2, q8=idx&3;
      int gm=m0+r;
      short8 v8 = z8;
      if(gm<M) v8 = *reinterpret_cast<const short8*>(A + (size_t)gm*Kd + k0 + q8*8);
      *reinterpret_cast<short8*>(&As[r*40+q8*8]) = v8;
    }
    #pragma unroll
    for(int p=0;p<2;p++){
      int idx=t+p*256; int r=idx>>2, q8=idx&3;
      short8 v8 = *reinterpret_cast<const short8*>(Bt + (size_t)(n0+r)*Kd + k0 + q8*8);
      *reinterpret_cast<short8*>(&Bs[r*40+q8*8]) = v8;
    }
    __syncthreads();
    short8 af[4], bfr[4];
    #pragma unroll
    for(int i=0;i<4;i++) af[i] = *reinterpret_cast<const short8*>(&As[(wm*64+i*16+lr)*40 + lk*8]);
    #pragma unroll
    for(int j=0;j<4;j++) bfr[j] = *reinterpret_cast<const short8*>(&Bs[(wn*64+j*16+lr)*40 + lk*8]);
    #pragma unroll
    for(int i=0;i<4;i++)
      #pragma unroll
      for(int j=0;j<4;j++) acc[i][j] = MFMA16(af[i], bfr[j], acc[i][j]);
    __syncthreads();
  }
  #pragma unroll
  for(int i=0;i<4;i++){
    int gm0 = m0 + wm*64 + i*16 + lk*4;
    #pragma unroll
    for(int j=0;j<4;j++){
      int gc = n0 + wn*64 + j*16 + lr;
      float bs = bias[gc];
      #pragma unroll
      for(int r=0;r<4;r++){
        int gm = gm0 + r;
        if(gm<M){
          float vv = acc[i][j][r] + bs;
          if(EPI==2) vv = gelu_f(vv);
          size_t idx = (size_t)gm*N + gc;
          if(OBF){
            ((short*)Cv)[idx] = f2b(vv);
          } else {
            float* C = (float*)Cv;
            if(EPI==1) vv += C[idx];
            C[idx] = vv;
          }
        }
      }
    }
  }
}

// ---------------- projbf: bf16(proj * NORMC), 320 rows (pad zero)
__global__ __launch_bounds__(256) void projprep_kernel(const float* __restrict__ proj, short* __restrict__ projbf){
  int i = blockIdx.x*256 + threadIdx.x;
  if(i < 320*64){
    int m = i>>6, d = i&63;
    float v = (m<MF)? proj[(size_t)m*DH + d]*NORMC : 0.f;
    projbf[i] = f2b(v);
  }
}

// ---------------- diag_k from bf16 k
__global__ __launch_bounds__(256) void diagk_kernel(const short* __restrict__ kbf, float* __restrict__ diagk){
  int row = blockIdx.x; int b=row/NSEQ, n=row%NSEQ;
  int t=threadIdx.x; int h=t>>6;
  float v = b2f(kbf[(size_t)row*DIM + t]);
  float s = waveSum(v*v);
  if((t&63)==0) diagk[((size_t)(b*NH+h))*NSEQ + n] = 0.0625f*s;
}

__global__ void kmax_init_kernel(unsigned* km){ *km = 0u; }

// ---------------- zero ctxT pad regions (rows 64-79 full, cols 272-287 of d-rows)
__global__ __launch_bounds__(256) void ctx_zero(short* __restrict__ ctxT){
  int bh=blockIdx.x, t=threadIdx.x;
  short* cT = ctxT + (size_t)bh*80*288;
  for(int i=t;i<16*288;i+=256) cT[64*288+i]=0;
  for(int i=t;i<64*16;i+=256){ int d=i>>4, c=i&15; cT[d*288+272+c]=0; }
}

// ---------------- kside pass0: global max of xd_k (bf16 k)
__global__ __launch_bounds__(256) void kside_max(
    const short* __restrict__ kbf, const short* __restrict__ projbf,
    unsigned* __restrict__ kmax){
  __shared__ short kS[32*72];
  __shared__ float red[4];
  int t=threadIdx.x, l=t&63, w=t>>6, lr=l&15, lk=l>>4;
  int split = blockIdx.x, bh = blockIdx.y;
  int b=bh>>2, h=bh&3;
  int c0 = split*17, c1 = min(c0+17, 65);
  int nf = (w==3)?5:4;
  short8 apf[5][2];
  #pragma unroll
  for(int fi=0;fi<5;fi++){
    int fr = (fi<4)? (fi*4+w) : 16;
    #pragma unroll
    for(int ks=0;ks<2;ks++)
      apf[fi][ks] = *reinterpret_cast<const short8*>(projbf + (fr*16+lr)*64 + ks*32 + lk*8);
  }
  const short8 z8 = {0,0,0,0,0,0,0,0};
  float lmax = -3.0e38f;
  for(int ch=c0; ch<c1; ++ch){
    int n0 = ch*32;
    __syncthreads();
    {
      int r = t>>3, c8 = (t&7)*8;
      int gn = n0 + r;
      short8 v8 = z8;
      if(gn<NSEQ) v8 = *reinterpret_cast<const short8*>(kbf + ((size_t)(b*NSEQ+gn))*DIM + h*DH + c8);
      *reinterpret_cast<short8*>(&kS[r*72+c8]) = v8;
    }
    __syncthreads();
    for(int fi=0;fi<nf;fi++){
      int fr = (fi<4)? (fi*4+w) : 16;
      #pragma unroll
      for(int fn=0;fn<2;fn++){
        f32x4 xa = f32x4{0.f,0.f,0.f,0.f};
        #pragma unroll
        for(int ks=0;ks<2;ks++){
          short8 bk = *reinterpret_cast<const short8*>(&kS[(fn*16+lr)*72 + ks*32 + lk*8]);
          xa = MFMA16(apf[fi][ks], bk, xa);
        }
        #pragma unroll
        for(int r=0;r<4;r++){
          int m = fr*16 + lk*4 + r;
          int n = n0 + fn*16 + lr;
          if(m<MF && n<NSEQ) lmax = fmaxf(lmax, xa[r]);
        }
      }
    }
  }
  float bm = blockMax256(lmax, red);
  if(t==0) atomicMax(kmax, fenc(bm));
}

// ---------------- kside pass1 v3: f-split grid (4, bh). Block bfb owns f-groups
// F0=bfb*5 .. F0+4 (groups >=17 fully masked). No breaks, no conditional loads,
// every fragment initialized. ksum via MFMA(B=ones), write-side guards only.
__global__ __launch_bounds__(256) void kside_ctx(
    const short* __restrict__ kbf, const short* __restrict__ vbf,
    const short* __restrict__ projbf, const float* __restrict__ diagk,
    const unsigned* __restrict__ kmax, short* __restrict__ ctxT){
  __shared__ short kS[32*72];
  __shared__ short vT[64*40];
  __shared__ short kfS[80*40];
  __shared__ float diagS[32];
  int t=threadIdx.x, l=t&63, w=t>>6, lr=l&15, lk=l>>4;
  int bfb=blockIdx.x, bh=blockIdx.y; int b=bh>>2, h=bh&3;
  int F0 = bfb*5;                       // groups F0..F0+4
  float stab = fdec(*kmax);
  // A-fragments: unconditional, always in-bounds (projbf has 320 rows)
  short8 apf0[2], apf1[2];
  #pragma unroll
  for(int ks=0;ks<2;ks++){
    apf0[ks] = *reinterpret_cast<const short8*>(projbf + ((F0+w)*16+lr)*64 + ks*32 + lk*8);
    apf1[ks] = *reinterpret_cast<const short8*>(projbf + ((F0+4)*16+lr)*64 + ks*32 + lk*8);
  }
  f32x4 ctx[5];
  #pragma unroll
  for(int f=0;f<5;f++) ctx[f]=f32x4{0.f,0.f,0.f,0.f};
  f32x4 ksc0 = f32x4{0.f,0.f,0.f,0.f};
  f32x4 ksc1 = f32x4{0.f,0.f,0.f,0.f};
  const short ONE=(short)0x3F80;
  const short8 ones8 = {ONE,ONE,ONE,ONE,ONE,ONE,ONE,ONE};
  const short8 z8 = {0,0,0,0,0,0,0,0};
  for(int ch=0; ch<65; ++ch){
    int n0 = ch*32;
    __syncthreads();
    // stage k chunk (32n x 64d)
    {
      int r = t>>3, c8 = (t&7)*8;
      int gn = n0 + r;
      short8 v8 = z8;
      if(gn<NSEQ) v8 = *reinterpret_cast<const short8*>(kbf + ((size_t)(b*NSEQ+gn))*DIM + h*DH + c8);
      *reinterpret_cast<short8*>(&kS[r*72+c8]) = v8;
    }
    // stage v transposed vT[d][n]
    #pragma unroll
    for(int p=0;p<4;p++){
      int n2 = 2*w + 8*p;
      int dd = t&63;
      int gn0=n0+n2, gn1=gn0+1;
      short v0 = (gn0<NSEQ)? vbf[((size_t)(b*NSEQ+gn0))*DIM + h*DH + dd] : (short)0;
      short v1 = (gn1<NSEQ)? vbf[((size_t)(b*NSEQ+gn1))*DIM + h*DH + dd] : (short)0;
      *reinterpret_cast<short2*>(&vT[dd*40 + n2]) = make_short2(v0,v1);
    }
    if(t<32) diagS[t] = (n0+t<NSEQ)? diagk[(size_t)bh*NSEQ + n0+t] : 0.f;
    __syncthreads();
    // xd -> kf, group fl=w (all waves)
    #pragma unroll
    for(int fn=0;fn<2;fn++){
      f32x4 xa = f32x4{0.f,0.f,0.f,0.f};
      #pragma unroll
      for(int ks=0;ks<2;ks++){
        short8 bk = *reinterpret_cast<const short8*>(&kS[(fn*16+lr)*72 + ks*32 + lk*8]);
        xa = MFMA16(apf0[ks], bk, xa);
      }
      float dgn = diagS[fn*16+lr];
      #pragma unroll
      for(int r=0;r<4;r++){
        int m = (F0+w)*16 + lk*4 + r;
        int n = n0 + fn*16 + lr;
        float kf = (m<MF && n<NSEQ)? RATIOC*(expf(xa[r]-dgn-stab)+1e-4f) : 0.f;
        kfS[(w*16+lk*4+r)*40 + fn*16 + lr] = f2b(kf);
      }
    }
    // xd -> kf, group fl=4 (wave 0 writes rows 64..79)
    if(w==0){
      #pragma unroll
      for(int fn=0;fn<2;fn++){
        f32x4 xa = f32x4{0.f,0.f,0.f,0.f};
        #pragma unroll
        for(int ks=0;ks<2;ks++){
          short8 bk = *reinterpret_cast<const short8*>(&kS[(fn*16+lr)*72 + ks*32 + lk*8]);
          xa = MFMA16(apf1[ks], bk, xa);
        }
        float dgn = diagS[fn*16+lr];
        #pragma unroll
        for(int r=0;r<4;r++){
          int m = (F0+4)*16 + lk*4 + r;
          int n = n0 + fn*16 + lr;
          float kf = (m<MF && n<NSEQ)? RATIOC*(expf(xa[r]-dgn-stab)+1e-4f) : 0.f;
          kfS[(64+lk*4+r)*40 + fn*16 + lr] = f2b(kf);
        }
      }
    }
    __syncthreads();
    // ctx + ksum accumulation (unconditional MFMAs)
    short8 bv = *reinterpret_cast<const short8*>(&vT[(w*16+lr)*40 + lk*8]);
    short8 a0 = *reinterpret_cast<const short8*>(&kfS[(w*16+lr)*40 + lk*8]);
    short8 a4 = *reinterpret_cast<const short8*>(&kfS[(64+lr)*40 + lk*8]);
    ksc0 = MFMA16(a0, ones8, ksc0);
    ksc1 = MFMA16(a4, ones8, ksc1);
    #pragma unroll
    for(int fl=0;fl<5;fl++){
      short8 a_ = *reinterpret_cast<const short8*>(&kfS[(fl*16+lr)*40 + lk*8]);
      ctx[fl] = MFMA16(a_, bv, ctx[fl]);
    }
  }
  // epilogue (write-side guards)
  short* cT = ctxT + (size_t)bh*80*288;
  #pragma unroll
  for(int fl=0;fl<5;fl++){
    #pragma unroll
    for(int r=0;r<4;r++){
      int m = (F0+fl)*16 + lk*4 + r;
      if(m<272) cT[(w*16+lr)*288 + m] = f2b(ctx[fl][r]);
    }
  }
  if(lr==0){
    #pragma unroll
    for(int r=0;r<4;r++){
      int m = (F0+w)*16 + lk*4 + r;
      if(m<272) cT[64*288 + m] = f2b(ksc0[r]);
    }
    if(w==0){
      #pragma unroll
      for(int r=0;r<4;r++){
        int m = (F0+4)*16 + lk*4 + r;
        if(m<272) cT[64*288 + m] = f2b(ksc1[r]);
      }
    }
  }
}

// ---------------- qside fused (bf16 q in, bf16 o out)
__global__ __launch_bounds__(256) void qside_mfma(
    const short* __restrict__ qbf, const short* __restrict__ projbf,
    const short* __restrict__ ctxT, short* __restrict__ obf){
  __shared__ short qS[64*72];
  __shared__ short qfS[64*296];
  __shared__ float diagS[64];
  int t=threadIdx.x, l=t&63, w=t>>6, lr=l&15, lk=l>>4;
  int n0 = blockIdx.x*64, bh = blockIdx.y;
  int b = bh>>2, h = bh&3;
  const short8 z8 = {0,0,0,0,0,0,0,0};
  // stage q (64x64 bf16) + diag + zero qfS pad cols
  {
    int r = t>>2, c8 = (t&3)*16;
    int gn = n0 + r;
    float ssq = 0.f;
    #pragma unroll
    for(int i=0;i<2;i++){
      short8 v8 = z8;
      if(gn<NSEQ) v8 = *reinterpret_cast<const short8*>(qbf + ((size_t)(b*NSEQ+gn))*DIM + h*DH + c8 + i*8);
      #pragma unroll
      for(int u=0;u<8;u++){ float fv=b2f(v8[u]); ssq += fv*fv; }
      *reinterpret_cast<short8*>(&qS[r*72+c8+i*8]) = v8;
    }
    ssq += __shfl_xor(ssq,1); ssq += __shfl_xor(ssq,2);
    if((t&3)==0) diagS[r] = 0.0625f*ssq;
    #pragma unroll
    for(int i=0;i<4;i++) qfS[r*296 + 272 + (t&3)*4 + i] = 0;
  }
  __syncthreads();
  // xd = q @ projn^T : wave w owns q-rows [w*16, w*16+16)
  short8 aq[2];
  #pragma unroll
  for(int ks=0;ks<2;ks++) aq[ks] = *reinterpret_cast<const short8*>(&qS[(w*16+lr)*72 + ks*32 + lk*8]);
  f32x4 acc[17];
  #pragma unroll
  for(int f=0;f<17;f++) acc[f]=f32x4{0.f,0.f,0.f,0.f};
  #pragma unroll
  for(int f=0;f<17;f++){
    #pragma unroll
    for(int ks=0;ks<2;ks++){
      short8 bp = *reinterpret_cast<const short8*>(projbf + (f*16+lr)*64 + ks*32 + lk*8);
      acc[f] = MFMA16(aq[ks], bp, acc[f]);
    }
  }
  // rowmax (mask pad), diag, exp -> qfS
  float rmax[4];
  #pragma unroll
  for(int r=0;r<4;r++){
    float m = -3.0e38f;
    #pragma unroll
    for(int f=0;f<17;f++){
      float v = (f==16 && lr>=10)? -3.0e38f : acc[f][r];
      m = fmaxf(m,v);
    }
    m = fmaxf(m,__shfl_xor(m,1)); m = fmaxf(m,__shfl_xor(m,2));
    m = fmaxf(m,__shfl_xor(m,4)); m = fmaxf(m,__shfl_xor(m,8));
    rmax[r]=m;
  }
  float dg[4];
  #pragma unroll
  for(int r=0;r<4;r++) dg[r] = diagS[w*16 + lk*4 + r];
  #pragma unroll
  for(int f=0;f<17;f++)
    #pragma unroll
    for(int r=0;r<4;r++){
      float qv = RATIOC*(expf(acc[f][r] - dg[r] - rmax[r]) + 1e-4f);
      qfS[(w*16+lk*4+r)*296 + f*16 + lr] = f2b(qv);
    }
  __syncthreads();
  // PV: out[64 x 80] = qf[64 x 288] @ ctxT^T ; col 64 = denominator
  f32x4 pv[5];
  #pragma unroll
  for(int f=0;f<5;f++) pv[f]=f32x4{0.f,0.f,0.f,0.f};
  const short* cT = ctxT + (size_t)bh*80*288;
  for(int ks=0;ks<9;ks++){
    short8 a_ = *reinterpret_cast<const short8*>(&qfS[(w*16+lr)*296 + ks*32 + lk*8]);
    #pragma unroll
    for(int f=0;f<5;f++){
      short8 bb = *reinterpret_cast<const short8*>(cT + (f*16+lr)*288 + ks*32 + lk*8);
      pv[f] = MFMA16(a_, bb, pv[f]);
    }
  }
  #pragma unroll
  for(int r=0;r<4;r++){
    int gn = n0 + w*16 + lk*4 + r;
    if(gn>=NSEQ) continue;
    float den = __shfl(pv[4][r], (l & 48), 64);   // lane lr==0 holds col 64
    float inv = 1.0f/den;
    size_t obase = ((size_t)(b*NSEQ+gn))*DIM + h*DH;
    #pragma unroll
    for(int f=0;f<4;f++) obf[obase + f*16 + lr] = f2b(pv[f][r]*inv);
  }
}

// ---------------- small row projection (fp32)
__global__ __launch_bounds__(256) void rowproj_kernel(const float* __restrict__ src,
    const float* __restrict__ W, const float* __restrict__ bias,
    float* __restrict__ dst, int rowstride){
  __shared__ float rs[DIM];
  int b=blockIdx.x, t=threadIdx.x;
  rs[t]=src[(size_t)b*rowstride+t];
  __syncthreads();
  float s=bias[t];
  for(int j=0;j<DIM;j++) s += rs[j]*W[(size_t)j*DIM+t];
  dst[(size_t)b*DIM+t]=s;
}

// ---------------- final pooling attention (bf16 kk/vv)
__global__ __launch_bounds__(256) void attnpool_kernel(const float* __restrict__ qfin,
    const short* __restrict__ kk, const short* __restrict__ vv, float* __restrict__ pooled){
  __shared__ float qsh[DIM];
  __shared__ float sc[KG];
  __shared__ float red[4];
  int b=blockIdx.x, t=threadIdx.x;
  qsh[t]=qfin[b*DIM+t];
  __syncthreads();
  float ls[8]; float lmax=-3.4e38f;
  #pragma unroll
  for(int i=0;i<8;i++){
    int kidx=t+i*256;
    const short* kr = kk + ((size_t)(b*NSEQ+1+kidx))*DIM;
    float s=0;
    for(int j8=0;j8<32;j8++){
      short8 kv = *reinterpret_cast<const short8*>(kr + j8*8);
      #pragma unroll
      for(int u=0;u<8;u++) s += qsh[j8*8+u]*b2f(kv[u]);
    }
    s *= 0.0625f;
    ls[i]=s; lmax=fmaxf(lmax,s);
  }
  float gmax=blockMax256(lmax,red);
  float lsum=0;
  #pragma unroll
  for(int i=0;i<8;i++){ float e=expf(ls[i]-gmax); sc[t+i*256]=e; lsum+=e; }
  float gsum=blockSum256(lsum,red);
  __syncthreads();
  float inv=1.0f/gsum;
  float p=0;
  for(int kidx=0;kidx<KG;kidx++) p += sc[kidx]*b2f(vv[((size_t)(b*NSEQ+1+kidx))*DIM + t]);
  pooled[b*DIM+t]=p*inv;
}

extern "C" void kernel_launch(void* const* d_in, const int* in_sizes, int n_in,
                              void* d_out, int out_size, void* d_ws, size_t ws_size,
                              hipStream_t stream){
  const float* expr   =(const float*)d_in[0];
  const float* coords =(const float*)d_in[1];
  const float* gene_emb=(const float*)d_in[2];
  const float* pos_emb=(const float*)d_in[3];
  const float* val_w  =(const float*)d_in[4];
  const float* val_b  =(const float*)d_in[5];
  const float* val_g  =(const float*)d_in[6];
  const float* val_bb =(const float*)d_in[7];
  const float* sp_w   =(const float*)d_in[8];
  const float* sp_b   =(const float*)d_in[9];
  const float* sp_g   =(const float*)d_in[10];
  const float* sp_bb  =(const float*)d_in[11];
  const float* p_ln1_g=(const float*)d_in[12];
  const float* p_ln1_b=(const float*)d_in[13];
  const float* p_wq   =(const float*)d_in[14];
  const float* p_bq   =(const float*)d_in[15];
  const float* p_wk   =(const float*)d_in[16];
  const float* p_bk   =(const float*)d_in[17];
  const float* p_wv   =(const float*)d_in[18];
  const float* p_bv   =(const float*)d_in[19];
  const float* p_wo   =(const float*)d_in[20];
  const float* p_bo   =(const float*)d_in[21];
  const float* p_ln2_g=(const float*)d_in[22];
  const float* p_ln2_b=(const float*)d_in[23];
  const float* p_ff1_w=(const float*)d_in[24];
  const float* p_ff1_b=(const float*)d_in[25];
  const float* p_ff2_w=(const float*)d_in[26];
  const float* p_ff2_b=(const float*)d_in[27];
  const float* proj   =(const float*)d_in[28];
  const float* q_w    =(const float*)d_in[29];
  const float* q_b    =(const float*)d_in[30];
  const float* k_w    =(const float*)d_in[31];
  const float* k_b    =(const float*)d_in[32];
  const float* v_w    =(const float*)d_in[33];
  const float* v_b    =(const float*)d_in[34];
  const float* o_w    =(const float*)d_in[35];
  const float* o_b    =(const float*)d_in[36];
  float* out = (float*)d_out;

  const size_t BND = (size_t)BN*DIM;     // 16,785,408
  size_t needB = BND*4 + BND*2*4
               + ((size_t)NB*NH*NSEQ + 4 + 2*(size_t)NB*DIM)*4
               + ((size_t)20480 + 2949120 + 1703936)*2;
  if(ws_size < needB){
    hipMemsetAsync(d_out, 0, (size_t)out_size*sizeof(float), stream);
    return;
  }
  float* ws = (float*)d_ws;
  float* x  = ws;                                  // BND fp32
  short* ybf = (short*)(x + BND);
  short* qbf = ybf + BND;
  short* kbf = qbf + BND;
  short* vbf = kbf + BND;
  float* diagk = (float*)(vbf + BND);
  unsigned* kmax = (unsigned*)(diagk + (size_t)NB*NH*NSEQ);
  float* qfin   = (float*)(kmax+4);
  float* pooled = qfin + NB*DIM;
  short* projbf = (short*)(pooled + NB*DIM);       // 320*64 = 20480
  short* ctxT   = projbf + 20480;                  // 128*80*288
  short* wt     = ctxT + (size_t)128*80*288;       // 1,703,936
  const size_t LW = 786432;

  // ---- weight prep (bf16, transposed)
  for(int l=0;l<2;l++){
    short* wl = wt + (size_t)l*LW;
    wprep<<<256,256,0,stream>>>(p_wq +(size_t)l*DIM*DIM, wl,          DIM, DIM);
    wprep<<<256,256,0,stream>>>(p_wk +(size_t)l*DIM*DIM, wl+65536,    DIM, DIM);
    wprep<<<256,256,0,stream>>>(p_wv +(size_t)l*DIM*DIM, wl+131072,   DIM, DIM);
    wprep<<<256,256,0,stream>>>(p_wo +(size_t)l*DIM*DIM, wl+196608,   DIM, DIM);
    wprep<<<1024,256,0,stream>>>(p_ff1_w+(size_t)l*DIM*FFD, wl+262144, DIM, FFD);
    wprep<<<1024,256,0,stream>>>(p_ff2_w+(size_t)l*FFD*DIM, wl+524288, FFD, DIM);
  }
  short* wtkk = wt + 2*LW;
  short* wtvv = wtkk + 65536;
  wprep<<<256,256,0,stream>>>(k_w, wtkk, DIM, DIM);
  wprep<<<256,256,0,stream>>>(v_w, wtvv, DIM, DIM);

  embed_kernel<<<BN,256,0,stream>>>(expr,coords,gene_emb,pos_emb,val_w,val_b,val_g,val_bb,
                                    sp_w,sp_b,sp_g,sp_bb,x);

  dim3 gdd(2, (BN+127)/128);        // N=256 GEMMs over BN rows
  dim3 gff1(8, (FFROWS+127)/128);   // N=1024
  dim3 gff2(2, (FFROWS+127)/128);   // N=256, K=1024
  dim3 gkm(4, NB*NH);
  dim3 gkc(4, NB*NH);
  dim3 gq((NSEQ+63)/64, NB*NH);

  for(int l=0;l<2;l++){
    short* wl = wt + (size_t)l*LW;
    ln_bf<<<BN,256,0,stream>>>(x, p_ln1_g+l*DIM, p_ln1_b+l*DIM, ybf);
    mgemm2<0,1><<<gdd,256,0,stream>>>(ybf, wl+65536,  p_bk+l*DIM, kbf, BN, DIM, DIM);
    mgemm2<0,1><<<gdd,256,0,stream>>>(ybf, wl+131072, p_bv+l*DIM, vbf, BN, DIM, DIM);
    mgemm2<0,1><<<gdd,256,0,stream>>>(ybf, wl,        p_bq+l*DIM, qbf, BN, DIM, DIM);
    diagk_kernel<<<BN,256,0,stream>>>(kbf, diagk);
    kmax_init_kernel<<<1,1,0,stream>>>(kmax);
    projprep_kernel<<<80,256,0,stream>>>(proj + (size_t)l*MF*DH, projbf);
    ctx_zero<<<NB*NH,256,0,stream>>>(ctxT);
    kside_max<<<gkm,256,0,stream>>>(kbf, projbf, kmax);
    kside_ctx<<<gkc,256,0,stream>>>(kbf, vbf, projbf, diagk, kmax, ctxT);
    qside_mfma<<<gq,256,0,stream>>>(qbf, projbf, ctxT, kbf);   // o -> kbf (k dead)
    mgemm2<1,0><<<gdd,256,0,stream>>>(kbf, wl+196608, p_bo+l*DIM, x, BN, DIM, DIM);
    ln_bf<<<BN,256,0,stream>>>(x, p_ln2_g+l*DIM, p_ln2_b+l*DIM, ybf);
    for(int c4=0;c4<4;c4++){
      size_t roff=(size_t)c4*FFROWS;
      mgemm2<2,1><<<gff1,256,0,stream>>>(ybf+roff*DIM, wl+262144, p_ff1_b+l*FFD, vbf,
                                         FFROWS, FFD, DIM);
      mgemm2<1,0><<<gff2,256,0,stream>>>(vbf, wl+524288, p_ff2_b+l*DIM, x+roff*DIM,
                                         FFROWS, DIM, FFD);
    }
  }

  // final pooling attention
  castbf<<<BND/1024,256,0,stream>>>(x, ybf);
  mgemm2<0,1><<<gdd,256,0,stream>>>(ybf, wtkk, k_b, kbf, BN, DIM, DIM);
  mgemm2<0,1><<<gdd,256,0,stream>>>(ybf, wtvv, v_b, vbf, BN, DIM, DIM);
  rowproj_kernel<<<NB,256,0,stream>>>(x, q_w, q_b, qfin, NSEQ*DIM);
  attnpool_kernel<<<NB,256,0,stream>>>(qfin, kbf, vbf, pooled);
  rowproj_kernel<<<NB,256,0,stream>>>(pooled, o_w, o_b, out, DIM);
}

// Round 7
// 1895.726 us; speedup vs baseline: 8.3906x; 1.2515x over previous
//
#include <hip/hip_runtime.h>
#include <hip/hip_bf16.h>
#include <math.h>

#define NB   32
#define KG   2048
#define NSEQ 2049
#define DIM  256
#define NH   4
#define DH   64
#define MF   266
#define FFD  1024
#define BN   (NB*NSEQ)          // 65568
#define FFROWS2 32784           // BN/2
#define NORMC 0.35355339059327376f   // 64^-0.25
#define RATIOC (1.0f/16.309506430300091f) // 266^-0.5

typedef __attribute__((ext_vector_type(8))) short short8;
typedef __attribute__((ext_vector_type(4))) float f32x4;
#define MFMA16(a,b,c) __builtin_amdgcn_mfma_f32_16x16x32_bf16(a,b,c,0,0,0)

__device__ __forceinline__ short f2b(float f){
  union{ __hip_bfloat16 h; short s;} u; u.h = __float2bfloat16(f); return u.s;
}
__device__ __forceinline__ float b2f(short s){
  union{ short s; __hip_bfloat16 h;} u; u.s = s; return __bfloat162float(u.h);
}
__device__ __forceinline__ float gelu_f(float x){
  return 0.5f*x*(1.0f+erff(x*0.70710678118654752f));
}
__device__ __forceinline__ float waveSum(float v){
  #pragma unroll
  for(int o=32;o>0;o>>=1) v += __shfl_down(v,o);
  return v;   // valid in lane 0 only
}
__device__ __forceinline__ float waveMax(float v){
  #pragma unroll
  for(int o=32;o>0;o>>=1) v = fmaxf(v,__shfl_down(v,o));
  return v;   // valid in lane 0 only
}
// exact full-wave sum, valid in ALL 64 lanes (xor sources always in range)
__device__ __forceinline__ float xorSum64(float v){
  v += __shfl_xor(v,32); v += __shfl_xor(v,16); v += __shfl_xor(v,8);
  v += __shfl_xor(v,4);  v += __shfl_xor(v,2);  v += __shfl_xor(v,1);
  return v;
}
__device__ __forceinline__ float blockSum256(float v, float* red){
  int lane = threadIdx.x & 63, wid = threadIdx.x >> 6;
  v = waveSum(v);
  __syncthreads();
  if(lane==0) red[wid]=v;
  __syncthreads();
  return red[0]+red[1]+red[2]+red[3];
}
__device__ __forceinline__ float blockMax256(float v, float* red){
  int lane = threadIdx.x & 63, wid = threadIdx.x >> 6;
  v = waveMax(v);
  __syncthreads();
  if(lane==0) red[wid]=v;
  __syncthreads();
  return fmaxf(fmaxf(red[0],red[1]),fmaxf(red[2],red[3]));
}
__device__ __forceinline__ unsigned fenc(float f){
  unsigned u = __float_as_uint(f);
  return (u & 0x80000000u) ? ~u : (u | 0x80000000u);
}
__device__ __forceinline__ float fdec(unsigned u){
  return (u & 0x80000000u) ? __uint_as_float(u & 0x7FFFFFFFu) : __uint_as_float(~u);
}

// ---------------- embed
__global__ __launch_bounds__(256) void embed_kernel(
    const float* __restrict__ expr, const float* __restrict__ coords,
    const float* __restrict__ gene_emb, const float* __restrict__ pos_emb,
    const float* __restrict__ val_w, const float* __restrict__ val_b,
    const float* __restrict__ val_g, const float* __restrict__ val_bb,
    const float* __restrict__ sp_w, const float* __restrict__ sp_b,
    const float* __restrict__ sp_g, const float* __restrict__ sp_bb,
    float* __restrict__ x){
  __shared__ float red[4];
  int row = blockIdx.x; int b = row / NSEQ, n = row % NSEQ;
  int d = threadIdx.x;
  float v;
  if(n==0) v = coords[b*2]*sp_w[d] + coords[b*2+1]*sp_w[DIM+d] + sp_b[d];
  else     v = expr[(size_t)b*KG + (n-1)]*val_w[d] + val_b[d];
  float mu = blockSum256(v, red)*(1.0f/DIM);
  float c  = v - mu;
  float var = blockSum256(c*c, red)*(1.0f/DIM);
  float r = rsqrtf(var + 1e-5f);
  float g  = (n==0)? sp_g[d]  : val_g[d];
  float be = (n==0)? sp_bb[d] : val_bb[d];
  float h = gelu_f(c*r*g + be);
  float o = (n==0)? h : (gene_emb[(size_t)(n-1)*DIM+d]+pos_emb[(size_t)(n-1)*DIM+d]+h);
  x[(size_t)row*DIM + d] = o;
}

// ---------------- LN -> bf16, wave-per-row (4 rows/block), xor-exact reductions
__global__ __launch_bounds__(256) void ln_bf4(const float* __restrict__ xin,
    const float* __restrict__ g, const float* __restrict__ bb, short* __restrict__ ybf){
  int w = threadIdx.x >> 6, l = threadIdx.x & 63;
  int row = blockIdx.x*4 + w;
  const float* xr = xin + (size_t)row*DIM;
  float4 v = *reinterpret_cast<const float4*>(xr + l*4);
  float s = xorSum64(v.x+v.y+v.z+v.w);          // full sum, ALL lanes exact
  float mu = s*(1.0f/DIM);
  float cx=v.x-mu, cy=v.y-mu, cz=v.z-mu, cw=v.w-mu;
  float var = xorSum64(cx*cx+cy*cy+cz*cz+cw*cw)*(1.0f/DIM);
  float r = rsqrtf(var+1e-5f);
  const float4 gv = *reinterpret_cast<const float4*>(g + l*4);
  const float4 bv = *reinterpret_cast<const float4*>(bb + l*4);
  short4 o = make_short4(f2b(cx*r*gv.x+bv.x), f2b(cy*r*gv.y+bv.y),
                         f2b(cz*r*gv.z+bv.z), f2b(cw*r*gv.w+bv.w));
  *reinterpret_cast<short4*>(ybf + (size_t)row*DIM + l*4) = o;
}

// ---------------- diag_k from bf16 k, wave-per-row (per-head 16-lane xor groups)
__global__ __launch_bounds__(256) void diagk4(const short* __restrict__ kbf, float* __restrict__ diagk){
  int w = threadIdx.x >> 6, l = threadIdx.x & 63;
  int row = blockIdx.x*4 + w;
  int b = row / NSEQ, n = row % NSEQ;
  short4 v = *reinterpret_cast<const short4*>(kbf + (size_t)row*DIM + l*4);
  float a0=b2f(v.x), a1=b2f(v.y), a2=b2f(v.z), a3=b2f(v.w);
  float s = a0*a0+a1*a1+a2*a2+a3*a3;
  s += __shfl_xor(s,1); s += __shfl_xor(s,2);
  s += __shfl_xor(s,4); s += __shfl_xor(s,8);
  if((l&15)==0){
    int h = l>>4;
    diagk[((size_t)(b*NH+h))*NSEQ + n] = 0.0625f*s;
  }
}

// ---------------- fp32 -> bf16 cast
__global__ __launch_bounds__(256) void castbf(const float* __restrict__ in, short* __restrict__ out){
  size_t i = ((size_t)blockIdx.x*256 + threadIdx.x)*4;
  float4 v = *reinterpret_cast<const float4*>(in+i);
  *reinterpret_cast<short4*>(out+i) = make_short4(f2b(v.x),f2b(v.y),f2b(v.z),f2b(v.w));
}

// ---------------- weight prep: W[k][n] fp32 -> WT[n][k] bf16
__global__ __launch_bounds__(256) void wprep(const float* __restrict__ W, short* __restrict__ out,
                                             int K, int N){
  int i = blockIdx.x*256 + threadIdx.x;
  if(i < K*N){ int k = i/N, n = i - k*N; out[(size_t)n*K + k] = f2b(W[i]); }
}

// ---------------- MFMA GEMM v2: bf16 A [M][Kd], bf16 Bt [N][Kd], fp32 bias
template<int EPI, int OBF>
__global__ __launch_bounds__(256) void mgemm2(
    const short* __restrict__ A, const short* __restrict__ Bt,
    const float* __restrict__ bias, void* __restrict__ Cv,
    int M, int N, int Kd){
  __shared__ short As[128*40];
  __shared__ short Bs[128*40];
  int t=threadIdx.x, l=t&63, w=t>>6, lr=l&15, lk=l>>4;
  int wm=w>>1, wn=w&1;
  int m0=blockIdx.y*128, n0=blockIdx.x*128;
  f32x4 acc[4][4];
  #pragma unroll
  for(int i=0;i<4;i++)
    #pragma unroll
    for(int j=0;j<4;j++) acc[i][j]=f32x4{0.f,0.f,0.f,0.f};
  const short8 z8 = {0,0,0,0,0,0,0,0};
  for(int k0=0;k0<Kd;k0+=32){
    #pragma unroll
    for(int p=0;p<2;p++){
      int idx=t+p*256; int r=idx>>2, q8=idx&3;
      int gm=m0+r;
      short8 v8 = z8;
      if(gm<M) v8 = *reinterpret_cast<const short8*>(A + (size_t)gm*Kd + k0 + q8*8);
      *reinterpret_cast<short8*>(&As[r*40+q8*8]) = v8;
    }
    #pragma unroll
    for(int p=0;p<2;p++){
      int idx=t+p*256; int r=idx>>2, q8=idx&3;
      short8 v8 = *reinterpret_cast<const short8*>(Bt + (size_t)(n0+r)*Kd + k0 + q8*8);
      *reinterpret_cast<short8*>(&Bs[r*40+q8*8]) = v8;
    }
    __syncthreads();
    short8 af[4], bfr[4];
    #pragma unroll
    for(int i=0;i<4;i++) af[i] = *reinterpret_cast<const short8*>(&As[(wm*64+i*16+lr)*40 + lk*8]);
    #pragma unroll
    for(int j=0;j<4;j++) bfr[j] = *reinterpret_cast<const short8*>(&Bs[(wn*64+j*16+lr)*40 + lk*8]);
    #pragma unroll
    for(int i=0;i<4;i++)
      #pragma unroll
      for(int j=0;j<4;j++) acc[i][j] = MFMA16(af[i], bfr[j], acc[i][j]);
    __syncthreads();
  }
  #pragma unroll
  for(int i=0;i<4;i++){
    int gm0 = m0 + wm*64 + i*16 + lk*4;
    #pragma unroll
    for(int j=0;j<4;j++){
      int gc = n0 + wn*64 + j*16 + lr;
      float bs = bias[gc];
      #pragma unroll
      for(int r=0;r<4;r++){
        int gm = gm0 + r;
        if(gm<M){
          float vv = acc[i][j][r] + bs;
          if(EPI==2) vv = gelu_f(vv);
          size_t idx = (size_t)gm*N + gc;
          if(OBF){
            ((short*)Cv)[idx] = f2b(vv);
          } else {
            float* C = (float*)Cv;
            if(EPI==1) vv += C[idx];
            C[idx] = vv;
          }
        }
      }
    }
  }
}

// ---------------- projbf: bf16(proj * NORMC), 320 rows (pad zero)
__global__ __launch_bounds__(256) void projprep_kernel(const float* __restrict__ proj, short* __restrict__ projbf){
  int i = blockIdx.x*256 + threadIdx.x;
  if(i < 320*64){
    int m = i>>6, d = i&63;
    float v = (m<MF)? proj[(size_t)m*DH + d]*NORMC : 0.f;
    projbf[i] = f2b(v);
  }
}

__global__ void kmax_init_kernel(unsigned* km){ *km = 0u; }

// ---------------- kside pass0: global max of xd_k (bf16 k), 8-way n-split
__global__ __launch_bounds__(256) void kside_max(
    const short* __restrict__ kbf, const short* __restrict__ projbf,
    unsigned* __restrict__ kmax){
  __shared__ short kS[32*72];
  __shared__ float red[4];
  int t=threadIdx.x, l=t&63, w=t>>6, lr=l&15, lk=l>>4;
  int split = blockIdx.x, bh = blockIdx.y;
  int b=bh>>2, h=bh&3;
  int c0 = split*9, c1 = min(c0+9, 65);
  int nf = (w==3)?5:4;
  short8 apf[5][2];
  #pragma unroll
  for(int fi=0;fi<5;fi++){
    int fr = (fi<4)? (fi*4+w) : 16;
    #pragma unroll
    for(int ks=0;ks<2;ks++)
      apf[fi][ks] = *reinterpret_cast<const short8*>(projbf + (fr*16+lr)*64 + ks*32 + lk*8);
  }
  const short8 z8 = {0,0,0,0,0,0,0,0};
  float lmax = -3.0e38f;
  for(int ch=c0; ch<c1; ++ch){
    int n0 = ch*32;
    __syncthreads();
    {
      int r = t>>3, c8 = (t&7)*8;
      int gn = n0 + r;
      short8 v8 = z8;
      if(gn<NSEQ) v8 = *reinterpret_cast<const short8*>(kbf + ((size_t)(b*NSEQ+gn))*DIM + h*DH + c8);
      *reinterpret_cast<short8*>(&kS[r*72+c8]) = v8;
    }
    __syncthreads();
    for(int fi=0;fi<nf;fi++){
      int fr = (fi<4)? (fi*4+w) : 16;
      #pragma unroll
      for(int fn=0;fn<2;fn++){
        f32x4 xa = f32x4{0.f,0.f,0.f,0.f};
        #pragma unroll
        for(int ks=0;ks<2;ks++){
          short8 bk = *reinterpret_cast<const short8*>(&kS[(fn*16+lr)*72 + ks*32 + lk*8]);
          xa = MFMA16(apf[fi][ks], bk, xa);
        }
        #pragma unroll
        for(int r=0;r<4;r++){
          int m = fr*16 + lk*4 + r;
          int n = n0 + fn*16 + lr;
          if(m<MF && n<NSEQ) lmax = fmaxf(lmax, xa[r]);
        }
      }
    }
  }
  float bm = blockMax256(lmax, red);
  if(t==0) atomicMax(kmax, fenc(bm));
}

// ---------------- kside pass1 v4: (f=4 x n=2) split, fp32 partials.
__global__ __launch_bounds__(256) void kside_ctx(
    const short* __restrict__ kbf, const short* __restrict__ vbf,
    const short* __restrict__ projbf, const float* __restrict__ diagk,
    const unsigned* __restrict__ kmax, float* __restrict__ ctxP){
  __shared__ short kS[32*72];
  __shared__ short vT[64*40];
  __shared__ short kfS[80*40];
  __shared__ float diagS[32];
  int t=threadIdx.x, l=t&63, w=t>>6, lr=l&15, lk=l>>4;
  int fb=blockIdx.x&3, qh=blockIdx.x>>2, bh=blockIdx.y; int b=bh>>2, h=bh&3;
  int F0 = fb*5;
  int ch0 = qh*33, ch1 = min(65, ch0+33);
  float stab = fdec(*kmax);
  short8 apf0[2], apf1[2];
  #pragma unroll
  for(int ks=0;ks<2;ks++){
    apf0[ks] = *reinterpret_cast<const short8*>(projbf + ((F0+w)*16+lr)*64 + ks*32 + lk*8);
    apf1[ks] = *reinterpret_cast<const short8*>(projbf + ((F0+4)*16+lr)*64 + ks*32 + lk*8);
  }
  f32x4 ctx[5];
  #pragma unroll
  for(int f=0;f<5;f++) ctx[f]=f32x4{0.f,0.f,0.f,0.f};
  f32x4 ksc0 = f32x4{0.f,0.f,0.f,0.f};
  f32x4 ksc1 = f32x4{0.f,0.f,0.f,0.f};
  const short ONE=(short)0x3F80;
  const short8 ones8 = {ONE,ONE,ONE,ONE,ONE,ONE,ONE,ONE};
  const short8 z8 = {0,0,0,0,0,0,0,0};
  for(int ch=ch0; ch<ch1; ++ch){
    int n0 = ch*32;
    __syncthreads();
    {
      int r = t>>3, c8 = (t&7)*8;
      int gn = n0 + r;
      short8 v8 = z8;
      if(gn<NSEQ) v8 = *reinterpret_cast<const short8*>(kbf + ((size_t)(b*NSEQ+gn))*DIM + h*DH + c8);
      *reinterpret_cast<short8*>(&kS[r*72+c8]) = v8;
    }
    #pragma unroll
    for(int p=0;p<4;p++){
      int n2 = 2*w + 8*p;
      int dd = t&63;
      int gn0=n0+n2, gn1=gn0+1;
      short v0 = (gn0<NSEQ)? vbf[((size_t)(b*NSEQ+gn0))*DIM + h*DH + dd] : (short)0;
      short v1 = (gn1<NSEQ)? vbf[((size_t)(b*NSEQ+gn1))*DIM + h*DH + dd] : (short)0;
      *reinterpret_cast<short2*>(&vT[dd*40 + n2]) = make_short2(v0,v1);
    }
    if(t<32) diagS[t] = (n0+t<NSEQ)? diagk[(size_t)bh*NSEQ + n0+t] : 0.f;
    __syncthreads();
    #pragma unroll
    for(int fn=0;fn<2;fn++){
      f32x4 xa = f32x4{0.f,0.f,0.f,0.f};
      #pragma unroll
      for(int ks=0;ks<2;ks++){
        short8 bk = *reinterpret_cast<const short8*>(&kS[(fn*16+lr)*72 + ks*32 + lk*8]);
        xa = MFMA16(apf0[ks], bk, xa);
      }
      float dgn = diagS[fn*16+lr];
      #pragma unroll
      for(int r=0;r<4;r++){
        int m = (F0+w)*16 + lk*4 + r;
        int n = n0 + fn*16 + lr;
        float kf = (m<MF && n<NSEQ)? RATIOC*(expf(xa[r]-dgn-stab)+1e-4f) : 0.f;
        kfS[(w*16+lk*4+r)*40 + fn*16 + lr] = f2b(kf);
      }
    }
    if(w==0){
      #pragma unroll
      for(int fn=0;fn<2;fn++){
        f32x4 xa = f32x4{0.f,0.f,0.f,0.f};
        #pragma unroll
        for(int ks=0;ks<2;ks++){
          short8 bk = *reinterpret_cast<const short8*>(&kS[(fn*16+lr)*72 + ks*32 + lk*8]);
          xa = MFMA16(apf1[ks], bk, xa);
        }
        float dgn = diagS[fn*16+lr];
        #pragma unroll
        for(int r=0;r<4;r++){
          int m = (F0+4)*16 + lk*4 + r;
          int n = n0 + fn*16 + lr;
          float kf = (m<MF && n<NSEQ)? RATIOC*(expf(xa[r]-dgn-stab)+1e-4f) : 0.f;
          kfS[(64+lk*4+r)*40 + fn*16 + lr] = f2b(kf);
        }
      }
    }
    __syncthreads();
    short8 bv = *reinterpret_cast<const short8*>(&vT[(w*16+lr)*40 + lk*8]);
    short8 a0 = *reinterpret_cast<const short8*>(&kfS[(w*16+lr)*40 + lk*8]);
    short8 a4 = *reinterpret_cast<const short8*>(&kfS[(64+lr)*40 + lk*8]);
    ksc0 = MFMA16(a0, ones8, ksc0);
    ksc1 = MFMA16(a4, ones8, ksc1);
    #pragma unroll
    for(int fl=0;fl<5;fl++){
      short8 a_ = *reinterpret_cast<const short8*>(&kfS[(fl*16+lr)*40 + lk*8]);
      ctx[fl] = MFMA16(a_, bv, ctx[fl]);
    }
  }
  float* P = ctxP + ((size_t)(qh*128 + bh))*65*320;
  #pragma unroll
  for(int fl=0;fl<5;fl++){
    #pragma unroll
    for(int r=0;r<4;r++){
      int m = (F0+fl)*16 + lk*4 + r;
      P[(size_t)(w*16+lr)*320 + m] = ctx[fl][r];
    }
  }
  if(lr==0){
    #pragma unroll
    for(int r=0;r<4;r++){
      int m = (F0+w)*16 + lk*4 + r;
      P[(size_t)64*320 + m] = ksc0[r];
    }
    if(w==0){
      #pragma unroll
      for(int r=0;r<4;r++){
        int m = (F0+4)*16 + lk*4 + r;
        P[(size_t)64*320 + m] = ksc1[r];
      }
    }
  }
}

// ---------------- reduce 2 fp32 partials -> bf16 ctxT[bh][80][288] (zero-padded)
__global__ __launch_bounds__(256) void ctx_reduce(const float* __restrict__ ctxP, short* __restrict__ ctxT){
  int row = blockIdx.x, bh = blockIdx.y, t = threadIdx.x;
  short* o = ctxT + ((size_t)bh*80 + row)*288;
  if(row < 65){
    const float* P0 = ctxP + ((size_t)bh*65 + row)*320;
    const float* P1 = ctxP + ((size_t)(128+bh)*65 + row)*320;
    for(int m=t; m<288; m+=256)
      o[m] = (m<272)? f2b(P0[m]+P1[m]) : (short)0;
  } else {
    for(int m=t; m<288; m+=256) o[m] = 0;
  }
}

// ---------------- qside fused (bf16 q in, bf16 o out)
__global__ __launch_bounds__(256) void qside_mfma(
    const short* __restrict__ qbf, const short* __restrict__ projbf,
    const short* __restrict__ ctxT, short* __restrict__ obf){
  __shared__ short qS[64*72];
  __shared__ short qfS[64*296];
  __shared__ float diagS[64];
  int t=threadIdx.x, l=t&63, w=t>>6, lr=l&15, lk=l>>4;
  int n0 = blockIdx.x*64, bh = blockIdx.y;
  int b = bh>>2, h = bh&3;
  const short8 z8 = {0,0,0,0,0,0,0,0};
  {
    int r = t>>2, c8 = (t&3)*16;
    int gn = n0 + r;
    float ssq = 0.f;
    #pragma unroll
    for(int i=0;i<2;i++){
      short8 v8 = z8;
      if(gn<NSEQ) v8 = *reinterpret_cast<const short8*>(qbf + ((size_t)(b*NSEQ+gn))*DIM + h*DH + c8 + i*8);
      #pragma unroll
      for(int u=0;u<8;u++){ float fv=b2f(v8[u]); ssq += fv*fv; }
      *reinterpret_cast<short8*>(&qS[r*72+c8+i*8]) = v8;
    }
    ssq += __shfl_xor(ssq,1); ssq += __shfl_xor(ssq,2);
    if((t&3)==0) diagS[r] = 0.0625f*ssq;
    #pragma unroll
    for(int i=0;i<4;i++) qfS[r*296 + 272 + (t&3)*4 + i] = 0;
  }
  __syncthreads();
  short8 aq[2];
  #pragma unroll
  for(int ks=0;ks<2;ks++) aq[ks] = *reinterpret_cast<const short8*>(&qS[(w*16+lr)*72 + ks*32 + lk*8]);
  f32x4 acc[17];
  #pragma unroll
  for(int f=0;f<17;f++) acc[f]=f32x4{0.f,0.f,0.f,0.f};
  #pragma unroll
  for(int f=0;f<17;f++){
    #pragma unroll
    for(int ks=0;ks<2;ks++){
      short8 bp = *reinterpret_cast<const short8*>(projbf + (f*16+lr)*64 + ks*32 + lk*8);
      acc[f] = MFMA16(aq[ks], bp, acc[f]);
    }
  }
  float rmax[4];
  #pragma unroll
  for(int r=0;r<4;r++){
    float m = -3.0e38f;
    #pragma unroll
    for(int f=0;f<17;f++){
      float v = (f==16 && lr>=10)? -3.0e38f : acc[f][r];
      m = fmaxf(m,v);
    }
    m = fmaxf(m,__shfl_xor(m,1)); m = fmaxf(m,__shfl_xor(m,2));
    m = fmaxf(m,__shfl_xor(m,4)); m = fmaxf(m,__shfl_xor(m,8));
    rmax[r]=m;
  }
  float dg[4];
  #pragma unroll
  for(int r=0;r<4;r++) dg[r] = diagS[w*16 + lk*4 + r];
  #pragma unroll
  for(int f=0;f<17;f++)
    #pragma unroll
    for(int r=0;r<4;r++){
      float qv = RATIOC*(expf(acc[f][r] - dg[r] - rmax[r]) + 1e-4f);
      qfS[(w*16+lk*4+r)*296 + f*16 + lr] = f2b(qv);
    }
  __syncthreads();
  f32x4 pv[5];
  #pragma unroll
  for(int f=0;f<5;f++) pv[f]=f32x4{0.f,0.f,0.f,0.f};
  const short* cT = ctxT + (size_t)bh*80*288;
  for(int ks=0;ks<9;ks++){
    short8 a_ = *reinterpret_cast<const short8*>(&qfS[(w*16+lr)*296 + ks*32 + lk*8]);
    #pragma unroll
    for(int f=0;f<5;f++){
      short8 bb = *reinterpret_cast<const short8*>(cT + (f*16+lr)*288 + ks*32 + lk*8);
      pv[f] = MFMA16(a_, bb, pv[f]);
    }
  }
  #pragma unroll
  for(int r=0;r<4;r++){
    int gn = n0 + w*16 + lk*4 + r;
    if(gn>=NSEQ) continue;
    float den = __shfl(pv[4][r], (l & 48), 64);
    float inv = 1.0f/den;
    size_t obase = ((size_t)(b*NSEQ+gn))*DIM + h*DH;
    #pragma unroll
    for(int f=0;f<4;f++) obf[obase + f*16 + lr] = f2b(pv[f][r]*inv);
  }
}

// ---------------- small row projection (fp32)
__global__ __launch_bounds__(256) void rowproj_kernel(const float* __restrict__ src,
    const float* __restrict__ W, const float* __restrict__ bias,
    float* __restrict__ dst, int rowstride){
  __shared__ float rs[DIM];
  int b=blockIdx.x, t=threadIdx.x;
  rs[t]=src[(size_t)b*rowstride+t];
  __syncthreads();
  float s=bias[t];
  for(int j=0;j<DIM;j++) s += rs[j]*W[(size_t)j*DIM+t];
  dst[(size_t)b*DIM+t]=s;
}

// ---------------- final pooling attention (bf16 kk/vv)
__global__ __launch_bounds__(256) void attnpool_kernel(const float* __restrict__ qfin,
    const short* __restrict__ kk, const short* __restrict__ vv, float* __restrict__ pooled){
  __shared__ float qsh[DIM];
  __shared__ float sc[KG];
  __shared__ float red[4];
  int b=blockIdx.x, t=threadIdx.x;
  qsh[t]=qfin[b*DIM+t];
  __syncthreads();
  float ls[8]; float lmax=-3.4e38f;
  #pragma unroll
  for(int i=0;i<8;i++){
    int kidx=t+i*256;
    const short* kr = kk + ((size_t)(b*NSEQ+1+kidx))*DIM;
    float s=0;
    for(int j8=0;j8<32;j8++){
      short8 kv = *reinterpret_cast<const short8*>(kr + j8*8);
      #pragma unroll
      for(int u=0;u<8;u++) s += qsh[j8*8+u]*b2f(kv[u]);
    }
    s *= 0.0625f;
    ls[i]=s; lmax=fmaxf(lmax,s);
  }
  float gmax=blockMax256(lmax,red);
  float lsum=0;
  #pragma unroll
  for(int i=0;i<8;i++){ float e=expf(ls[i]-gmax); sc[t+i*256]=e; lsum+=e; }
  float gsum=blockSum256(lsum,red);
  __syncthreads();
  float inv=1.0f/gsum;
  float p=0;
  for(int kidx=0;kidx<KG;kidx++) p += sc[kidx]*b2f(vv[((size_t)(b*NSEQ+1+kidx))*DIM + t]);
  pooled[b*DIM+t]=p*inv;
}

extern "C" void kernel_launch(void* const* d_in, const int* in_sizes, int n_in,
                              void* d_out, int out_size, void* d_ws, size_t ws_size,
                              hipStream_t stream){
  const float* expr   =(const float*)d_in[0];
  const float* coords =(const float*)d_in[1];
  const float* gene_emb=(const float*)d_in[2];
  const float* pos_emb=(const float*)d_in[3];
  const float* val_w  =(const float*)d_in[4];
  const float* val_b  =(const float*)d_in[5];
  const float* val_g  =(const float*)d_in[6];
  const float* val_bb =(const float*)d_in[7];
  const float* sp_w   =(const float*)d_in[8];
  const float* sp_b   =(const float*)d_in[9];
  const float* sp_g   =(const float*)d_in[10];
  const float* sp_bb  =(const float*)d_in[11];
  const float* p_ln1_g=(const float*)d_in[12];
  const float* p_ln1_b=(const float*)d_in[13];
  const float* p_wq   =(const float*)d_in[14];
  const float* p_bq   =(const float*)d_in[15];
  const float* p_wk   =(const float*)d_in[16];
  const float* p_bk   =(const float*)d_in[17];
  const float* p_wv   =(const float*)d_in[18];
  const float* p_bv   =(const float*)d_in[19];
  const float* p_wo   =(const float*)d_in[20];
  const float* p_bo   =(const float*)d_in[21];
  const float* p_ln2_g=(const float*)d_in[22];
  const float* p_ln2_b=(const float*)d_in[23];
  const float* p_ff1_w=(const float*)d_in[24];
  const float* p_ff1_b=(const float*)d_in[25];
  const float* p_ff2_w=(const float*)d_in[26];
  const float* p_ff2_b=(const float*)d_in[27];
  const float* proj   =(const float*)d_in[28];
  const float* q_w    =(const float*)d_in[29];
  const float* q_b    =(const float*)d_in[30];
  const float* k_w    =(const float*)d_in[31];
  const float* k_b    =(const float*)d_in[32];
  const float* v_w    =(const float*)d_in[33];
  const float* v_b    =(const float*)d_in[34];
  const float* o_w    =(const float*)d_in[35];
  const float* o_b    =(const float*)d_in[36];
  float* out = (float*)d_out;

  const size_t BND = (size_t)BN*DIM;     // 16,785,408
  size_t needB = BND*4 + BND*2*4
               + ((size_t)NB*NH*NSEQ + 4 + 2*(size_t)NB*DIM)*4
               + ((size_t)20480 + 2949120 + 1703936)*2;
  if(ws_size < needB){
    hipMemsetAsync(d_out, 0, (size_t)out_size*sizeof(float), stream);
    return;
  }
  float* ws = (float*)d_ws;
  float* x  = ws;                                  // BND fp32
  short* ybf = (short*)(x + BND);
  short* qbf = ybf + BND;
  short* kbf = qbf + BND;
  short* vbf = kbf + BND;
  float* diagk = (float*)(vbf + BND);
  unsigned* kmax = (unsigned*)(diagk + (size_t)NB*NH*NSEQ);
  float* qfin   = (float*)(kmax+4);
  float* pooled = qfin + NB*DIM;
  short* projbf = (short*)(pooled + NB*DIM);       // 320*64 = 20480
  short* ctxT   = projbf + 20480;                  // 128*80*288
  short* wt     = ctxT + (size_t)128*80*288;       // 1,703,936
  const size_t LW = 786432;
  float* ctxP = (float*)ybf;   // 21.3MB partials in dead ybf region

  for(int l=0;l<2;l++){
    short* wl = wt + (size_t)l*LW;
    wprep<<<256,256,0,stream>>>(p_wq +(size_t)l*DIM*DIM, wl,          DIM, DIM);
    wprep<<<256,256,0,stream>>>(p_wk +(size_t)l*DIM*DIM, wl+65536,    DIM, DIM);
    wprep<<<256,256,0,stream>>>(p_wv +(size_t)l*DIM*DIM, wl+131072,   DIM, DIM);
    wprep<<<256,256,0,stream>>>(p_wo +(size_t)l*DIM*DIM, wl+196608,   DIM, DIM);
    wprep<<<1024,256,0,stream>>>(p_ff1_w+(size_t)l*DIM*FFD, wl+262144, DIM, FFD);
    wprep<<<1024,256,0,stream>>>(p_ff2_w+(size_t)l*FFD*DIM, wl+524288, FFD, DIM);
  }
  short* wtkk = wt + 2*LW;
  short* wtvv = wtkk + 65536;
  wprep<<<256,256,0,stream>>>(k_w, wtkk, DIM, DIM);
  wprep<<<256,256,0,stream>>>(v_w, wtvv, DIM, DIM);

  embed_kernel<<<BN,256,0,stream>>>(expr,coords,gene_emb,pos_emb,val_w,val_b,val_g,val_bb,
                                    sp_w,sp_b,sp_g,sp_bb,x);

  dim3 gdd(2, (BN+127)/128);         // N=256 GEMMs over BN rows
  dim3 gff1(8, (FFROWS2+127)/128);   // N=1024
  dim3 gff2(2, (FFROWS2+127)/128);   // N=256, K=1024
  dim3 gkm(8, NB*NH);
  dim3 gkc(8, NB*NH);                // (f4 x n2) x 128 bh
  dim3 gcr(80, NB*NH);
  dim3 gq((NSEQ+63)/64, NB*NH);

  for(int l=0;l<2;l++){
    short* wl = wt + (size_t)l*LW;
    ln_bf4<<<BN/4,256,0,stream>>>(x, p_ln1_g+l*DIM, p_ln1_b+l*DIM, ybf);
    mgemm2<0,1><<<gdd,256,0,stream>>>(ybf, wl+65536,  p_bk+l*DIM, kbf, BN, DIM, DIM);
    mgemm2<0,1><<<gdd,256,0,stream>>>(ybf, wl+131072, p_bv+l*DIM, vbf, BN, DIM, DIM);
    mgemm2<0,1><<<gdd,256,0,stream>>>(ybf, wl,        p_bq+l*DIM, qbf, BN, DIM, DIM);
    diagk4<<<BN/4,256,0,stream>>>(kbf, diagk);
    kmax_init_kernel<<<1,1,0,stream>>>(kmax);
    projprep_kernel<<<80,256,0,stream>>>(proj + (size_t)l*MF*DH, projbf);
    kside_max<<<gkm,256,0,stream>>>(kbf, projbf, kmax);
    kside_ctx<<<gkc,256,0,stream>>>(kbf, vbf, projbf, diagk, kmax, ctxP);
    ctx_reduce<<<gcr,256,0,stream>>>(ctxP, ctxT);
    qside_mfma<<<gq,256,0,stream>>>(qbf, projbf, ctxT, kbf);   // o -> kbf (k dead)
    mgemm2<1,0><<<gdd,256,0,stream>>>(kbf, wl+196608, p_bo+l*DIM, x, BN, DIM, DIM);
    ln_bf4<<<BN/4,256,0,stream>>>(x, p_ln2_g+l*DIM, p_ln2_b+l*DIM, ybf);
    for(int c2=0;c2<2;c2++){
      size_t roff=(size_t)c2*FFROWS2;
      mgemm2<2,1><<<gff1,256,0,stream>>>(ybf+roff*DIM, wl+262144, p_ff1_b+l*FFD, qbf,
                                         FFROWS2, FFD, DIM);
      mgemm2<1,0><<<gff2,256,0,stream>>>(qbf, wl+524288, p_ff2_b+l*DIM, x+roff*DIM,
                                         FFROWS2, DIM, FFD);
    }
  }

  // final pooling attention
  castbf<<<(int)(BND/1024),256,0,stream>>>(x, ybf);
  mgemm2<0,1><<<gdd,256,0,stream>>>(ybf, wtkk, k_b, kbf, BN, DIM, DIM);
  mgemm2<0,1><<<gdd,256,0,stream>>>(ybf, wtvv, v_b, vbf, BN, DIM, DIM);
  rowproj_kernel<<<NB,256,0,stream>>>(x, q_w, q_b, qfin, NSEQ*DIM);
  attnpool_kernel<<<NB,256,0,stream>>>(qfin, kbf, vbf, pooled);
  rowproj_kernel<<<NB,256,0,stream>>>(pooled, o_w, o_b, out, DIM);
}

// Round 8
// 1793.606 us; speedup vs baseline: 8.8683x; 1.0569x over previous
//
#include <hip/hip_runtime.h>
#include <hip/hip_bf16.h>
#include <math.h>

#define NB   32
#define KG   2048
#define NSEQ 2049
#define DIM  256
#define NH   4
#define DH   64
#define MF   266
#define FFD  1024
#define BN   (NB*NSEQ)          // 65568
#define FFROWS2 32784           // BN/2
#define NORMC 0.35355339059327376f   // 64^-0.25
#define RATIOC (1.0f/16.309506430300091f) // 266^-0.5

typedef __attribute__((ext_vector_type(8))) short short8;
typedef __attribute__((ext_vector_type(4))) float f32x4;
#define MFMA16(a,b,c) __builtin_amdgcn_mfma_f32_16x16x32_bf16(a,b,c,0,0,0)

__device__ __forceinline__ short f2b(float f){
  union{ __hip_bfloat16 h; short s;} u; u.h = __float2bfloat16(f); return u.s;
}
__device__ __forceinline__ float b2f(short s){
  union{ short s; __hip_bfloat16 h;} u; u.s = s; return __bfloat162float(u.h);
}
__device__ __forceinline__ float gelu_f(float x){
  return 0.5f*x*(1.0f+erff(x*0.70710678118654752f));
}
// async global->LDS, 16B per lane; lds base must be wave-uniform
__device__ __forceinline__ void gload16(const short* g, short* l){
  __builtin_amdgcn_global_load_lds(
      (const __attribute__((address_space(1))) void*)g,
      (__attribute__((address_space(3))) void*)l, 16, 0, 0);
}
__device__ __forceinline__ float waveSum(float v){
  #pragma unroll
  for(int o=32;o>0;o>>=1) v += __shfl_down(v,o);
  return v;   // lane 0 only
}
__device__ __forceinline__ float waveMax(float v){
  #pragma unroll
  for(int o=32;o>0;o>>=1) v = fmaxf(v,__shfl_down(v,o));
  return v;   // lane 0 only
}
__device__ __forceinline__ float xorSum64(float v){
  v += __shfl_xor(v,32); v += __shfl_xor(v,16); v += __shfl_xor(v,8);
  v += __shfl_xor(v,4);  v += __shfl_xor(v,2);  v += __shfl_xor(v,1);
  return v;   // exact, all lanes
}
__device__ __forceinline__ float blockSum256(float v, float* red){
  int lane = threadIdx.x & 63, wid = threadIdx.x >> 6;
  v = waveSum(v);
  __syncthreads();
  if(lane==0) red[wid]=v;
  __syncthreads();
  return red[0]+red[1]+red[2]+red[3];
}
__device__ __forceinline__ float blockMax256(float v, float* red){
  int lane = threadIdx.x & 63, wid = threadIdx.x >> 6;
  v = waveMax(v);
  __syncthreads();
  if(lane==0) red[wid]=v;
  __syncthreads();
  return fmaxf(fmaxf(red[0],red[1]),fmaxf(red[2],red[3]));
}
__device__ __forceinline__ unsigned fenc(float f){
  unsigned u = __float_as_uint(f);
  return (u & 0x80000000u) ? ~u : (u | 0x80000000u);
}
__device__ __forceinline__ float fdec(unsigned u){
  return (u & 0x80000000u) ? __uint_as_float(u & 0x7FFFFFFFu) : __uint_as_float(~u);
}

// ---------------- embed
__global__ __launch_bounds__(256) void embed_kernel(
    const float* __restrict__ expr, const float* __restrict__ coords,
    const float* __restrict__ gene_emb, const float* __restrict__ pos_emb,
    const float* __restrict__ val_w, const float* __restrict__ val_b,
    const float* __restrict__ val_g, const float* __restrict__ val_bb,
    const float* __restrict__ sp_w, const float* __restrict__ sp_b,
    const float* __restrict__ sp_g, const float* __restrict__ sp_bb,
    float* __restrict__ x){
  __shared__ float red[4];
  int row = blockIdx.x; int b = row / NSEQ, n = row % NSEQ;
  int d = threadIdx.x;
  float v;
  if(n==0) v = coords[b*2]*sp_w[d] + coords[b*2+1]*sp_w[DIM+d] + sp_b[d];
  else     v = expr[(size_t)b*KG + (n-1)]*val_w[d] + val_b[d];
  float mu = blockSum256(v, red)*(1.0f/DIM);
  float c  = v - mu;
  float var = blockSum256(c*c, red)*(1.0f/DIM);
  float r = rsqrtf(var + 1e-5f);
  float g  = (n==0)? sp_g[d]  : val_g[d];
  float be = (n==0)? sp_bb[d] : val_bb[d];
  float h = gelu_f(c*r*g + be);
  float o = (n==0)? h : (gene_emb[(size_t)(n-1)*DIM+d]+pos_emb[(size_t)(n-1)*DIM+d]+h);
  x[(size_t)row*DIM + d] = o;
}

// ---------------- LN -> bf16, wave-per-row, xor-exact
__global__ __launch_bounds__(256) void ln_bf4(const float* __restrict__ xin,
    const float* __restrict__ g, const float* __restrict__ bb, short* __restrict__ ybf){
  int w = threadIdx.x >> 6, l = threadIdx.x & 63;
  int row = blockIdx.x*4 + w;
  const float* xr = xin + (size_t)row*DIM;
  float4 v = *reinterpret_cast<const float4*>(xr + l*4);
  float s = xorSum64(v.x+v.y+v.z+v.w);
  float mu = s*(1.0f/DIM);
  float cx=v.x-mu, cy=v.y-mu, cz=v.z-mu, cw=v.w-mu;
  float var = xorSum64(cx*cx+cy*cy+cz*cz+cw*cw)*(1.0f/DIM);
  float r = rsqrtf(var+1e-5f);
  const float4 gv = *reinterpret_cast<const float4*>(g + l*4);
  const float4 bv = *reinterpret_cast<const float4*>(bb + l*4);
  short4 o = make_short4(f2b(cx*r*gv.x+bv.x), f2b(cy*r*gv.y+bv.y),
                         f2b(cz*r*gv.z+bv.z), f2b(cw*r*gv.w+bv.w));
  *reinterpret_cast<short4*>(ybf + (size_t)row*DIM + l*4) = o;
}

// ---------------- diag_k, wave-per-row (16-lane xor groups)
__global__ __launch_bounds__(256) void diagk4(const short* __restrict__ kbf, float* __restrict__ diagk){
  int w = threadIdx.x >> 6, l = threadIdx.x & 63;
  int row = blockIdx.x*4 + w;
  int b = row / NSEQ, n = row % NSEQ;
  short4 v = *reinterpret_cast<const short4*>(kbf + (size_t)row*DIM + l*4);
  float a0=b2f(v.x), a1=b2f(v.y), a2=b2f(v.z), a3=b2f(v.w);
  float s = a0*a0+a1*a1+a2*a2+a3*a3;
  s += __shfl_xor(s,1); s += __shfl_xor(s,2);
  s += __shfl_xor(s,4); s += __shfl_xor(s,8);
  if((l&15)==0){
    int h = l>>4;
    diagk[((size_t)(b*NH+h))*NSEQ + n] = 0.0625f*s;
  }
}

// ---------------- fp32 -> bf16 cast
__global__ __launch_bounds__(256) void castbf(const float* __restrict__ in, short* __restrict__ out){
  size_t i = ((size_t)blockIdx.x*256 + threadIdx.x)*4;
  float4 v = *reinterpret_cast<const float4*>(in+i);
  *reinterpret_cast<short4*>(out+i) = make_short4(f2b(v.x),f2b(v.y),f2b(v.z),f2b(v.w));
}

// ---------------- weight prep: W[k][n] fp32 -> WT[n][k] bf16
__global__ __launch_bounds__(256) void wprep(const float* __restrict__ W, short* __restrict__ out,
                                             int K, int N){
  int i = blockIdx.x*256 + threadIdx.x;
  if(i < K*N){ int k = i/N, n = i - k*N; out[(size_t)n*K + k] = f2b(W[i]); }
}

// ---------------- MFMA GEMM v3: global_load_lds staging, linear LDS [128][32]
// bf16 A [M][Kd], bf16 Bt [N][Kd], fp32 bias. tile 128x128x32, 4 waves 2x2.
// A staging is UNGUARDED: OOB rows read garbage inside ws (callers guarantee
// the next ws buffer absorbs the spill); output store is guarded by gm<M.
template<int EPI, int OBF>
__global__ __launch_bounds__(256) void mgemm2(
    const short* __restrict__ A, const short* __restrict__ Bt,
    const float* __restrict__ bias, void* __restrict__ Cv,
    int M, int N, int Kd){
  __shared__ short As[128*32];
  __shared__ short Bs[128*32];
  int t=threadIdx.x, l=t&63, w=t>>6, lr=l&15, lk=l>>4;
  int wm=w>>1, wn=w&1;
  int m0=blockIdx.y*128, n0=blockIdx.x*128;
  f32x4 acc[4][4];
  #pragma unroll
  for(int i=0;i<4;i++)
    #pragma unroll
    for(int j=0;j<4;j++) acc[i][j]=f32x4{0.f,0.f,0.f,0.f};
  for(int k0=0;k0<Kd;k0+=32){
    // async stage: 512 chunks of 16B per tile; chunk -> row=chunk>>2, qc=chunk&3
    #pragma unroll
    for(int p=0;p<2;p++){
      int chunk = p*256 + t;
      int row = chunk>>2, qc = chunk&3;
      short* lbase = &As[(size_t)(p*256 + w*64)*8];      // wave-uniform
      gload16(A + (size_t)(m0+row)*Kd + k0 + qc*8, lbase);
    }
    #pragma unroll
    for(int p=0;p<2;p++){
      int chunk = p*256 + t;
      int row = chunk>>2, qc = chunk&3;
      short* lbase = &Bs[(size_t)(p*256 + w*64)*8];
      gload16(Bt + (size_t)(n0+row)*Kd + k0 + qc*8, lbase);
    }
    __syncthreads();   // drains vmcnt before barrier
    short8 af[4], bfr[4];
    #pragma unroll
    for(int i=0;i<4;i++) af[i] = *reinterpret_cast<const short8*>(&As[(wm*64+i*16+lr)*32 + lk*8]);
    #pragma unroll
    for(int j=0;j<4;j++) bfr[j] = *reinterpret_cast<const short8*>(&Bs[(wn*64+j*16+lr)*32 + lk*8]);
    #pragma unroll
    for(int i=0;i<4;i++)
      #pragma unroll
      for(int j=0;j<4;j++) acc[i][j] = MFMA16(af[i], bfr[j], acc[i][j]);
    __syncthreads();
  }
  #pragma unroll
  for(int i=0;i<4;i++){
    int gm0 = m0 + wm*64 + i*16 + lk*4;
    #pragma unroll
    for(int j=0;j<4;j++){
      int gc = n0 + wn*64 + j*16 + lr;
      float bs = bias[gc];
      #pragma unroll
      for(int r=0;r<4;r++){
        int gm = gm0 + r;
        if(gm<M){
          float vv = acc[i][j][r] + bs;
          if(EPI==2) vv = gelu_f(vv);
          size_t idx = (size_t)gm*N + gc;
          if(OBF){
            ((short*)Cv)[idx] = f2b(vv);
          } else {
            float* C = (float*)Cv;
            if(EPI==1) vv += C[idx];
            C[idx] = vv;
          }
        }
      }
    }
  }
}

// ---------------- projbf: bf16(proj * NORMC), 320 rows (pad zero); also init kmax
__global__ __launch_bounds__(256) void projprep_kernel(const float* __restrict__ proj,
    short* __restrict__ projbf, unsigned* __restrict__ kmax){
  int i = blockIdx.x*256 + threadIdx.x;
  if(i==0) *kmax = 0u;
  if(i < 320*64){
    int m = i>>6, d = i&63;
    float v = (m<MF)? proj[(size_t)m*DH + d]*NORMC : 0.f;
    projbf[i] = f2b(v);
  }
}

// ---------------- kside pass0: global max of xd_k (bf16 k), 8-way n-split
__global__ __launch_bounds__(256) void kside_max(
    const short* __restrict__ kbf, const short* __restrict__ projbf,
    unsigned* __restrict__ kmax){
  __shared__ short kS[32*72];
  __shared__ float red[4];
  int t=threadIdx.x, l=t&63, w=t>>6, lr=l&15, lk=l>>4;
  int split = blockIdx.x, bh = blockIdx.y;
  int b=bh>>2, h=bh&3;
  int c0 = split*9, c1 = min(c0+9, 65);
  int nf = (w==3)?5:4;
  short8 apf[5][2];
  #pragma unroll
  for(int fi=0;fi<5;fi++){
    int fr = (fi<4)? (fi*4+w) : 16;
    #pragma unroll
    for(int ks=0;ks<2;ks++)
      apf[fi][ks] = *reinterpret_cast<const short8*>(projbf + (fr*16+lr)*64 + ks*32 + lk*8);
  }
  const short8 z8 = {0,0,0,0,0,0,0,0};
  float lmax = -3.0e38f;
  for(int ch=c0; ch<c1; ++ch){
    int n0 = ch*32;
    __syncthreads();
    {
      int r = t>>3, c8 = (t&7)*8;
      int gn = n0 + r;
      short8 v8 = z8;
      if(gn<NSEQ) v8 = *reinterpret_cast<const short8*>(kbf + ((size_t)(b*NSEQ+gn))*DIM + h*DH + c8);
      *reinterpret_cast<short8*>(&kS[r*72+c8]) = v8;
    }
    __syncthreads();
    for(int fi=0;fi<nf;fi++){
      int fr = (fi<4)? (fi*4+w) : 16;
      #pragma unroll
      for(int fn=0;fn<2;fn++){
        f32x4 xa = f32x4{0.f,0.f,0.f,0.f};
        #pragma unroll
        for(int ks=0;ks<2;ks++){
          short8 bk = *reinterpret_cast<const short8*>(&kS[(fn*16+lr)*72 + ks*32 + lk*8]);
          xa = MFMA16(apf[fi][ks], bk, xa);
        }
        #pragma unroll
        for(int r=0;r<4;r++){
          int m = fr*16 + lk*4 + r;
          int n = n0 + fn*16 + lr;
          if(m<MF && n<NSEQ) lmax = fmaxf(lmax, xa[r]);
        }
      }
    }
  }
  float bm = blockMax256(lmax, red);
  if(t==0) atomicMax(kmax, fenc(bm));
}

// ---------------- kside pass1: (f=4 x n=2) split, fp32 partials
__global__ __launch_bounds__(256) void kside_ctx(
    const short* __restrict__ kbf, const short* __restrict__ vbf,
    const short* __restrict__ projbf, const float* __restrict__ diagk,
    const unsigned* __restrict__ kmax, float* __restrict__ ctxP){
  __shared__ short kS[32*72];
  __shared__ short vT[64*40];
  __shared__ short kfS[80*40];
  __shared__ float diagS[32];
  int t=threadIdx.x, l=t&63, w=t>>6, lr=l&15, lk=l>>4;
  int fb=blockIdx.x&3, qh=blockIdx.x>>2, bh=blockIdx.y; int b=bh>>2, h=bh&3;
  int F0 = fb*5;
  int ch0 = qh*33, ch1 = min(65, ch0+33);
  float stab = fdec(*kmax);
  short8 apf0[2], apf1[2];
  #pragma unroll
  for(int ks=0;ks<2;ks++){
    apf0[ks] = *reinterpret_cast<const short8*>(projbf + ((F0+w)*16+lr)*64 + ks*32 + lk*8);
    apf1[ks] = *reinterpret_cast<const short8*>(projbf + ((F0+4)*16+lr)*64 + ks*32 + lk*8);
  }
  f32x4 ctx[5];
  #pragma unroll
  for(int f=0;f<5;f++) ctx[f]=f32x4{0.f,0.f,0.f,0.f};
  f32x4 ksc0 = f32x4{0.f,0.f,0.f,0.f};
  f32x4 ksc1 = f32x4{0.f,0.f,0.f,0.f};
  const short ONE=(short)0x3F80;
  const short8 ones8 = {ONE,ONE,ONE,ONE,ONE,ONE,ONE,ONE};
  const short8 z8 = {0,0,0,0,0,0,0,0};
  for(int ch=ch0; ch<ch1; ++ch){
    int n0 = ch*32;
    __syncthreads();
    {
      int r = t>>3, c8 = (t&7)*8;
      int gn = n0 + r;
      short8 v8 = z8;
      if(gn<NSEQ) v8 = *reinterpret_cast<const short8*>(kbf + ((size_t)(b*NSEQ+gn))*DIM + h*DH + c8);
      *reinterpret_cast<short8*>(&kS[r*72+c8]) = v8;
    }
    #pragma unroll
    for(int p=0;p<4;p++){
      int n2 = 2*w + 8*p;
      int dd = t&63;
      int gn0=n0+n2, gn1=gn0+1;
      short v0 = (gn0<NSEQ)? vbf[((size_t)(b*NSEQ+gn0))*DIM + h*DH + dd] : (short)0;
      short v1 = (gn1<NSEQ)? vbf[((size_t)(b*NSEQ+gn1))*DIM + h*DH + dd] : (short)0;
      *reinterpret_cast<short2*>(&vT[dd*40 + n2]) = make_short2(v0,v1);
    }
    if(t<32) diagS[t] = (n0+t<NSEQ)? diagk[(size_t)bh*NSEQ + n0+t] : 0.f;
    __syncthreads();
    #pragma unroll
    for(int fn=0;fn<2;fn++){
      f32x4 xa = f32x4{0.f,0.f,0.f,0.f};
      #pragma unroll
      for(int ks=0;ks<2;ks++){
        short8 bk = *reinterpret_cast<const short8*>(&kS[(fn*16+lr)*72 + ks*32 + lk*8]);
        xa = MFMA16(apf0[ks], bk, xa);
      }
      float dgn = diagS[fn*16+lr];
      #pragma unroll
      for(int r=0;r<4;r++){
        int m = (F0+w)*16 + lk*4 + r;
        int n = n0 + fn*16 + lr;
        float kf = (m<MF && n<NSEQ)? RATIOC*(__expf(xa[r]-dgn-stab)+1e-4f) : 0.f;
        kfS[(w*16+lk*4+r)*40 + fn*16 + lr] = f2b(kf);
      }
    }
    if(w==0){
      #pragma unroll
      for(int fn=0;fn<2;fn++){
        f32x4 xa = f32x4{0.f,0.f,0.f,0.f};
        #pragma unroll
        for(int ks=0;ks<2;ks++){
          short8 bk = *reinterpret_cast<const short8*>(&kS[(fn*16+lr)*72 + ks*32 + lk*8]);
          xa = MFMA16(apf1[ks], bk, xa);
        }
        float dgn = diagS[fn*16+lr];
        #pragma unroll
        for(int r=0;r<4;r++){
          int m = (F0+4)*16 + lk*4 + r;
          int n = n0 + fn*16 + lr;
          float kf = (m<MF && n<NSEQ)? RATIOC*(__expf(xa[r]-dgn-stab)+1e-4f) : 0.f;
          kfS[(64+lk*4+r)*40 + fn*16 + lr] = f2b(kf);
        }
      }
    }
    __syncthreads();
    short8 bv = *reinterpret_cast<const short8*>(&vT[(w*16+lr)*40 + lk*8]);
    short8 a0 = *reinterpret_cast<const short8*>(&kfS[(w*16+lr)*40 + lk*8]);
    short8 a4 = *reinterpret_cast<const short8*>(&kfS[(64+lr)*40 + lk*8]);
    ksc0 = MFMA16(a0, ones8, ksc0);
    ksc1 = MFMA16(a4, ones8, ksc1);
    #pragma unroll
    for(int fl=0;fl<5;fl++){
      short8 a_ = *reinterpret_cast<const short8*>(&kfS[(fl*16+lr)*40 + lk*8]);
      ctx[fl] = MFMA16(a_, bv, ctx[fl]);
    }
  }
  float* P = ctxP + ((size_t)(qh*128 + bh))*65*320;
  #pragma unroll
  for(int fl=0;fl<5;fl++){
    #pragma unroll
    for(int r=0;r<4;r++){
      int m = (F0+fl)*16 + lk*4 + r;
      P[(size_t)(w*16+lr)*320 + m] = ctx[fl][r];
    }
  }
  if(lr==0){
    #pragma unroll
    for(int r=0;r<4;r++){
      int m = (F0+w)*16 + lk*4 + r;
      P[(size_t)64*320 + m] = ksc0[r];
    }
    if(w==0){
      #pragma unroll
      for(int r=0;r<4;r++){
        int m = (F0+4)*16 + lk*4 + r;
        P[(size_t)64*320 + m] = ksc1[r];
      }
    }
  }
}

// ---------------- reduce 2 fp32 partials -> bf16 ctxT[bh][80][288]
__global__ __launch_bounds__(256) void ctx_reduce(const float* __restrict__ ctxP, short* __restrict__ ctxT){
  int row = blockIdx.x, bh = blockIdx.y, t = threadIdx.x;
  short* o = ctxT + ((size_t)bh*80 + row)*288;
  if(row < 65){
    const float* P0 = ctxP + ((size_t)bh*65 + row)*320;
    const float* P1 = ctxP + ((size_t)(128+bh)*65 + row)*320;
    for(int m=t; m<288; m+=256)
      o[m] = (m<272)? f2b(P0[m]+P1[m]) : (short)0;
  } else {
    for(int m=t; m<288; m+=256) o[m] = 0;
  }
}

// ---------------- qside fused (bf16 q in, bf16 o out)
__global__ __launch_bounds__(256) void qside_mfma(
    const short* __restrict__ qbf, const short* __restrict__ projbf,
    const short* __restrict__ ctxT, short* __restrict__ obf){
  __shared__ short qS[64*72];
  __shared__ short qfS[64*296];
  __shared__ float diagS[64];
  int t=threadIdx.x, l=t&63, w=t>>6, lr=l&15, lk=l>>4;
  int n0 = blockIdx.x*64, bh = blockIdx.y;
  int b = bh>>2, h = bh&3;
  const short8 z8 = {0,0,0,0,0,0,0,0};
  {
    int r = t>>2, c8 = (t&3)*16;
    int gn = n0 + r;
    float ssq = 0.f;
    #pragma unroll
    for(int i=0;i<2;i++){
      short8 v8 = z8;
      if(gn<NSEQ) v8 = *reinterpret_cast<const short8*>(qbf + ((size_t)(b*NSEQ+gn))*DIM + h*DH + c8 + i*8);
      #pragma unroll
      for(int u=0;u<8;u++){ float fv=b2f(v8[u]); ssq += fv*fv; }
      *reinterpret_cast<short8*>(&qS[r*72+c8+i*8]) = v8;
    }
    ssq += __shfl_xor(ssq,1); ssq += __shfl_xor(ssq,2);
    if((t&3)==0) diagS[r] = 0.0625f*ssq;
    #pragma unroll
    for(int i=0;i<4;i++) qfS[r*296 + 272 + (t&3)*4 + i] = 0;
  }
  __syncthreads();
  short8 aq[2];
  #pragma unroll
  for(int ks=0;ks<2;ks++) aq[ks] = *reinterpret_cast<const short8*>(&qS[(w*16+lr)*72 + ks*32 + lk*8]);
  f32x4 acc[17];
  #pragma unroll
  for(int f=0;f<17;f++) acc[f]=f32x4{0.f,0.f,0.f,0.f};
  #pragma unroll
  for(int f=0;f<17;f++){
    #pragma unroll
    for(int ks=0;ks<2;ks++){
      short8 bp = *reinterpret_cast<const short8*>(projbf + (f*16+lr)*64 + ks*32 + lk*8);
      acc[f] = MFMA16(aq[ks], bp, acc[f]);
    }
  }
  float rmax[4];
  #pragma unroll
  for(int r=0;r<4;r++){
    float m = -3.0e38f;
    #pragma unroll
    for(int f=0;f<17;f++){
      float v = (f==16 && lr>=10)? -3.0e38f : acc[f][r];
      m = fmaxf(m,v);
    }
    m = fmaxf(m,__shfl_xor(m,1)); m = fmaxf(m,__shfl_xor(m,2));
    m = fmaxf(m,__shfl_xor(m,4)); m = fmaxf(m,__shfl_xor(m,8));
    rmax[r]=m;
  }
  float dg[4];
  #pragma unroll
  for(int r=0;r<4;r++) dg[r] = diagS[w*16 + lk*4 + r];
  #pragma unroll
  for(int f=0;f<17;f++)
    #pragma unroll
    for(int r=0;r<4;r++){
      float qv = RATIOC*(__expf(acc[f][r] - dg[r] - rmax[r]) + 1e-4f);
      qfS[(w*16+lk*4+r)*296 + f*16 + lr] = f2b(qv);
    }
  __syncthreads();
  f32x4 pv[5];
  #pragma unroll
  for(int f=0;f<5;f++) pv[f]=f32x4{0.f,0.f,0.f,0.f};
  const short* cT = ctxT + (size_t)bh*80*288;
  for(int ks=0;ks<9;ks++){
    short8 a_ = *reinterpret_cast<const short8*>(&qfS[(w*16+lr)*296 + ks*32 + lk*8]);
    #pragma unroll
    for(int f=0;f<5;f++){
      short8 bb = *reinterpret_cast<const short8*>(cT + (f*16+lr)*288 + ks*32 + lk*8);
      pv[f] = MFMA16(a_, bb, pv[f]);
    }
  }
  #pragma unroll
  for(int r=0;r<4;r++){
    int gn = n0 + w*16 + lk*4 + r;
    if(gn>=NSEQ) continue;
    float den = __shfl(pv[4][r], (l & 48), 64);
    float inv = 1.0f/den;
    size_t obase = ((size_t)(b*NSEQ+gn))*DIM + h*DH;
    #pragma unroll
    for(int f=0;f<4;f++) obf[obase + f*16 + lr] = f2b(pv[f][r]*inv);
  }
}

// ---------------- small row projection (fp32)
__global__ __launch_bounds__(256) void rowproj_kernel(const float* __restrict__ src,
    const float* __restrict__ W, const float* __restrict__ bias,
    float* __restrict__ dst, int rowstride){
  __shared__ float rs[DIM];
  int b=blockIdx.x, t=threadIdx.x;
  rs[t]=src[(size_t)b*rowstride+t];
  __syncthreads();
  float s=bias[t];
  for(int j=0;j<DIM;j++) s += rs[j]*W[(size_t)j*DIM+t];
  dst[(size_t)b*DIM+t]=s;
}

// ---------------- final pooling: pass 1 — raw scores (grid 8 x NB)
__global__ __launch_bounds__(256) void pool_scores(const float* __restrict__ qfin,
    const short* __restrict__ kk, float* __restrict__ scb){
  __shared__ float qsh[DIM];
  int kc=blockIdx.x, b=blockIdx.y, t=threadIdx.x;
  qsh[t]=qfin[b*DIM+t];
  __syncthreads();
  int kidx = kc*256 + t;
  const short* kr = kk + ((size_t)(b*NSEQ+1+kidx))*DIM;
  float s=0;
  for(int j8=0;j8<32;j8++){
    short8 kv = *reinterpret_cast<const short8*>(kr + j8*8);
    #pragma unroll
    for(int u=0;u<8;u++) s += qsh[j8*8+u]*b2f(kv[u]);
  }
  scb[(size_t)b*KG + kidx] = s*0.0625f;
}

// ---------------- final pooling: pass 2 — softmax + PV (grid NB)
__global__ __launch_bounds__(256) void pool_pv(const float* __restrict__ scb,
    const short* __restrict__ vv, float* __restrict__ pooled){
  __shared__ float sc[KG];
  __shared__ float red[4];
  int b=blockIdx.x, t=threadIdx.x;
  float ls[8]; float lmax=-3.4e38f;
  #pragma unroll
  for(int i=0;i<8;i++){
    ls[i] = scb[(size_t)b*KG + t + i*256];
    lmax = fmaxf(lmax, ls[i]);
  }
  float gmax=blockMax256(lmax,red);
  float lsum=0;
  #pragma unroll
  for(int i=0;i<8;i++){ float e=__expf(ls[i]-gmax); sc[t+i*256]=e; lsum+=e; }
  float gsum=blockSum256(lsum,red);
  __syncthreads();
  float inv=1.0f/gsum;
  float p=0;
  for(int kidx=0;kidx<KG;kidx++) p += sc[kidx]*b2f(vv[((size_t)(b*NSEQ+1+kidx))*DIM + t]);
  pooled[b*DIM+t]=p*inv;
}

extern "C" void kernel_launch(void* const* d_in, const int* in_sizes, int n_in,
                              void* d_out, int out_size, void* d_ws, size_t ws_size,
                              hipStream_t stream){
  const float* expr   =(const float*)d_in[0];
  const float* coords =(const float*)d_in[1];
  const float* gene_emb=(const float*)d_in[2];
  const float* pos_emb=(const float*)d_in[3];
  const float* val_w  =(const float*)d_in[4];
  const float* val_b  =(const float*)d_in[5];
  const float* val_g  =(const float*)d_in[6];
  const float* val_bb =(const float*)d_in[7];
  const float* sp_w   =(const float*)d_in[8];
  const float* sp_b   =(const float*)d_in[9];
  const float* sp_g   =(const float*)d_in[10];
  const float* sp_bb  =(const float*)d_in[11];
  const float* p_ln1_g=(const float*)d_in[12];
  const float* p_ln1_b=(const float*)d_in[13];
  const float* p_wq   =(const float*)d_in[14];
  const float* p_bq   =(const float*)d_in[15];
  const float* p_wk   =(const float*)d_in[16];
  const float* p_bk   =(const float*)d_in[17];
  const float* p_wv   =(const float*)d_in[18];
  const float* p_bv   =(const float*)d_in[19];
  const float* p_wo   =(const float*)d_in[20];
  const float* p_bo   =(const float*)d_in[21];
  const float* p_ln2_g=(const float*)d_in[22];
  const float* p_ln2_b=(const float*)d_in[23];
  const float* p_ff1_w=(const float*)d_in[24];
  const float* p_ff1_b=(const float*)d_in[25];
  const float* p_ff2_w=(const float*)d_in[26];
  const float* p_ff2_b=(const float*)d_in[27];
  const float* proj   =(const float*)d_in[28];
  const float* q_w    =(const float*)d_in[29];
  const float* q_b    =(const float*)d_in[30];
  const float* k_w    =(const float*)d_in[31];
  const float* k_b    =(const float*)d_in[32];
  const float* v_w    =(const float*)d_in[33];
  const float* v_b    =(const float*)d_in[34];
  const float* o_w    =(const float*)d_in[35];
  const float* o_b    =(const float*)d_in[36];
  float* out = (float*)d_out;

  const size_t BND = (size_t)BN*DIM;     // 16,785,408
  size_t needB = BND*4 + BND*2*4
               + ((size_t)NB*NH*NSEQ + 4 + 2*(size_t)NB*DIM)*4
               + ((size_t)20480 + 2949120 + 1703936)*2;
  if(ws_size < needB){
    hipMemsetAsync(d_out, 0, (size_t)out_size*sizeof(float), stream);
    return;
  }
  float* ws = (float*)d_ws;
  float* x  = ws;                                  // BND fp32
  short* ybf = (short*)(x + BND);
  short* qbf = ybf + BND;
  short* kbf = qbf + BND;
  short* vbf = kbf + BND;
  float* diagk = (float*)(vbf + BND);
  unsigned* kmax = (unsigned*)(diagk + (size_t)NB*NH*NSEQ);
  float* qfin   = (float*)(kmax+4);
  float* pooled = qfin + NB*DIM;
  short* projbf = (short*)(pooled + NB*DIM);       // 320*64 = 20480
  short* ctxT   = projbf + 20480;                  // 128*80*288
  short* wt     = ctxT + (size_t)128*80*288;       // 1,703,936
  const size_t LW = 786432;
  float* ctxP = (float*)ybf;   // fp32 partials in dead ybf region (21.3MB <= 33.6MB)
  float* scb  = diagk;         // pool scores scratch (dead after layers, 64K <= 262K floats)

  for(int l=0;l<2;l++){
    short* wl = wt + (size_t)l*LW;
    wprep<<<256,256,0,stream>>>(p_wq +(size_t)l*DIM*DIM, wl,          DIM, DIM);
    wprep<<<256,256,0,stream>>>(p_wk +(size_t)l*DIM*DIM, wl+65536,    DIM, DIM);
    wprep<<<256,256,0,stream>>>(p_wv +(size_t)l*DIM*DIM, wl+131072,   DIM, DIM);
    wprep<<<256,256,0,stream>>>(p_wo +(size_t)l*DIM*DIM, wl+196608,   DIM, DIM);
    wprep<<<1024,256,0,stream>>>(p_ff1_w+(size_t)l*DIM*FFD, wl+262144, DIM, FFD);
    wprep<<<1024,256,0,stream>>>(p_ff2_w+(size_t)l*FFD*DIM, wl+524288, FFD, DIM);
  }
  short* wtkk = wt + 2*LW;
  short* wtvv = wtkk + 65536;
  wprep<<<256,256,0,stream>>>(k_w, wtkk, DIM, DIM);
  wprep<<<256,256,0,stream>>>(v_w, wtvv, DIM, DIM);

  embed_kernel<<<BN,256,0,stream>>>(expr,coords,gene_emb,pos_emb,val_w,val_b,val_g,val_bb,
                                    sp_w,sp_b,sp_g,sp_bb,x);

  dim3 gdd(2, (BN+127)/128);         // N=256 GEMMs over BN rows
  dim3 gff1(8, (FFROWS2+127)/128);   // N=1024
  dim3 gff2(2, (FFROWS2+127)/128);   // N=256, K=1024
  dim3 gkm(8, NB*NH);
  dim3 gkc(8, NB*NH);
  dim3 gcr(80, NB*NH);
  dim3 gq((NSEQ+63)/64, NB*NH);
  dim3 gps(8, NB);

  for(int l=0;l<2;l++){
    short* wl = wt + (size_t)l*LW;
    ln_bf4<<<BN/4,256,0,stream>>>(x, p_ln1_g+l*DIM, p_ln1_b+l*DIM, ybf);
    mgemm2<0,1><<<gdd,256,0,stream>>>(ybf, wl+65536,  p_bk+l*DIM, kbf, BN, DIM, DIM);
    mgemm2<0,1><<<gdd,256,0,stream>>>(ybf, wl+131072, p_bv+l*DIM, vbf, BN, DIM, DIM);
    mgemm2<0,1><<<gdd,256,0,stream>>>(ybf, wl,        p_bq+l*DIM, qbf, BN, DIM, DIM);
    diagk4<<<BN/4,256,0,stream>>>(kbf, diagk);
    projprep_kernel<<<80,256,0,stream>>>(proj + (size_t)l*MF*DH, projbf, kmax);
    kside_max<<<gkm,256,0,stream>>>(kbf, projbf, kmax);
    kside_ctx<<<gkc,256,0,stream>>>(kbf, vbf, projbf, diagk, kmax, ctxP);
    ctx_reduce<<<gcr,256,0,stream>>>(ctxP, ctxT);
    qside_mfma<<<gq,256,0,stream>>>(qbf, projbf, ctxT, kbf);   // o -> kbf (k dead)
    mgemm2<1,0><<<gdd,256,0,stream>>>(kbf, wl+196608, p_bo+l*DIM, x, BN, DIM, DIM);
    ln_bf4<<<BN/4,256,0,stream>>>(x, p_ln2_g+l*DIM, p_ln2_b+l*DIM, ybf);
    for(int c2=0;c2<2;c2++){
      size_t roff=(size_t)c2*FFROWS2;
      mgemm2<2,1><<<gff1,256,0,stream>>>(ybf+roff*DIM, wl+262144, p_ff1_b+l*FFD, qbf,
                                         FFROWS2, FFD, DIM);
      mgemm2<1,0><<<gff2,256,0,stream>>>(qbf, wl+524288, p_ff2_b+l*DIM, x+roff*DIM,
                                         FFROWS2, DIM, FFD);
    }
  }

  // final pooling attention
  castbf<<<(int)(BND/1024),256,0,stream>>>(x, ybf);
  mgemm2<0,1><<<gdd,256,0,stream>>>(ybf, wtkk, k_b, kbf, BN, DIM, DIM);
  mgemm2<0,1><<<gdd,256,0,stream>>>(ybf, wtvv, v_b, vbf, BN, DIM, DIM);
  rowproj_kernel<<<NB,256,0,stream>>>(x, q_w, q_b, qfin, NSEQ*DIM);
  pool_scores<<<gps,256,0,stream>>>(qfin, kbf, scb);
  pool_pv<<<NB,256,0,stream>>>(scb, vbf, pooled);
  rowproj_kernel<<<NB,256,0,stream>>>(pooled, o_w, o_b, out, DIM);
}

// Round 9
// 1769.714 us; speedup vs baseline: 8.9880x; 1.0135x over previous
//
#include <hip/hip_runtime.h>
#include <hip/hip_bf16.h>
#include <math.h>

#define NB   32
#define KG   2048
#define NSEQ 2049
#define DIM  256
#define NH   4
#define DH   64
#define MF   266
#define FFD  1024
#define BN   (NB*NSEQ)          // 65568
#define FFROWS2 32784           // BN/2
#define NORMC 0.35355339059327376f   // 64^-0.25
#define RATIOC (1.0f/16.309506430300091f) // 266^-0.5

typedef __attribute__((ext_vector_type(8))) short short8;
typedef __attribute__((ext_vector_type(4))) float f32x4;
#define MFMA16(a,b,c) __builtin_amdgcn_mfma_f32_16x16x32_bf16(a,b,c,0,0,0)

__device__ __forceinline__ short f2b(float f){
  union{ __hip_bfloat16 h; short s;} u; u.h = __float2bfloat16(f); return u.s;
}
__device__ __forceinline__ float b2f(short s){
  union{ short s; __hip_bfloat16 h;} u; u.s = s; return __bfloat162float(u.h);
}
__device__ __forceinline__ float gelu_f(float x){
  return 0.5f*x*(1.0f+erff(x*0.70710678118654752f));
}
__device__ __forceinline__ void gload16(const short* g, short* l){
  __builtin_amdgcn_global_load_lds(
      (const __attribute__((address_space(1))) void*)g,
      (__attribute__((address_space(3))) void*)l, 16, 0, 0);
}
__device__ __forceinline__ float waveSum(float v){
  #pragma unroll
  for(int o=32;o>0;o>>=1) v += __shfl_down(v,o);
  return v;   // lane 0 only
}
__device__ __forceinline__ float waveMax(float v){
  #pragma unroll
  for(int o=32;o>0;o>>=1) v = fmaxf(v,__shfl_down(v,o));
  return v;   // lane 0 only
}
__device__ __forceinline__ float xorSum64(float v){
  v += __shfl_xor(v,32); v += __shfl_xor(v,16); v += __shfl_xor(v,8);
  v += __shfl_xor(v,4);  v += __shfl_xor(v,2);  v += __shfl_xor(v,1);
  return v;   // exact, all lanes
}
__device__ __forceinline__ float blockSum256(float v, float* red){
  int lane = threadIdx.x & 63, wid = threadIdx.x >> 6;
  v = waveSum(v);
  __syncthreads();
  if(lane==0) red[wid]=v;
  __syncthreads();
  return red[0]+red[1]+red[2]+red[3];
}
__device__ __forceinline__ float blockMax256(float v, float* red){
  int lane = threadIdx.x & 63, wid = threadIdx.x >> 6;
  v = waveMax(v);
  __syncthreads();
  if(lane==0) red[wid]=v;
  __syncthreads();
  return fmaxf(fmaxf(red[0],red[1]),fmaxf(red[2],red[3]));
}
__device__ __forceinline__ unsigned fenc(float f){
  unsigned u = __float_as_uint(f);
  return (u & 0x80000000u) ? ~u : (u | 0x80000000u);
}
__device__ __forceinline__ float fdec(unsigned u){
  return (u & 0x80000000u) ? __uint_as_float(u & 0x7FFFFFFFu) : __uint_as_float(~u);
}

// ---------------- embed v2: wave-per-row, 4 rows/block, xor-exact
__global__ __launch_bounds__(256) void embed_kernel(
    const float* __restrict__ expr, const float* __restrict__ coords,
    const float* __restrict__ gene_emb, const float* __restrict__ pos_emb,
    const float* __restrict__ val_w, const float* __restrict__ val_b,
    const float* __restrict__ val_g, const float* __restrict__ val_bb,
    const float* __restrict__ sp_w, const float* __restrict__ sp_b,
    const float* __restrict__ sp_g, const float* __restrict__ sp_bb,
    float* __restrict__ x){
  int w = threadIdx.x >> 6, l = threadIdx.x & 63;
  int row = blockIdx.x*4 + w;
  int b = row / NSEQ, n = row % NSEQ;
  int d0 = l*4;
  float4 v;
  if(n==0){
    float c0 = coords[b*2], c1 = coords[b*2+1];
    float4 w0 = *reinterpret_cast<const float4*>(sp_w + d0);
    float4 w1 = *reinterpret_cast<const float4*>(sp_w + DIM + d0);
    float4 bb = *reinterpret_cast<const float4*>(sp_b + d0);
    v = make_float4(c0*w0.x+c1*w1.x+bb.x, c0*w0.y+c1*w1.y+bb.y,
                    c0*w0.z+c1*w1.z+bb.z, c0*w0.w+c1*w1.w+bb.w);
  } else {
    float e = expr[(size_t)b*KG + (n-1)];
    float4 vw = *reinterpret_cast<const float4*>(val_w + d0);
    float4 vb = *reinterpret_cast<const float4*>(val_b + d0);
    v = make_float4(e*vw.x+vb.x, e*vw.y+vb.y, e*vw.z+vb.z, e*vw.w+vb.w);
  }
  float mu = xorSum64(v.x+v.y+v.z+v.w)*(1.0f/DIM);
  float cx=v.x-mu, cy=v.y-mu, cz=v.z-mu, cw=v.w-mu;
  float var = xorSum64(cx*cx+cy*cy+cz*cz+cw*cw)*(1.0f/DIM);
  float r = rsqrtf(var + 1e-5f);
  float4 g  = (n==0)? *reinterpret_cast<const float4*>(sp_g + d0)
                    : *reinterpret_cast<const float4*>(val_g + d0);
  float4 be = (n==0)? *reinterpret_cast<const float4*>(sp_bb + d0)
                    : *reinterpret_cast<const float4*>(val_bb + d0);
  float4 h = make_float4(gelu_f(cx*r*g.x+be.x), gelu_f(cy*r*g.y+be.y),
                         gelu_f(cz*r*g.z+be.z), gelu_f(cw*r*g.w+be.w));
  if(n!=0){
    float4 ge = *reinterpret_cast<const float4*>(gene_emb + (size_t)(n-1)*DIM + d0);
    float4 pe = *reinterpret_cast<const float4*>(pos_emb  + (size_t)(n-1)*DIM + d0);
    h.x += ge.x+pe.x; h.y += ge.y+pe.y; h.z += ge.z+pe.z; h.w += ge.w+pe.w;
  }
  *reinterpret_cast<float4*>(x + (size_t)row*DIM + d0) = h;
}

// ---------------- LN -> bf16, wave-per-row, xor-exact
__global__ __launch_bounds__(256) void ln_bf4(const float* __restrict__ xin,
    const float* __restrict__ g, const float* __restrict__ bb, short* __restrict__ ybf){
  int w = threadIdx.x >> 6, l = threadIdx.x & 63;
  int row = blockIdx.x*4 + w;
  const float* xr = xin + (size_t)row*DIM;
  float4 v = *reinterpret_cast<const float4*>(xr + l*4);
  float s = xorSum64(v.x+v.y+v.z+v.w);
  float mu = s*(1.0f/DIM);
  float cx=v.x-mu, cy=v.y-mu, cz=v.z-mu, cw=v.w-mu;
  float var = xorSum64(cx*cx+cy*cy+cz*cz+cw*cw)*(1.0f/DIM);
  float r = rsqrtf(var+1e-5f);
  const float4 gv = *reinterpret_cast<const float4*>(g + l*4);
  const float4 bv = *reinterpret_cast<const float4*>(bb + l*4);
  short4 o = make_short4(f2b(cx*r*gv.x+bv.x), f2b(cy*r*gv.y+bv.y),
                         f2b(cz*r*gv.z+bv.z), f2b(cw*r*gv.w+bv.w));
  *reinterpret_cast<short4*>(ybf + (size_t)row*DIM + l*4) = o;
}

// ---------------- diag_k, wave-per-row (16-lane xor groups)
__global__ __launch_bounds__(256) void diagk4(const short* __restrict__ kbf, float* __restrict__ diagk){
  int w = threadIdx.x >> 6, l = threadIdx.x & 63;
  int row = blockIdx.x*4 + w;
  int b = row / NSEQ, n = row % NSEQ;
  short4 v = *reinterpret_cast<const short4*>(kbf + (size_t)row*DIM + l*4);
  float a0=b2f(v.x), a1=b2f(v.y), a2=b2f(v.z), a3=b2f(v.w);
  float s = a0*a0+a1*a1+a2*a2+a3*a3;
  s += __shfl_xor(s,1); s += __shfl_xor(s,2);
  s += __shfl_xor(s,4); s += __shfl_xor(s,8);
  if((l&15)==0){
    int h = l>>4;
    diagk[((size_t)(b*NH+h))*NSEQ + n] = 0.0625f*s;
  }
}

// ---------------- fp32 -> bf16 cast
__global__ __launch_bounds__(256) void castbf(const float* __restrict__ in, short* __restrict__ out){
  size_t i = ((size_t)blockIdx.x*256 + threadIdx.x)*4;
  float4 v = *reinterpret_cast<const float4*>(in+i);
  *reinterpret_cast<short4*>(out+i) = make_short4(f2b(v.x),f2b(v.y),f2b(v.z),f2b(v.w));
}

// ---------------- fused weight prep: 14 matrices, 32x32 LDS tile transpose
#define NW 14
struct WPArgs {
  const float* src[NW];
  short* dst[NW];
  int K[NW], N[NW];
  int ts[NW+1];     // cumulative tile starts
};
__global__ __launch_bounds__(256) void wprep_fused(WPArgs a){
  __shared__ float tile[32][33];
  int bx = blockIdx.x, t = threadIdx.x;
  int i = 0;
  while(bx >= a.ts[i+1]) i++;
  int tl = bx - a.ts[i];
  int N = a.N[i], K = a.K[i];
  int tcols = N >> 5;
  int tr = tl / tcols, tc = tl - tr*tcols;
  const float* src = a.src[i];
  short* dst = a.dst[i];
  int r = t>>3, c4 = (t&7)*4;
  float4 v = *reinterpret_cast<const float4*>(src + (size_t)(tr*32+r)*N + tc*32 + c4);
  tile[r][c4+0]=v.x; tile[r][c4+1]=v.y; tile[r][c4+2]=v.z; tile[r][c4+3]=v.w;
  __syncthreads();
  short4 o = make_short4(f2b(tile[c4+0][r]), f2b(tile[c4+1][r]),
                         f2b(tile[c4+2][r]), f2b(tile[c4+3][r]));
  *reinterpret_cast<short4*>(dst + (size_t)(tc*32+r)*K + tr*32 + c4) = o;
}

// ---------------- MFMA GEMM v3: global_load_lds staging, linear LDS [128][32]
template<int EPI, int OBF>
__global__ __launch_bounds__(256) void mgemm2(
    const short* __restrict__ A, const short* __restrict__ Bt,
    const float* __restrict__ bias, void* __restrict__ Cv,
    int M, int N, int Kd){
  __shared__ short As[128*32];
  __shared__ short Bs[128*32];
  int t=threadIdx.x, l=t&63, w=t>>6, lr=l&15, lk=l>>4;
  int wm=w>>1, wn=w&1;
  int m0=blockIdx.y*128, n0=blockIdx.x*128;
  f32x4 acc[4][4];
  #pragma unroll
  for(int i=0;i<4;i++)
    #pragma unroll
    for(int j=0;j<4;j++) acc[i][j]=f32x4{0.f,0.f,0.f,0.f};
  for(int k0=0;k0<Kd;k0+=32){
    #pragma unroll
    for(int p=0;p<2;p++){
      int chunk = p*256 + t;
      int row = chunk>>2, qc = chunk&3;
      short* lbase = &As[(size_t)(p*256 + w*64)*8];
      gload16(A + (size_t)(m0+row)*Kd + k0 + qc*8, lbase);
    }
    #pragma unroll
    for(int p=0;p<2;p++){
      int chunk = p*256 + t;
      int row = chunk>>2, qc = chunk&3;
      short* lbase = &Bs[(size_t)(p*256 + w*64)*8];
      gload16(Bt + (size_t)(n0+row)*Kd + k0 + qc*8, lbase);
    }
    __syncthreads();
    short8 af[4], bfr[4];
    #pragma unroll
    for(int i=0;i<4;i++) af[i] = *reinterpret_cast<const short8*>(&As[(wm*64+i*16+lr)*32 + lk*8]);
    #pragma unroll
    for(int j=0;j<4;j++) bfr[j] = *reinterpret_cast<const short8*>(&Bs[(wn*64+j*16+lr)*32 + lk*8]);
    #pragma unroll
    for(int i=0;i<4;i++)
      #pragma unroll
      for(int j=0;j<4;j++) acc[i][j] = MFMA16(af[i], bfr[j], acc[i][j]);
    __syncthreads();
  }
  #pragma unroll
  for(int i=0;i<4;i++){
    int gm0 = m0 + wm*64 + i*16 + lk*4;
    #pragma unroll
    for(int j=0;j<4;j++){
      int gc = n0 + wn*64 + j*16 + lr;
      float bs = bias[gc];
      #pragma unroll
      for(int r=0;r<4;r++){
        int gm = gm0 + r;
        if(gm<M){
          float vv = acc[i][j][r] + bs;
          if(EPI==2) vv = gelu_f(vv);
          size_t idx = (size_t)gm*N + gc;
          if(OBF){
            ((short*)Cv)[idx] = f2b(vv);
          } else {
            float* C = (float*)Cv;
            if(EPI==1) vv += C[idx];
            C[idx] = vv;
          }
        }
      }
    }
  }
}

// ---------------- projbf: bf16(proj * NORMC), 320 rows (pad zero); init kmax
__global__ __launch_bounds__(256) void projprep_kernel(const float* __restrict__ proj,
    short* __restrict__ projbf, unsigned* __restrict__ kmax){
  int i = blockIdx.x*256 + threadIdx.x;
  if(i==0) *kmax = 0u;
  if(i < 320*64){
    int m = i>>6, d = i&63;
    float v = (m<MF)? proj[(size_t)m*DH + d]*NORMC : 0.f;
    projbf[i] = f2b(v);
  }
}

// ---------------- kside pass0: global max of xd_k, 8-way n-split
__global__ __launch_bounds__(256) void kside_max(
    const short* __restrict__ kbf, const short* __restrict__ projbf,
    unsigned* __restrict__ kmax){
  __shared__ short kS[32*72];
  __shared__ float red[4];
  int t=threadIdx.x, l=t&63, w=t>>6, lr=l&15, lk=l>>4;
  int split = blockIdx.x, bh = blockIdx.y;
  int b=bh>>2, h=bh&3;
  int c0 = split*9, c1 = min(c0+9, 65);
  int nf = (w==3)?5:4;
  short8 apf[5][2];
  #pragma unroll
  for(int fi=0;fi<5;fi++){
    int fr = (fi<4)? (fi*4+w) : 16;
    #pragma unroll
    for(int ks=0;ks<2;ks++)
      apf[fi][ks] = *reinterpret_cast<const short8*>(projbf + (fr*16+lr)*64 + ks*32 + lk*8);
  }
  const short8 z8 = {0,0,0,0,0,0,0,0};
  float lmax = -3.0e38f;
  for(int ch=c0; ch<c1; ++ch){
    int n0 = ch*32;
    __syncthreads();
    {
      int r = t>>3, c8 = (t&7)*8;
      int gn = n0 + r;
      short8 v8 = z8;
      if(gn<NSEQ) v8 = *reinterpret_cast<const short8*>(kbf + ((size_t)(b*NSEQ+gn))*DIM + h*DH + c8);
      *reinterpret_cast<short8*>(&kS[r*72+c8]) = v8;
    }
    __syncthreads();
    for(int fi=0;fi<nf;fi++){
      int fr = (fi<4)? (fi*4+w) : 16;
      #pragma unroll
      for(int fn=0;fn<2;fn++){
        f32x4 xa = f32x4{0.f,0.f,0.f,0.f};
        #pragma unroll
        for(int ks=0;ks<2;ks++){
          short8 bk = *reinterpret_cast<const short8*>(&kS[(fn*16+lr)*72 + ks*32 + lk*8]);
          xa = MFMA16(apf[fi][ks], bk, xa);
        }
        #pragma unroll
        for(int r=0;r<4;r++){
          int m = fr*16 + lk*4 + r;
          int n = n0 + fn*16 + lr;
          if(m<MF && n<NSEQ) lmax = fmaxf(lmax, xa[r]);
        }
      }
    }
  }
  float bm = blockMax256(lmax, red);
  if(t==0) atomicMax(kmax, fenc(bm));
}

// ---------------- kside pass1: (f=4 x n=2) split, fp32 partials
__global__ __launch_bounds__(256) void kside_ctx(
    const short* __restrict__ kbf, const short* __restrict__ vbf,
    const short* __restrict__ projbf, const float* __restrict__ diagk,
    const unsigned* __restrict__ kmax, float* __restrict__ ctxP){
  __shared__ short kS[32*72];
  __shared__ short vT[64*40];
  __shared__ short kfS[80*40];
  __shared__ float diagS[32];
  int t=threadIdx.x, l=t&63, w=t>>6, lr=l&15, lk=l>>4;
  int fb=blockIdx.x&3, qh=blockIdx.x>>2, bh=blockIdx.y; int b=bh>>2, h=bh&3;
  int F0 = fb*5;
  int ch0 = qh*33, ch1 = min(65, ch0+33);
  float stab = fdec(*kmax);
  short8 apf0[2], apf1[2];
  #pragma unroll
  for(int ks=0;ks<2;ks++){
    apf0[ks] = *reinterpret_cast<const short8*>(projbf + ((F0+w)*16+lr)*64 + ks*32 + lk*8);
    apf1[ks] = *reinterpret_cast<const short8*>(projbf + ((F0+4)*16+lr)*64 + ks*32 + lk*8);
  }
  f32x4 ctx[5];
  #pragma unroll
  for(int f=0;f<5;f++) ctx[f]=f32x4{0.f,0.f,0.f,0.f};
  f32x4 ksc0 = f32x4{0.f,0.f,0.f,0.f};
  f32x4 ksc1 = f32x4{0.f,0.f,0.f,0.f};
  const short ONE=(short)0x3F80;
  const short8 ones8 = {ONE,ONE,ONE,ONE,ONE,ONE,ONE,ONE};
  const short8 z8 = {0,0,0,0,0,0,0,0};
  for(int ch=ch0; ch<ch1; ++ch){
    int n0 = ch*32;
    __syncthreads();
    {
      int r = t>>3, c8 = (t&7)*8;
      int gn = n0 + r;
      short8 v8 = z8;
      if(gn<NSEQ) v8 = *reinterpret_cast<const short8*>(kbf + ((size_t)(b*NSEQ+gn))*DIM + h*DH + c8);
      *reinterpret_cast<short8*>(&kS[r*72+c8]) = v8;
    }
    #pragma unroll
    for(int p=0;p<4;p++){
      int n2 = 2*w + 8*p;
      int dd = t&63;
      int gn0=n0+n2, gn1=gn0+1;
      short v0 = (gn0<NSEQ)? vbf[((size_t)(b*NSEQ+gn0))*DIM + h*DH + dd] : (short)0;
      short v1 = (gn1<NSEQ)? vbf[((size_t)(b*NSEQ+gn1))*DIM + h*DH + dd] : (short)0;
      *reinterpret_cast<short2*>(&vT[dd*40 + n2]) = make_short2(v0,v1);
    }
    if(t<32) diagS[t] = (n0+t<NSEQ)? diagk[(size_t)bh*NSEQ + n0+t] : 0.f;
    __syncthreads();
    #pragma unroll
    for(int fn=0;fn<2;fn++){
      f32x4 xa = f32x4{0.f,0.f,0.f,0.f};
      #pragma unroll
      for(int ks=0;ks<2;ks++){
        short8 bk = *reinterpret_cast<const short8*>(&kS[(fn*16+lr)*72 + ks*32 + lk*8]);
        xa = MFMA16(apf0[ks], bk, xa);
      }
      float dgn = diagS[fn*16+lr];
      #pragma unroll
      for(int r=0;r<4;r++){
        int m = (F0+w)*16 + lk*4 + r;
        int n = n0 + fn*16 + lr;
        float kf = (m<MF && n<NSEQ)? RATIOC*(__expf(xa[r]-dgn-stab)+1e-4f) : 0.f;
        kfS[(w*16+lk*4+r)*40 + fn*16 + lr] = f2b(kf);
      }
    }
    if(w==0){
      #pragma unroll
      for(int fn=0;fn<2;fn++){
        f32x4 xa = f32x4{0.f,0.f,0.f,0.f};
        #pragma unroll
        for(int ks=0;ks<2;ks++){
          short8 bk = *reinterpret_cast<const short8*>(&kS[(fn*16+lr)*72 + ks*32 + lk*8]);
          xa = MFMA16(apf1[ks], bk, xa);
        }
        float dgn = diagS[fn*16+lr];
        #pragma unroll
        for(int r=0;r<4;r++){
          int m = (F0+4)*16 + lk*4 + r;
          int n = n0 + fn*16 + lr;
          float kf = (m<MF && n<NSEQ)? RATIOC*(__expf(xa[r]-dgn-stab)+1e-4f) : 0.f;
          kfS[(64+lk*4+r)*40 + fn*16 + lr] = f2b(kf);
        }
      }
    }
    __syncthreads();
    short8 bv = *reinterpret_cast<const short8*>(&vT[(w*16+lr)*40 + lk*8]);
    short8 a0 = *reinterpret_cast<const short8*>(&kfS[(w*16+lr)*40 + lk*8]);
    short8 a4 = *reinterpret_cast<const short8*>(&kfS[(64+lr)*40 + lk*8]);
    ksc0 = MFMA16(a0, ones8, ksc0);
    ksc1 = MFMA16(a4, ones8, ksc1);
    #pragma unroll
    for(int fl=0;fl<5;fl++){
      short8 a_ = *reinterpret_cast<const short8*>(&kfS[(fl*16+lr)*40 + lk*8]);
      ctx[fl] = MFMA16(a_, bv, ctx[fl]);
    }
  }
  float* P = ctxP + ((size_t)(qh*128 + bh))*65*320;
  #pragma unroll
  for(int fl=0;fl<5;fl++){
    #pragma unroll
    for(int r=0;r<4;r++){
      int m = (F0+fl)*16 + lk*4 + r;
      P[(size_t)(w*16+lr)*320 + m] = ctx[fl][r];
    }
  }
  if(lr==0){
    #pragma unroll
    for(int r=0;r<4;r++){
      int m = (F0+w)*16 + lk*4 + r;
      P[(size_t)64*320 + m] = ksc0[r];
    }
    if(w==0){
      #pragma unroll
      for(int r=0;r<4;r++){
        int m = (F0+4)*16 + lk*4 + r;
        P[(size_t)64*320 + m] = ksc1[r];
      }
    }
  }
}

// ---------------- reduce 2 fp32 partials -> bf16 ctxT[bh][80][288]
__global__ __launch_bounds__(256) void ctx_reduce(const float* __restrict__ ctxP, short* __restrict__ ctxT){
  int row = blockIdx.x, bh = blockIdx.y, t = threadIdx.x;
  short* o = ctxT + ((size_t)bh*80 + row)*288;
  if(row < 65){
    const float* P0 = ctxP + ((size_t)bh*65 + row)*320;
    const float* P1 = ctxP + ((size_t)(128+bh)*65 + row)*320;
    for(int m=t; m<288; m+=256)
      o[m] = (m<272)? f2b(P0[m]+P1[m]) : (short)0;
  } else {
    for(int m=t; m<288; m+=256) o[m] = 0;
  }
}

// ---------------- qside v3: barrier-free, direct fragment loads, wave-local LDS
__global__ __launch_bounds__(256) void qside_mfma(
    const short* __restrict__ qbf, const short* __restrict__ projbf,
    const short* __restrict__ ctxT, short* __restrict__ obf){
  __shared__ short qfS[64*296];
  int t=threadIdx.x, l=t&63, w=t>>6, lr=l&15, lk=l>>4;
  int n0 = blockIdx.x*64, bh = blockIdx.y;
  int b = bh>>2, h = bh&3;
  const short8 z8 = {0,0,0,0,0,0,0,0};
  // A-fragments direct from global: row n0+w*16+lr, cols ks*32+lk*8 (16B each)
  int gn_a = n0 + w*16 + lr;
  const short* qrow = qbf + ((size_t)(b*NSEQ+gn_a))*DIM + h*DH;
  short8 aq[2];
  float ssq = 0.f;
  #pragma unroll
  for(int ks=0;ks<2;ks++){
    aq[ks] = (gn_a<NSEQ)? *reinterpret_cast<const short8*>(qrow + ks*32 + lk*8) : z8;
    #pragma unroll
    for(int u=0;u<8;u++){ float fv=b2f(aq[ks][u]); ssq += fv*fv; }
  }
  // full row-sum across lk lanes (bits 4,5 of lane id)
  ssq += __shfl_xor(ssq,16); ssq += __shfl_xor(ssq,32);
  // dg[r] for row w*16+lk*4+r lives in lane lk*4+r (lr==lk*4+r, lk'==0)
  float dg[4];
  #pragma unroll
  for(int r=0;r<4;r++) dg[r] = 0.0625f*__shfl(ssq, lk*4+r, 64);
  // zero qfS pad cols (wave-local rows)
  {
    int pr = w*16 + (l>>2), pc = 272 + (l&3)*4;
    #pragma unroll
    for(int i=0;i<4;i++) qfS[pr*296 + pc + i] = 0;
  }
  // xd = q @ projn^T
  f32x4 acc[17];
  #pragma unroll
  for(int f=0;f<17;f++) acc[f]=f32x4{0.f,0.f,0.f,0.f};
  #pragma unroll
  for(int f=0;f<17;f++){
    #pragma unroll
    for(int ks=0;ks<2;ks++){
      short8 bp = *reinterpret_cast<const short8*>(projbf + (f*16+lr)*64 + ks*32 + lk*8);
      acc[f] = MFMA16(aq[ks], bp, acc[f]);
    }
  }
  float rmax[4];
  #pragma unroll
  for(int r=0;r<4;r++){
    float m = -3.0e38f;
    #pragma unroll
    for(int f=0;f<17;f++){
      float v = (f==16 && lr>=10)? -3.0e38f : acc[f][r];
      m = fmaxf(m,v);
    }
    m = fmaxf(m,__shfl_xor(m,1)); m = fmaxf(m,__shfl_xor(m,2));
    m = fmaxf(m,__shfl_xor(m,4)); m = fmaxf(m,__shfl_xor(m,8));
    rmax[r]=m;
  }
  #pragma unroll
  for(int f=0;f<17;f++)
    #pragma unroll
    for(int r=0;r<4;r++){
      float qv = RATIOC*(__expf(acc[f][r] - dg[r] - rmax[r]) + 1e-4f);
      qfS[(w*16+lk*4+r)*296 + f*16 + lr] = f2b(qv);
    }
  // PV (wave-local qfS rows; no barrier needed)
  f32x4 pv[5];
  #pragma unroll
  for(int f=0;f<5;f++) pv[f]=f32x4{0.f,0.f,0.f,0.f};
  const short* cT = ctxT + (size_t)bh*80*288;
  for(int ks=0;ks<9;ks++){
    short8 a_ = *reinterpret_cast<const short8*>(&qfS[(w*16+lr)*296 + ks*32 + lk*8]);
    #pragma unroll
    for(int f=0;f<5;f++){
      short8 bb = *reinterpret_cast<const short8*>(cT + (f*16+lr)*288 + ks*32 + lk*8);
      pv[f] = MFMA16(a_, bb, pv[f]);
    }
  }
  #pragma unroll
  for(int r=0;r<4;r++){
    int gn = n0 + w*16 + lk*4 + r;
    if(gn>=NSEQ) continue;
    float den = __shfl(pv[4][r], (l & 48), 64);
    float inv = 1.0f/den;
    size_t obase = ((size_t)(b*NSEQ+gn))*DIM + h*DH;
    #pragma unroll
    for(int f=0;f<4;f++) obf[obase + f*16 + lr] = f2b(pv[f][r]*inv);
  }
}

// ---------------- small row projection (fp32)
__global__ __launch_bounds__(256) void rowproj_kernel(const float* __restrict__ src,
    const float* __restrict__ W, const float* __restrict__ bias,
    float* __restrict__ dst, int rowstride){
  __shared__ float rs[DIM];
  int b=blockIdx.x, t=threadIdx.x;
  rs[t]=src[(size_t)b*rowstride+t];
  __syncthreads();
  float s=bias[t];
  for(int j=0;j<DIM;j++) s += rs[j]*W[(size_t)j*DIM+t];
  dst[(size_t)b*DIM+t]=s;
}

// ---------------- final pooling: pass 1 — raw scores (grid 8 x NB)
__global__ __launch_bounds__(256) void pool_scores(const float* __restrict__ qfin,
    const short* __restrict__ kk, float* __restrict__ scb){
  __shared__ float qsh[DIM];
  int kc=blockIdx.x, b=blockIdx.y, t=threadIdx.x;
  qsh[t]=qfin[b*DIM+t];
  __syncthreads();
  int kidx = kc*256 + t;
  const short* kr = kk + ((size_t)(b*NSEQ+1+kidx))*DIM;
  float s=0;
  for(int j8=0;j8<32;j8++){
    short8 kv = *reinterpret_cast<const short8*>(kr + j8*8);
    #pragma unroll
    for(int u=0;u<8;u++) s += qsh[j8*8+u]*b2f(kv[u]);
  }
  scb[(size_t)b*KG + kidx] = s*0.0625f;
}

// ---------------- final pooling: pass 2 — softmax + PV (grid NB)
__global__ __launch_bounds__(256) void pool_pv(const float* __restrict__ scb,
    const short* __restrict__ vv, float* __restrict__ pooled){
  __shared__ float sc[KG];
  __shared__ float red[4];
  int b=blockIdx.x, t=threadIdx.x;
  float ls[8]; float lmax=-3.4e38f;
  #pragma unroll
  for(int i=0;i<8;i++){
    ls[i] = scb[(size_t)b*KG + t + i*256];
    lmax = fmaxf(lmax, ls[i]);
  }
  float gmax=blockMax256(lmax,red);
  float lsum=0;
  #pragma unroll
  for(int i=0;i<8;i++){ float e=__expf(ls[i]-gmax); sc[t+i*256]=e; lsum+=e; }
  float gsum=blockSum256(lsum,red);
  __syncthreads();
  float inv=1.0f/gsum;
  float p=0;
  for(int kidx=0;kidx<KG;kidx++) p += sc[kidx]*b2f(vv[((size_t)(b*NSEQ+1+kidx))*DIM + t]);
  pooled[b*DIM+t]=p*inv;
}

extern "C" void kernel_launch(void* const* d_in, const int* in_sizes, int n_in,
                              void* d_out, int out_size, void* d_ws, size_t ws_size,
                              hipStream_t stream){
  const float* expr   =(const float*)d_in[0];
  const float* coords =(const float*)d_in[1];
  const float* gene_emb=(const float*)d_in[2];
  const float* pos_emb=(const float*)d_in[3];
  const float* val_w  =(const float*)d_in[4];
  const float* val_b  =(const float*)d_in[5];
  const float* val_g  =(const float*)d_in[6];
  const float* val_bb =(const float*)d_in[7];
  const float* sp_w   =(const float*)d_in[8];
  const float* sp_b   =(const float*)d_in[9];
  const float* sp_g   =(const float*)d_in[10];
  const float* sp_bb  =(const float*)d_in[11];
  const float* p_ln1_g=(const float*)d_in[12];
  const float* p_ln1_b=(const float*)d_in[13];
  const float* p_wq   =(const float*)d_in[14];
  const float* p_bq   =(const float*)d_in[15];
  const float* p_wk   =(const float*)d_in[16];
  const float* p_bk   =(const float*)d_in[17];
  const float* p_wv   =(const float*)d_in[18];
  const float* p_bv   =(const float*)d_in[19];
  const float* p_wo   =(const float*)d_in[20];
  const float* p_bo   =(const float*)d_in[21];
  const float* p_ln2_g=(const float*)d_in[22];
  const float* p_ln2_b=(const float*)d_in[23];
  const float* p_ff1_w=(const float*)d_in[24];
  const float* p_ff1_b=(const float*)d_in[25];
  const float* p_ff2_w=(const float*)d_in[26];
  const float* p_ff2_b=(const float*)d_in[27];
  const float* proj   =(const float*)d_in[28];
  const float* q_w    =(const float*)d_in[29];
  const float* q_b    =(const float*)d_in[30];
  const float* k_w    =(const float*)d_in[31];
  const float* k_b    =(const float*)d_in[32];
  const float* v_w    =(const float*)d_in[33];
  const float* v_b    =(const float*)d_in[34];
  const float* o_w    =(const float*)d_in[35];
  const float* o_b    =(const float*)d_in[36];
  float* out = (float*)d_out;

  const size_t BND = (size_t)BN*DIM;     // 16,785,408
  size_t needB = BND*4 + BND*2*4
               + ((size_t)NB*NH*NSEQ + 4 + 2*(size_t)NB*DIM)*4
               + ((size_t)20480 + 2949120 + 1703936)*2;
  if(ws_size < needB){
    hipMemsetAsync(d_out, 0, (size_t)out_size*sizeof(float), stream);
    return;
  }
  float* ws = (float*)d_ws;
  float* x  = ws;                                  // BND fp32
  short* ybf = (short*)(x + BND);
  short* qbf = ybf + BND;
  short* kbf = qbf + BND;
  short* vbf = kbf + BND;
  float* diagk = (float*)(vbf + BND);
  unsigned* kmax = (unsigned*)(diagk + (size_t)NB*NH*NSEQ);
  float* qfin   = (float*)(kmax+4);
  float* pooled = qfin + NB*DIM;
  short* projbf = (short*)(pooled + NB*DIM);       // 320*64
  short* ctxT   = projbf + 20480;                  // 128*80*288
  short* wt     = ctxT + (size_t)128*80*288;       // 1,703,936
  const size_t LW = 786432;
  float* ctxP = (float*)ybf;   // fp32 partials in dead ybf region
  float* scb  = diagk;         // pool scores scratch

  // ---- fused weight prep: 10 x 256x256 (64 tiles) + 4 x FF (256 tiles)
  {
    WPArgs a;
    short* wtkk = wt + 2*LW;
    short* wtvv = wtkk + 65536;
    const float* s10[10] = {p_wq, p_wk, p_wv, p_wo,
                            p_wq+(size_t)DIM*DIM, p_wk+(size_t)DIM*DIM,
                            p_wv+(size_t)DIM*DIM, p_wo+(size_t)DIM*DIM,
                            k_w, v_w};
    short* d10[10] = {wt, wt+65536, wt+131072, wt+196608,
                      wt+LW, wt+LW+65536, wt+LW+131072, wt+LW+196608,
                      wtkk, wtvv};
    int ti = 0;
    for(int i=0;i<10;i++){
      a.src[i]=s10[i]; a.dst[i]=d10[i]; a.K[i]=DIM; a.N[i]=DIM;
      a.ts[i]=ti; ti+=64;
    }
    const float* sff[4] = {p_ff1_w, p_ff2_w, p_ff1_w+(size_t)DIM*FFD, p_ff2_w+(size_t)FFD*DIM};
    short* dff[4] = {wt+262144, wt+524288, wt+LW+262144, wt+LW+524288};
    int Kff[4] = {DIM, FFD, DIM, FFD};
    int Nff[4] = {FFD, DIM, FFD, DIM};
    for(int i=0;i<4;i++){
      a.src[10+i]=sff[i]; a.dst[10+i]=dff[i]; a.K[10+i]=Kff[i]; a.N[10+i]=Nff[i];
      a.ts[10+i]=ti; ti+=256;
    }
    a.ts[14]=ti;   // 1664
    wprep_fused<<<1664,256,0,stream>>>(a);
  }

  embed_kernel<<<BN/4,256,0,stream>>>(expr,coords,gene_emb,pos_emb,val_w,val_b,val_g,val_bb,
                                      sp_w,sp_b,sp_g,sp_bb,x);

  dim3 gdd(2, (BN+127)/128);
  dim3 gff1(8, (FFROWS2+127)/128);
  dim3 gff2(2, (FFROWS2+127)/128);
  dim3 gkm(8, NB*NH);
  dim3 gkc(8, NB*NH);
  dim3 gcr(80, NB*NH);
  dim3 gq((NSEQ+63)/64, NB*NH);
  dim3 gps(8, NB);
  short* wtkk = wt + 2*LW;
  short* wtvv = wtkk + 65536;

  for(int l=0;l<2;l++){
    short* wl = wt + (size_t)l*LW;
    ln_bf4<<<BN/4,256,0,stream>>>(x, p_ln1_g+l*DIM, p_ln1_b+l*DIM, ybf);
    mgemm2<0,1><<<gdd,256,0,stream>>>(ybf, wl+65536,  p_bk+l*DIM, kbf, BN, DIM, DIM);
    mgemm2<0,1><<<gdd,256,0,stream>>>(ybf, wl+131072, p_bv+l*DIM, vbf, BN, DIM, DIM);
    mgemm2<0,1><<<gdd,256,0,stream>>>(ybf, wl,        p_bq+l*DIM, qbf, BN, DIM, DIM);
    diagk4<<<BN/4,256,0,stream>>>(kbf, diagk);
    projprep_kernel<<<80,256,0,stream>>>(proj + (size_t)l*MF*DH, projbf, kmax);
    kside_max<<<gkm,256,0,stream>>>(kbf, projbf, kmax);
    kside_ctx<<<gkc,256,0,stream>>>(kbf, vbf, projbf, diagk, kmax, ctxP);
    ctx_reduce<<<gcr,256,0,stream>>>(ctxP, ctxT);
    qside_mfma<<<gq,256,0,stream>>>(qbf, projbf, ctxT, kbf);   // o -> kbf
    mgemm2<1,0><<<gdd,256,0,stream>>>(kbf, wl+196608, p_bo+l*DIM, x, BN, DIM, DIM);
    ln_bf4<<<BN/4,256,0,stream>>>(x, p_ln2_g+l*DIM, p_ln2_b+l*DIM, ybf);
    for(int c2=0;c2<2;c2++){
      size_t roff=(size_t)c2*FFROWS2;
      mgemm2<2,1><<<gff1,256,0,stream>>>(ybf+roff*DIM, wl+262144, p_ff1_b+l*FFD, qbf,
                                         FFROWS2, FFD, DIM);
      mgemm2<1,0><<<gff2,256,0,stream>>>(qbf, wl+524288, p_ff2_b+l*DIM, x+roff*DIM,
                                         FFROWS2, DIM, FFD);
    }
  }

  // final pooling attention
  castbf<<<(int)(BND/1024),256,0,stream>>>(x, ybf);
  mgemm2<0,1><<<gdd,256,0,stream>>>(ybf, wtkk, k_b, kbf, BN, DIM, DIM);
  mgemm2<0,1><<<gdd,256,0,stream>>>(ybf, wtvv, v_b, vbf, BN, DIM, DIM);
  rowproj_kernel<<<NB,256,0,stream>>>(x, q_w, q_b, qfin, NSEQ*DIM);
  pool_scores<<<gps,256,0,stream>>>(qfin, kbf, scb);
  pool_pv<<<NB,256,0,stream>>>(scb, vbf, pooled);
  rowproj_kernel<<<NB,256,0,stream>>>(pooled, o_w, o_b, out, DIM);
}

// Round 10
// 1663.493 us; speedup vs baseline: 9.5619x; 1.0639x over previous
//
#include <hip/hip_runtime.h>
#include <hip/hip_bf16.h>
#include <math.h>

#define NB   32
#define KG   2048
#define NSEQ 2049
#define DIM  256
#define NH   4
#define DH   64
#define MF   266
#define FFD  1024
#define BN   (NB*NSEQ)          // 65568
#define FFROWS2 32784           // BN/2
#define NORMC 0.35355339059327376f   // 64^-0.25
#define RATIOC (1.0f/16.309506430300091f) // 266^-0.5

typedef __attribute__((ext_vector_type(8))) short short8;
typedef __attribute__((ext_vector_type(4))) float f32x4;
#define MFMA16(a,b,c) __builtin_amdgcn_mfma_f32_16x16x32_bf16(a,b,c,0,0,0)

__device__ __forceinline__ short f2b(float f){
  union{ __hip_bfloat16 h; short s;} u; u.h = __float2bfloat16(f); return u.s;
}
__device__ __forceinline__ float b2f(short s){
  union{ short s; __hip_bfloat16 h;} u; u.s = s; return __bfloat162float(u.h);
}
__device__ __forceinline__ float gelu_f(float x){
  return 0.5f*x*(1.0f+erff(x*0.70710678118654752f));
}
__device__ __forceinline__ void gload16(const short* g, short* l){
  __builtin_amdgcn_global_load_lds(
      (const __attribute__((address_space(1))) void*)g,
      (__attribute__((address_space(3))) void*)l, 16, 0, 0);
}
__device__ __forceinline__ float waveSum(float v){
  #pragma unroll
  for(int o=32;o>0;o>>=1) v += __shfl_down(v,o);
  return v;   // lane 0 only
}
__device__ __forceinline__ float waveMax(float v){
  #pragma unroll
  for(int o=32;o>0;o>>=1) v = fmaxf(v,__shfl_down(v,o));
  return v;   // lane 0 only
}
__device__ __forceinline__ float xorSum64(float v){
  v += __shfl_xor(v,32); v += __shfl_xor(v,16); v += __shfl_xor(v,8);
  v += __shfl_xor(v,4);  v += __shfl_xor(v,2);  v += __shfl_xor(v,1);
  return v;   // exact, all lanes
}
__device__ __forceinline__ float blockSum256(float v, float* red){
  int lane = threadIdx.x & 63, wid = threadIdx.x >> 6;
  v = waveSum(v);
  __syncthreads();
  if(lane==0) red[wid]=v;
  __syncthreads();
  return red[0]+red[1]+red[2]+red[3];
}
__device__ __forceinline__ float blockMax256(float v, float* red){
  int lane = threadIdx.x & 63, wid = threadIdx.x >> 6;
  v = waveMax(v);
  __syncthreads();
  if(lane==0) red[wid]=v;
  __syncthreads();
  return fmaxf(fmaxf(red[0],red[1]),fmaxf(red[2],red[3]));
}
__device__ __forceinline__ unsigned fenc(float f){
  unsigned u = __float_as_uint(f);
  return (u & 0x80000000u) ? ~u : (u | 0x80000000u);
}
__device__ __forceinline__ float fdec(unsigned u){
  return (u & 0x80000000u) ? __uint_as_float(u & 0x7FFFFFFFu) : __uint_as_float(~u);
}

// ---------------- embed: wave-per-row, 4 rows/block, xor-exact
__global__ __launch_bounds__(256) void embed_kernel(
    const float* __restrict__ expr, const float* __restrict__ coords,
    const float* __restrict__ gene_emb, const float* __restrict__ pos_emb,
    const float* __restrict__ val_w, const float* __restrict__ val_b,
    const float* __restrict__ val_g, const float* __restrict__ val_bb,
    const float* __restrict__ sp_w, const float* __restrict__ sp_b,
    const float* __restrict__ sp_g, const float* __restrict__ sp_bb,
    float* __restrict__ x){
  int w = threadIdx.x >> 6, l = threadIdx.x & 63;
  int row = blockIdx.x*4 + w;
  int b = row / NSEQ, n = row % NSEQ;
  int d0 = l*4;
  float4 v;
  if(n==0){
    float c0 = coords[b*2], c1 = coords[b*2+1];
    float4 w0 = *reinterpret_cast<const float4*>(sp_w + d0);
    float4 w1 = *reinterpret_cast<const float4*>(sp_w + DIM + d0);
    float4 bb = *reinterpret_cast<const float4*>(sp_b + d0);
    v = make_float4(c0*w0.x+c1*w1.x+bb.x, c0*w0.y+c1*w1.y+bb.y,
                    c0*w0.z+c1*w1.z+bb.z, c0*w0.w+c1*w1.w+bb.w);
  } else {
    float e = expr[(size_t)b*KG + (n-1)];
    float4 vw = *reinterpret_cast<const float4*>(val_w + d0);
    float4 vb = *reinterpret_cast<const float4*>(val_b + d0);
    v = make_float4(e*vw.x+vb.x, e*vw.y+vb.y, e*vw.z+vb.z, e*vw.w+vb.w);
  }
  float mu = xorSum64(v.x+v.y+v.z+v.w)*(1.0f/DIM);
  float cx=v.x-mu, cy=v.y-mu, cz=v.z-mu, cw=v.w-mu;
  float var = xorSum64(cx*cx+cy*cy+cz*cz+cw*cw)*(1.0f/DIM);
  float r = rsqrtf(var + 1e-5f);
  float4 g  = (n==0)? *reinterpret_cast<const float4*>(sp_g + d0)
                    : *reinterpret_cast<const float4*>(val_g + d0);
  float4 be = (n==0)? *reinterpret_cast<const float4*>(sp_bb + d0)
                    : *reinterpret_cast<const float4*>(val_bb + d0);
  float4 h = make_float4(gelu_f(cx*r*g.x+be.x), gelu_f(cy*r*g.y+be.y),
                         gelu_f(cz*r*g.z+be.z), gelu_f(cw*r*g.w+be.w));
  if(n!=0){
    float4 ge = *reinterpret_cast<const float4*>(gene_emb + (size_t)(n-1)*DIM + d0);
    float4 pe = *reinterpret_cast<const float4*>(pos_emb  + (size_t)(n-1)*DIM + d0);
    h.x += ge.x+pe.x; h.y += ge.y+pe.y; h.z += ge.z+pe.z; h.w += ge.w+pe.w;
  }
  *reinterpret_cast<float4*>(x + (size_t)row*DIM + d0) = h;
}

// ---------------- LN -> bf16, wave-per-row, xor-exact
__global__ __launch_bounds__(256) void ln_bf4(const float* __restrict__ xin,
    const float* __restrict__ g, const float* __restrict__ bb, short* __restrict__ ybf){
  int w = threadIdx.x >> 6, l = threadIdx.x & 63;
  int row = blockIdx.x*4 + w;
  const float* xr = xin + (size_t)row*DIM;
  float4 v = *reinterpret_cast<const float4*>(xr + l*4);
  float s = xorSum64(v.x+v.y+v.z+v.w);
  float mu = s*(1.0f/DIM);
  float cx=v.x-mu, cy=v.y-mu, cz=v.z-mu, cw=v.w-mu;
  float var = xorSum64(cx*cx+cy*cy+cz*cz+cw*cw)*(1.0f/DIM);
  float r = rsqrtf(var+1e-5f);
  const float4 gv = *reinterpret_cast<const float4*>(g + l*4);
  const float4 bv = *reinterpret_cast<const float4*>(bb + l*4);
  short4 o = make_short4(f2b(cx*r*gv.x+bv.x), f2b(cy*r*gv.y+bv.y),
                         f2b(cz*r*gv.z+bv.z), f2b(cw*r*gv.w+bv.w));
  *reinterpret_cast<short4*>(ybf + (size_t)row*DIM + l*4) = o;
}

// ---------------- diag_k, wave-per-row (16-lane xor groups)
__global__ __launch_bounds__(256) void diagk4(const short* __restrict__ kbf, float* __restrict__ diagk){
  int w = threadIdx.x >> 6, l = threadIdx.x & 63;
  int row = blockIdx.x*4 + w;
  int b = row / NSEQ, n = row % NSEQ;
  short4 v = *reinterpret_cast<const short4*>(kbf + (size_t)row*DIM + l*4);
  float a0=b2f(v.x), a1=b2f(v.y), a2=b2f(v.z), a3=b2f(v.w);
  float s = a0*a0+a1*a1+a2*a2+a3*a3;
  s += __shfl_xor(s,1); s += __shfl_xor(s,2);
  s += __shfl_xor(s,4); s += __shfl_xor(s,8);
  if((l&15)==0){
    int h = l>>4;
    diagk[((size_t)(b*NH+h))*NSEQ + n] = 0.0625f*s;
  }
}

// ---------------- fused weight prep: 14 matrices, 32x32 LDS tile transpose
#define NW 14
struct WPArgs {
  const float* src[NW];
  short* dst[NW];
  int K[NW], N[NW];
  int ts[NW+1];
};
__global__ __launch_bounds__(256) void wprep_fused(WPArgs a){
  __shared__ float tile[32][33];
  int bx = blockIdx.x, t = threadIdx.x;
  int i = 0;
  while(bx >= a.ts[i+1]) i++;
  int tl = bx - a.ts[i];
  int N = a.N[i], K = a.K[i];
  int tcols = N >> 5;
  int tr = tl / tcols, tc = tl - tr*tcols;
  const float* src = a.src[i];
  short* dst = a.dst[i];
  int r = t>>3, c4 = (t&7)*4;
  float4 v = *reinterpret_cast<const float4*>(src + (size_t)(tr*32+r)*N + tc*32 + c4);
  tile[r][c4+0]=v.x; tile[r][c4+1]=v.y; tile[r][c4+2]=v.z; tile[r][c4+3]=v.w;
  __syncthreads();
  short4 o = make_short4(f2b(tile[c4+0][r]), f2b(tile[c4+1][r]),
                         f2b(tile[c4+2][r]), f2b(tile[c4+3][r]));
  *reinterpret_cast<short4*>(dst + (size_t)(tc*32+r)*K + tr*32 + c4) = o;
}

// ---------------- MFMA GEMM v3: global_load_lds staging, linear LDS [128][32]
// WBF: also mirror the result as bf16 into Yb (used to fold castbf)
template<int EPI, int OBF, int WBF>
__global__ __launch_bounds__(256) void mgemm2(
    const short* __restrict__ A, const short* __restrict__ Bt,
    const float* __restrict__ bias, void* __restrict__ Cv,
    int M, int N, int Kd, short* __restrict__ Yb){
  __shared__ short As[128*32];
  __shared__ short Bs[128*32];
  int t=threadIdx.x, l=t&63, w=t>>6, lr=l&15, lk=l>>4;
  int wm=w>>1, wn=w&1;
  int m0=blockIdx.y*128, n0=blockIdx.x*128;
  f32x4 acc[4][4];
  #pragma unroll
  for(int i=0;i<4;i++)
    #pragma unroll
    for(int j=0;j<4;j++) acc[i][j]=f32x4{0.f,0.f,0.f,0.f};
  for(int k0=0;k0<Kd;k0+=32){
    #pragma unroll
    for(int p=0;p<2;p++){
      int chunk = p*256 + t;
      int row = chunk>>2, qc = chunk&3;
      short* lbase = &As[(size_t)(p*256 + w*64)*8];
      gload16(A + (size_t)(m0+row)*Kd + k0 + qc*8, lbase);
    }
    #pragma unroll
    for(int p=0;p<2;p++){
      int chunk = p*256 + t;
      int row = chunk>>2, qc = chunk&3;
      short* lbase = &Bs[(size_t)(p*256 + w*64)*8];
      gload16(Bt + (size_t)(n0+row)*Kd + k0 + qc*8, lbase);
    }
    __syncthreads();
    short8 af[4], bfr[4];
    #pragma unroll
    for(int i=0;i<4;i++) af[i] = *reinterpret_cast<const short8*>(&As[(wm*64+i*16+lr)*32 + lk*8]);
    #pragma unroll
    for(int j=0;j<4;j++) bfr[j] = *reinterpret_cast<const short8*>(&Bs[(wn*64+j*16+lr)*32 + lk*8]);
    #pragma unroll
    for(int i=0;i<4;i++)
      #pragma unroll
      for(int j=0;j<4;j++) acc[i][j] = MFMA16(af[i], bfr[j], acc[i][j]);
    __syncthreads();
  }
  #pragma unroll
  for(int i=0;i<4;i++){
    int gm0 = m0 + wm*64 + i*16 + lk*4;
    #pragma unroll
    for(int j=0;j<4;j++){
      int gc = n0 + wn*64 + j*16 + lr;
      float bs = bias[gc];
      #pragma unroll
      for(int r=0;r<4;r++){
        int gm = gm0 + r;
        if(gm<M){
          float vv = acc[i][j][r] + bs;
          if(EPI==2) vv = gelu_f(vv);
          size_t idx = (size_t)gm*N + gc;
          if(OBF){
            ((short*)Cv)[idx] = f2b(vv);
          } else {
            float* C = (float*)Cv;
            if(EPI==1) vv += C[idx];
            C[idx] = vv;
            if(WBF) Yb[idx] = f2b(vv);
          }
        }
      }
    }
  }
}

// ---------------- fused QKV GEMM: Bt rows [0,768) = q|k|v transposed weights,
// epilogue routes gc>>8 to {q,k,v} buffers with per-segment bias.
__global__ __launch_bounds__(256) void qkv_gemm(
    const short* __restrict__ A, const short* __restrict__ Bt,
    const float* __restrict__ bq, const float* __restrict__ bk, const float* __restrict__ bv,
    short* __restrict__ qd, short* __restrict__ kd, short* __restrict__ vd, int M){
  __shared__ short As[128*32];
  __shared__ short Bs[128*32];
  int t=threadIdx.x, l=t&63, w=t>>6, lr=l&15, lk=l>>4;
  int wm=w>>1, wn=w&1;
  int m0=blockIdx.y*128, n0=blockIdx.x*128;
  f32x4 acc[4][4];
  #pragma unroll
  for(int i=0;i<4;i++)
    #pragma unroll
    for(int j=0;j<4;j++) acc[i][j]=f32x4{0.f,0.f,0.f,0.f};
  for(int k0=0;k0<DIM;k0+=32){
    #pragma unroll
    for(int p=0;p<2;p++){
      int chunk = p*256 + t;
      int row = chunk>>2, qc = chunk&3;
      short* lbase = &As[(size_t)(p*256 + w*64)*8];
      gload16(A + (size_t)(m0+row)*DIM + k0 + qc*8, lbase);
    }
    #pragma unroll
    for(int p=0;p<2;p++){
      int chunk = p*256 + t;
      int row = chunk>>2, qc = chunk&3;
      short* lbase = &Bs[(size_t)(p*256 + w*64)*8];
      gload16(Bt + (size_t)(n0+row)*DIM + k0 + qc*8, lbase);
    }
    __syncthreads();
    short8 af[4], bfr[4];
    #pragma unroll
    for(int i=0;i<4;i++) af[i] = *reinterpret_cast<const short8*>(&As[(wm*64+i*16+lr)*32 + lk*8]);
    #pragma unroll
    for(int j=0;j<4;j++) bfr[j] = *reinterpret_cast<const short8*>(&Bs[(wn*64+j*16+lr)*32 + lk*8]);
    #pragma unroll
    for(int i=0;i<4;i++)
      #pragma unroll
      for(int j=0;j<4;j++) acc[i][j] = MFMA16(af[i], bfr[j], acc[i][j]);
    __syncthreads();
  }
  #pragma unroll
  for(int i=0;i<4;i++){
    int gm0 = m0 + wm*64 + i*16 + lk*4;
    #pragma unroll
    for(int j=0;j<4;j++){
      int gc = n0 + wn*64 + j*16 + lr;   // 0..767
      int sel = gc >> 8, col = gc & 255;
      short* dst = (sel==0)? qd : ((sel==1)? kd : vd);
      const float* bp = (sel==0)? bq : ((sel==1)? bk : bv);
      float bs = bp[col];
      #pragma unroll
      for(int r=0;r<4;r++){
        int gm = gm0 + r;
        if(gm<M) dst[(size_t)gm*DIM + col] = f2b(acc[i][j][r] + bs);
      }
    }
  }
}

// ---------------- projbf + kmax init
__global__ __launch_bounds__(256) void projprep_kernel(const float* __restrict__ proj,
    short* __restrict__ projbf, unsigned* __restrict__ kmax){
  int i = blockIdx.x*256 + threadIdx.x;
  if(i==0) *kmax = 0u;
  if(i < 320*64){
    int m = i>>6, d = i&63;
    float v = (m<MF)? proj[(size_t)m*DH + d]*NORMC : 0.f;
    projbf[i] = f2b(v);
  }
}

// ---------------- kside pass0: global max of xd_k, 8-way n-split
__global__ __launch_bounds__(256) void kside_max(
    const short* __restrict__ kbf, const short* __restrict__ projbf,
    unsigned* __restrict__ kmax){
  __shared__ short kS[32*72];
  __shared__ float red[4];
  int t=threadIdx.x, l=t&63, w=t>>6, lr=l&15, lk=l>>4;
  int split = blockIdx.x, bh = blockIdx.y;
  int b=bh>>2, h=bh&3;
  int c0 = split*9, c1 = min(c0+9, 65);
  int nf = (w==3)?5:4;
  short8 apf[5][2];
  #pragma unroll
  for(int fi=0;fi<5;fi++){
    int fr = (fi<4)? (fi*4+w) : 16;
    #pragma unroll
    for(int ks=0;ks<2;ks++)
      apf[fi][ks] = *reinterpret_cast<const short8*>(projbf + (fr*16+lr)*64 + ks*32 + lk*8);
  }
  const short8 z8 = {0,0,0,0,0,0,0,0};
  float lmax = -3.0e38f;
  for(int ch=c0; ch<c1; ++ch){
    int n0 = ch*32;
    __syncthreads();
    {
      int r = t>>3, c8 = (t&7)*8;
      int gn = n0 + r;
      short8 v8 = z8;
      if(gn<NSEQ) v8 = *reinterpret_cast<const short8*>(kbf + ((size_t)(b*NSEQ+gn))*DIM + h*DH + c8);
      *reinterpret_cast<short8*>(&kS[r*72+c8]) = v8;
    }
    __syncthreads();
    for(int fi=0;fi<nf;fi++){
      int fr = (fi<4)? (fi*4+w) : 16;
      #pragma unroll
      for(int fn=0;fn<2;fn++){
        f32x4 xa = f32x4{0.f,0.f,0.f,0.f};
        #pragma unroll
        for(int ks=0;ks<2;ks++){
          short8 bk = *reinterpret_cast<const short8*>(&kS[(fn*16+lr)*72 + ks*32 + lk*8]);
          xa = MFMA16(apf[fi][ks], bk, xa);
        }
        #pragma unroll
        for(int r=0;r<4;r++){
          int m = fr*16 + lk*4 + r;
          int n = n0 + fn*16 + lr;
          if(m<MF && n<NSEQ) lmax = fmaxf(lmax, xa[r]);
        }
      }
    }
  }
  float bm = blockMax256(lmax, red);
  if(t==0) atomicMax(kmax, fenc(bm));
}

// ---------------- kside pass1: (f=4 x n=2) split, fp32 partials
__global__ __launch_bounds__(256) void kside_ctx(
    const short* __restrict__ kbf, const short* __restrict__ vbf,
    const short* __restrict__ projbf, const float* __restrict__ diagk,
    const unsigned* __restrict__ kmax, float* __restrict__ ctxP){
  __shared__ short kS[32*72];
  __shared__ short vT[64*40];
  __shared__ short kfS[80*40];
  __shared__ float diagS[32];
  int t=threadIdx.x, l=t&63, w=t>>6, lr=l&15, lk=l>>4;
  int fb=blockIdx.x&3, qh=blockIdx.x>>2, bh=blockIdx.y; int b=bh>>2, h=bh&3;
  int F0 = fb*5;
  int ch0 = qh*33, ch1 = min(65, ch0+33);
  float stab = fdec(*kmax);
  short8 apf0[2], apf1[2];
  #pragma unroll
  for(int ks=0;ks<2;ks++){
    apf0[ks] = *reinterpret_cast<const short8*>(projbf + ((F0+w)*16+lr)*64 + ks*32 + lk*8);
    apf1[ks] = *reinterpret_cast<const short8*>(projbf + ((F0+4)*16+lr)*64 + ks*32 + lk*8);
  }
  f32x4 ctx[5];
  #pragma unroll
  for(int f=0;f<5;f++) ctx[f]=f32x4{0.f,0.f,0.f,0.f};
  f32x4 ksc0 = f32x4{0.f,0.f,0.f,0.f};
  f32x4 ksc1 = f32x4{0.f,0.f,0.f,0.f};
  const short ONE=(short)0x3F80;
  const short8 ones8 = {ONE,ONE,ONE,ONE,ONE,ONE,ONE,ONE};
  const short8 z8 = {0,0,0,0,0,0,0,0};
  for(int ch=ch0; ch<ch1; ++ch){
    int n0 = ch*32;
    __syncthreads();
    {
      int r = t>>3, c8 = (t&7)*8;
      int gn = n0 + r;
      short8 v8 = z8;
      if(gn<NSEQ) v8 = *reinterpret_cast<const short8*>(kbf + ((size_t)(b*NSEQ+gn))*DIM + h*DH + c8);
      *reinterpret_cast<short8*>(&kS[r*72+c8]) = v8;
    }
    #pragma unroll
    for(int p=0;p<4;p++){
      int n2 = 2*w + 8*p;
      int dd = t&63;
      int gn0=n0+n2, gn1=gn0+1;
      short v0 = (gn0<NSEQ)? vbf[((size_t)(b*NSEQ+gn0))*DIM + h*DH + dd] : (short)0;
      short v1 = (gn1<NSEQ)? vbf[((size_t)(b*NSEQ+gn1))*DIM + h*DH + dd] : (short)0;
      *reinterpret_cast<short2*>(&vT[dd*40 + n2]) = make_short2(v0,v1);
    }
    if(t<32) diagS[t] = (n0+t<NSEQ)? diagk[(size_t)bh*NSEQ + n0+t] : 0.f;
    __syncthreads();
    #pragma unroll
    for(int fn=0;fn<2;fn++){
      f32x4 xa = f32x4{0.f,0.f,0.f,0.f};
      #pragma unroll
      for(int ks=0;ks<2;ks++){
        short8 bk = *reinterpret_cast<const short8*>(&kS[(fn*16+lr)*72 + ks*32 + lk*8]);
        xa = MFMA16(apf0[ks], bk, xa);
      }
      float dgn = diagS[fn*16+lr];
      #pragma unroll
      for(int r=0;r<4;r++){
        int m = (F0+w)*16 + lk*4 + r;
        int n = n0 + fn*16 + lr;
        float kf = (m<MF && n<NSEQ)? RATIOC*(__expf(xa[r]-dgn-stab)+1e-4f) : 0.f;
        kfS[(w*16+lk*4+r)*40 + fn*16 + lr] = f2b(kf);
      }
    }
    if(w==0){
      #pragma unroll
      for(int fn=0;fn<2;fn++){
        f32x4 xa = f32x4{0.f,0.f,0.f,0.f};
        #pragma unroll
        for(int ks=0;ks<2;ks++){
          short8 bk = *reinterpret_cast<const short8*>(&kS[(fn*16+lr)*72 + ks*32 + lk*8]);
          xa = MFMA16(apf1[ks], bk, xa);
        }
        float dgn = diagS[fn*16+lr];
        #pragma unroll
        for(int r=0;r<4;r++){
          int m = (F0+4)*16 + lk*4 + r;
          int n = n0 + fn*16 + lr;
          float kf = (m<MF && n<NSEQ)? RATIOC*(__expf(xa[r]-dgn-stab)+1e-4f) : 0.f;
          kfS[(64+lk*4+r)*40 + fn*16 + lr] = f2b(kf);
        }
      }
    }
    __syncthreads();
    short8 bv = *reinterpret_cast<const short8*>(&vT[(w*16+lr)*40 + lk*8]);
    short8 a0 = *reinterpret_cast<const short8*>(&kfS[(w*16+lr)*40 + lk*8]);
    short8 a4 = *reinterpret_cast<const short8*>(&kfS[(64+lr)*40 + lk*8]);
    ksc0 = MFMA16(a0, ones8, ksc0);
    ksc1 = MFMA16(a4, ones8, ksc1);
    #pragma unroll
    for(int fl=0;fl<5;fl++){
      short8 a_ = *reinterpret_cast<const short8*>(&kfS[(fl*16+lr)*40 + lk*8]);
      ctx[fl] = MFMA16(a_, bv, ctx[fl]);
    }
  }
  float* P = ctxP + ((size_t)(qh*128 + bh))*65*320;
  #pragma unroll
  for(int fl=0;fl<5;fl++){
    #pragma unroll
    for(int r=0;r<4;r++){
      int m = (F0+fl)*16 + lk*4 + r;
      P[(size_t)(w*16+lr)*320 + m] = ctx[fl][r];
    }
  }
  if(lr==0){
    #pragma unroll
    for(int r=0;r<4;r++){
      int m = (F0+w)*16 + lk*4 + r;
      P[(size_t)64*320 + m] = ksc0[r];
    }
    if(w==0){
      #pragma unroll
      for(int r=0;r<4;r++){
        int m = (F0+4)*16 + lk*4 + r;
        P[(size_t)64*320 + m] = ksc1[r];
      }
    }
  }
}

// ---------------- reduce 2 fp32 partials -> bf16 ctxT[bh][80][288]
__global__ __launch_bounds__(256) void ctx_reduce(const float* __restrict__ ctxP, short* __restrict__ ctxT){
  int row = blockIdx.x, bh = blockIdx.y, t = threadIdx.x;
  short* o = ctxT + ((size_t)bh*80 + row)*288;
  if(row < 65){
    const float* P0 = ctxP + ((size_t)bh*65 + row)*320;
    const float* P1 = ctxP + ((size_t)(128+bh)*65 + row)*320;
    for(int m=t; m<288; m+=256)
      o[m] = (m<272)? f2b(P0[m]+P1[m]) : (short)0;
  } else {
    for(int m=t; m<288; m+=256) o[m] = 0;
  }
}

// ---------------- qside fused (round-8 staged version; coalesced q staging)
__global__ __launch_bounds__(256) void qside_mfma(
    const short* __restrict__ qbf, const short* __restrict__ projbf,
    const short* __restrict__ ctxT, short* __restrict__ obf){
  __shared__ short qS[64*72];
  __shared__ short qfS[64*296];
  __shared__ float diagS[64];
  int t=threadIdx.x, l=t&63, w=t>>6, lr=l&15, lk=l>>4;
  int n0 = blockIdx.x*64, bh = blockIdx.y;
  int b = bh>>2, h = bh&3;
  const short8 z8 = {0,0,0,0,0,0,0,0};
  {
    int r = t>>2, c8 = (t&3)*16;
    int gn = n0 + r;
    float ssq = 0.f;
    #pragma unroll
    for(int i=0;i<2;i++){
      short8 v8 = z8;
      if(gn<NSEQ) v8 = *reinterpret_cast<const short8*>(qbf + ((size_t)(b*NSEQ+gn))*DIM + h*DH + c8 + i*8);
      #pragma unroll
      for(int u=0;u<8;u++){ float fv=b2f(v8[u]); ssq += fv*fv; }
      *reinterpret_cast<short8*>(&qS[r*72+c8+i*8]) = v8;
    }
    ssq += __shfl_xor(ssq,1); ssq += __shfl_xor(ssq,2);
    if((t&3)==0) diagS[r] = 0.0625f*ssq;
    #pragma unroll
    for(int i=0;i<4;i++) qfS[r*296 + 272 + (t&3)*4 + i] = 0;
  }
  __syncthreads();
  short8 aq[2];
  #pragma unroll
  for(int ks=0;ks<2;ks++) aq[ks] = *reinterpret_cast<const short8*>(&qS[(w*16+lr)*72 + ks*32 + lk*8]);
  f32x4 acc[17];
  #pragma unroll
  for(int f=0;f<17;f++) acc[f]=f32x4{0.f,0.f,0.f,0.f};
  #pragma unroll
  for(int f=0;f<17;f++){
    #pragma unroll
    for(int ks=0;ks<2;ks++){
      short8 bp = *reinterpret_cast<const short8*>(projbf + (f*16+lr)*64 + ks*32 + lk*8);
      acc[f] = MFMA16(aq[ks], bp, acc[f]);
    }
  }
  float rmax[4];
  #pragma unroll
  for(int r=0;r<4;r++){
    float m = -3.0e38f;
    #pragma unroll
    for(int f=0;f<17;f++){
      float v = (f==16 && lr>=10)? -3.0e38f : acc[f][r];
      m = fmaxf(m,v);
    }
    m = fmaxf(m,__shfl_xor(m,1)); m = fmaxf(m,__shfl_xor(m,2));
    m = fmaxf(m,__shfl_xor(m,4)); m = fmaxf(m,__shfl_xor(m,8));
    rmax[r]=m;
  }
  float dg[4];
  #pragma unroll
  for(int r=0;r<4;r++) dg[r] = diagS[w*16 + lk*4 + r];
  #pragma unroll
  for(int f=0;f<17;f++)
    #pragma unroll
    for(int r=0;r<4;r++){
      float qv = RATIOC*(__expf(acc[f][r] - dg[r] - rmax[r]) + 1e-4f);
      qfS[(w*16+lk*4+r)*296 + f*16 + lr] = f2b(qv);
    }
  __syncthreads();
  f32x4 pv[5];
  #pragma unroll
  for(int f=0;f<5;f++) pv[f]=f32x4{0.f,0.f,0.f,0.f};
  const short* cT = ctxT + (size_t)bh*80*288;
  for(int ks=0;ks<9;ks++){
    short8 a_ = *reinterpret_cast<const short8*>(&qfS[(w*16+lr)*296 + ks*32 + lk*8]);
    #pragma unroll
    for(int f=0;f<5;f++){
      short8 bb = *reinterpret_cast<const short8*>(cT + (f*16+lr)*288 + ks*32 + lk*8);
      pv[f] = MFMA16(a_, bb, pv[f]);
    }
  }
  #pragma unroll
  for(int r=0;r<4;r++){
    int gn = n0 + w*16 + lk*4 + r;
    if(gn>=NSEQ) continue;
    float den = __shfl(pv[4][r], (l & 48), 64);
    float inv = 1.0f/den;
    size_t obase = ((size_t)(b*NSEQ+gn))*DIM + h*DH;
    #pragma unroll
    for(int f=0;f<4;f++) obf[obase + f*16 + lr] = f2b(pv[f][r]*inv);
  }
}

// ---------------- small row projection (fp32)
__global__ __launch_bounds__(256) void rowproj_kernel(const float* __restrict__ src,
    const float* __restrict__ W, const float* __restrict__ bias,
    float* __restrict__ dst, int rowstride){
  __shared__ float rs[DIM];
  int b=blockIdx.x, t=threadIdx.x;
  rs[t]=src[(size_t)b*rowstride+t];
  __syncthreads();
  float s=bias[t];
  for(int j=0;j<DIM;j++) s += rs[j]*W[(size_t)j*DIM+t];
  dst[(size_t)b*DIM+t]=s;
}

// ---------------- final pooling: pass 1 — raw scores (grid 8 x NB)
__global__ __launch_bounds__(256) void pool_scores(const float* __restrict__ qfin,
    const short* __restrict__ kk, float* __restrict__ scb){
  __shared__ float qsh[DIM];
  int kc=blockIdx.x, b=blockIdx.y, t=threadIdx.x;
  qsh[t]=qfin[b*DIM+t];
  __syncthreads();
  int kidx = kc*256 + t;
  const short* kr = kk + ((size_t)(b*NSEQ+1+kidx))*DIM;
  float s=0;
  for(int j8=0;j8<32;j8++){
    short8 kv = *reinterpret_cast<const short8*>(kr + j8*8);
    #pragma unroll
    for(int u=0;u<8;u++) s += qsh[j8*8+u]*b2f(kv[u]);
  }
  scb[(size_t)b*KG + kidx] = s*0.0625f;
}

// ---------------- final pooling: pass 2 — softmax + PV (grid NB)
__global__ __launch_bounds__(256) void pool_pv(const float* __restrict__ scb,
    const short* __restrict__ vv, float* __restrict__ pooled){
  __shared__ float sc[KG];
  __shared__ float red[4];
  int b=blockIdx.x, t=threadIdx.x;
  float ls[8]; float lmax=-3.4e38f;
  #pragma unroll
  for(int i=0;i<8;i++){
    ls[i] = scb[(size_t)b*KG + t + i*256];
    lmax = fmaxf(lmax, ls[i]);
  }
  float gmax=blockMax256(lmax,red);
  float lsum=0;
  #pragma unroll
  for(int i=0;i<8;i++){ float e=__expf(ls[i]-gmax); sc[t+i*256]=e; lsum+=e; }
  float gsum=blockSum256(lsum,red);
  __syncthreads();
  float inv=1.0f/gsum;
  float p=0;
  for(int kidx=0;kidx<KG;kidx++) p += sc[kidx]*b2f(vv[((size_t)(b*NSEQ+1+kidx))*DIM + t]);
  pooled[b*DIM+t]=p*inv;
}

extern "C" void kernel_launch(void* const* d_in, const int* in_sizes, int n_in,
                              void* d_out, int out_size, void* d_ws, size_t ws_size,
                              hipStream_t stream){
  const float* expr   =(const float*)d_in[0];
  const float* coords =(const float*)d_in[1];
  const float* gene_emb=(const float*)d_in[2];
  const float* pos_emb=(const float*)d_in[3];
  const float* val_w  =(const float*)d_in[4];
  const float* val_b  =(const float*)d_in[5];
  const float* val_g  =(const float*)d_in[6];
  const float* val_bb =(const float*)d_in[7];
  const float* sp_w   =(const float*)d_in[8];
  const float* sp_b   =(const float*)d_in[9];
  const float* sp_g   =(const float*)d_in[10];
  const float* sp_bb  =(const float*)d_in[11];
  const float* p_ln1_g=(const float*)d_in[12];
  const float* p_ln1_b=(const float*)d_in[13];
  const float* p_wq   =(const float*)d_in[14];
  const float* p_bq   =(const float*)d_in[15];
  const float* p_wk   =(const float*)d_in[16];
  const float* p_bk   =(const float*)d_in[17];
  const float* p_wv   =(const float*)d_in[18];
  const float* p_bv   =(const float*)d_in[19];
  const float* p_wo   =(const float*)d_in[20];
  const float* p_bo   =(const float*)d_in[21];
  const float* p_ln2_g=(const float*)d_in[22];
  const float* p_ln2_b=(const float*)d_in[23];
  const float* p_ff1_w=(const float*)d_in[24];
  const float* p_ff1_b=(const float*)d_in[25];
  const float* p_ff2_w=(const float*)d_in[26];
  const float* p_ff2_b=(const float*)d_in[27];
  const float* proj   =(const float*)d_in[28];
  const float* q_w    =(const float*)d_in[29];
  const float* q_b    =(const float*)d_in[30];
  const float* k_w    =(const float*)d_in[31];
  const float* k_b    =(const float*)d_in[32];
  const float* v_w    =(const float*)d_in[33];
  const float* v_b    =(const float*)d_in[34];
  const float* o_w    =(const float*)d_in[35];
  const float* o_b    =(const float*)d_in[36];
  float* out = (float*)d_out;

  const size_t BND = (size_t)BN*DIM;     // 16,785,408
  size_t needB = BND*4 + BND*2*4
               + ((size_t)NB*NH*NSEQ + 4 + 2*(size_t)NB*DIM)*4
               + ((size_t)20480 + 2949120 + 1703936)*2;
  if(ws_size < needB){
    hipMemsetAsync(d_out, 0, (size_t)out_size*sizeof(float), stream);
    return;
  }
  float* ws = (float*)d_ws;
  float* x  = ws;                                  // BND fp32
  short* ybf = (short*)(x + BND);
  short* qbf = ybf + BND;
  short* kbf = qbf + BND;
  short* vbf = kbf + BND;
  float* diagk = (float*)(vbf + BND);
  unsigned* kmax = (unsigned*)(diagk + (size_t)NB*NH*NSEQ);
  float* qfin   = (float*)(kmax+4);
  float* pooled = qfin + NB*DIM;
  short* projbf = (short*)(pooled + NB*DIM);       // 320*64
  short* ctxT   = projbf + 20480;                  // 128*80*288
  short* wt     = ctxT + (size_t)128*80*288;       // 1,703,936
  const size_t LW = 786432;
  float* ctxP = (float*)ybf;   // fp32 partials in dead ybf region
  float* scb  = diagk;         // pool scores scratch

  // ---- fused weight prep
  {
    WPArgs a;
    short* wtkk = wt + 2*LW;
    short* wtvv = wtkk + 65536;
    const float* s10[10] = {p_wq, p_wk, p_wv, p_wo,
                            p_wq+(size_t)DIM*DIM, p_wk+(size_t)DIM*DIM,
                            p_wv+(size_t)DIM*DIM, p_wo+(size_t)DIM*DIM,
                            k_w, v_w};
    short* d10[10] = {wt, wt+65536, wt+131072, wt+196608,
                      wt+LW, wt+LW+65536, wt+LW+131072, wt+LW+196608,
                      wtkk, wtvv};
    int ti = 0;
    for(int i=0;i<10;i++){
      a.src[i]=s10[i]; a.dst[i]=d10[i]; a.K[i]=DIM; a.N[i]=DIM;
      a.ts[i]=ti; ti+=64;
    }
    const float* sff[4] = {p_ff1_w, p_ff2_w, p_ff1_w+(size_t)DIM*FFD, p_ff2_w+(size_t)FFD*DIM};
    short* dff[4] = {wt+262144, wt+524288, wt+LW+262144, wt+LW+524288};
    int Kff[4] = {DIM, FFD, DIM, FFD};
    int Nff[4] = {FFD, DIM, FFD, DIM};
    for(int i=0;i<4;i++){
      a.src[10+i]=sff[i]; a.dst[10+i]=dff[i]; a.K[10+i]=Kff[i]; a.N[10+i]=Nff[i];
      a.ts[10+i]=ti; ti+=256;
    }
    a.ts[14]=ti;
    wprep_fused<<<1664,256,0,stream>>>(a);
  }

  embed_kernel<<<BN/4,256,0,stream>>>(expr,coords,gene_emb,pos_emb,val_w,val_b,val_g,val_bb,
                                      sp_w,sp_b,sp_g,sp_bb,x);

  dim3 gdd(2, (BN+127)/128);
  dim3 gqkv(6, (BN+127)/128);
  dim3 gff1(8, (FFROWS2+127)/128);
  dim3 gff2(2, (FFROWS2+127)/128);
  dim3 gkm(8, NB*NH);
  dim3 gkc(8, NB*NH);
  dim3 gcr(80, NB*NH);
  dim3 gq((NSEQ+63)/64, NB*NH);
  dim3 gps(8, NB);
  short* wtkk = wt + 2*LW;
  short* wtvv = wtkk + 65536;

  for(int l=0;l<2;l++){
    short* wl = wt + (size_t)l*LW;
    ln_bf4<<<BN/4,256,0,stream>>>(x, p_ln1_g+l*DIM, p_ln1_b+l*DIM, ybf);
    // fused QKV: Bt rows [0,768) = q|k|v (contiguous in wl)
    qkv_gemm<<<gqkv,256,0,stream>>>(ybf, wl, p_bq+l*DIM, p_bk+l*DIM, p_bv+l*DIM,
                                    qbf, kbf, vbf, BN);
    diagk4<<<BN/4,256,0,stream>>>(kbf, diagk);
    projprep_kernel<<<80,256,0,stream>>>(proj + (size_t)l*MF*DH, projbf, kmax);
    kside_max<<<gkm,256,0,stream>>>(kbf, projbf, kmax);
    kside_ctx<<<gkc,256,0,stream>>>(kbf, vbf, projbf, diagk, kmax, ctxP);
    ctx_reduce<<<gcr,256,0,stream>>>(ctxP, ctxT);
    qside_mfma<<<gq,256,0,stream>>>(qbf, projbf, ctxT, kbf);   // o -> kbf
    mgemm2<1,0,0><<<gdd,256,0,stream>>>(kbf, wl+196608, p_bo+l*DIM, x, BN, DIM, DIM, nullptr);
    ln_bf4<<<BN/4,256,0,stream>>>(x, p_ln2_g+l*DIM, p_ln2_b+l*DIM, ybf);
    for(int c2=0;c2<2;c2++){
      size_t roff=(size_t)c2*FFROWS2;
      mgemm2<2,1,0><<<gff1,256,0,stream>>>(ybf+roff*DIM, wl+262144, p_ff1_b+l*FFD, qbf,
                                           FFROWS2, FFD, DIM, nullptr);
      if(l==1)
        mgemm2<1,0,1><<<gff2,256,0,stream>>>(qbf, wl+524288, p_ff2_b+l*DIM, x+roff*DIM,
                                             FFROWS2, DIM, FFD, ybf+roff*DIM);
      else
        mgemm2<1,0,0><<<gff2,256,0,stream>>>(qbf, wl+524288, p_ff2_b+l*DIM, x+roff*DIM,
                                             FFROWS2, DIM, FFD, nullptr);
    }
  }

  // final pooling attention (ybf already holds bf16(x) via WBF epilogue)
  mgemm2<0,1,0><<<gdd,256,0,stream>>>(ybf, wtkk, k_b, kbf, BN, DIM, DIM, nullptr);
  mgemm2<0,1,0><<<gdd,256,0,stream>>>(ybf, wtvv, v_b, vbf, BN, DIM, DIM, nullptr);
  rowproj_kernel<<<NB,256,0,stream>>>(x, q_w, q_b, qfin, NSEQ*DIM);
  pool_scores<<<gps,256,0,stream>>>(qfin, kbf, scb);
  pool_pv<<<NB,256,0,stream>>>(scb, vbf, pooled);
  rowproj_kernel<<<NB,256,0,stream>>>(pooled, o_w, o_b, out, DIM);
}